// Round 7
// baseline (828.606 us; speedup 1.0000x reference)
//
#include <hip/hip_runtime.h>
#include <hip/hip_bf16.h>

typedef __hip_bfloat16 bf16;
typedef __attribute__((ext_vector_type(8))) short s8v;   // 8 bf16 in 4 VGPRs
typedef __attribute__((ext_vector_type(4))) short s4v;   // 4 bf16 in 2 VGPRs
typedef __attribute__((ext_vector_type(4))) float f4v;   // mfma accumulator

#define MFMA(a, b, c) __builtin_amdgcn_mfma_f32_16x16x32_bf16(a, b, c, 0, 0, 0)

#define B_    256
#define DIN_  64
#define NU_   256
#define NN_   207
#define KC_   1280
#define NB_   (NN_ * B_)       // 52992 transformer rows; 52992 = 207*256
#define NBD_  13565952LL       // NB_ * 256 elements (one ws region)

// bf16 weight scratch layout (shorts), appended after the 6 proven regions
#define WU_OFF   0LL           // Wu rows 0..255   } contiguous => WUC[512][1280]
#define WC_OFF   327680LL      // Wc rows 256..511 }
#define IP_OFF   655360LL
#define OP_OFF   851968LL
#define F1_OFF   917504LL
#define F2_OFF   983040LL
#define ADJ_OFF  1048576LL     // adj padded to [207][256], zeros in pad
#define WEXT_N   (ADJ_OFF + 207LL * 256LL)   // 1101568 shorts

__device__ __forceinline__ float bf2f(bf16 v) { return __bfloat162float(v); }
__device__ __forceinline__ bf16  f2bf(float v) { return __float2bfloat16(v); }
__device__ __forceinline__ short f2s(float v) { bf16 t = __float2bfloat16(v); return *(short*)&t; }

// direct global->LDS DMA, 16B per lane; lds dest must be wave-uniform
__device__ __forceinline__ void gl16(const void* g, void* l) {
    __builtin_amdgcn_global_load_lds(
        (const __attribute__((address_space(1))) void*)g,
        (__attribute__((address_space(3))) void*)l, 16, 0, 0);
}

// Swizzled LDS tile layout: tile row stride 64 shorts; 16B chunk c of row r
// lives at position c^(r&7). gl16 writes linearly (lane -> seg*512+lane*16B),
// so the global SOURCE chunk is pre-swizzled with chunk^(lane>>3).
#define SWZ(rr, cb) ((rr) * 64 + ((((cb) + q) ^ ((rr) & 7)) << 3))

// ---------------------------------------------------------------------------
// One-shot fp32 -> bf16 weight conversion into wext.
// ---------------------------------------------------------------------------
__global__ __launch_bounds__(256) void cvt_w_k(
    const float* __restrict__ Wu, const float* __restrict__ Wc,
    const float* __restrict__ ip, const float* __restrict__ op,
    const float* __restrict__ f1, const float* __restrict__ f2,
    const float* __restrict__ adj, short* __restrict__ dst)
{
    long long t = (long long)blockIdx.x * 256 + threadIdx.x;
    long long nt = (long long)gridDim.x * 256;
    for (long long g = t; g < 262144; g += nt) {   // 1048576 elems / 4
        long long e = g * 4;
        const float* src; long long off;
        if (e < WC_OFF)      { src = Wu; off = e; }
        else if (e < IP_OFF) { src = Wc; off = e - WC_OFF; }
        else if (e < OP_OFF) { src = ip; off = e - IP_OFF; }
        else if (e < F1_OFF) { src = op; off = e - OP_OFF; }
        else if (e < F2_OFF) { src = f1; off = e - F1_OFF; }
        else                 { src = f2; off = e - F2_OFF; }
        float4 fv = *(const float4*)(src + off);
        s4v v = {f2s(fv.x), f2s(fv.y), f2s(fv.z), f2s(fv.w)};
        *(s4v*)(dst + e) = v;
    }
    short* adst = dst + ADJ_OFF;
    for (long long g = t; g < 207LL * 256LL; g += nt) {
        int r = (int)(g >> 8), c = (int)(g & 255);
        adst[g] = (c < NN_) ? f2s(adj[r * NN_ + c]) : (short)0;
    }
}

// ---------------------------------------------------------------------------
// Pipelined MFMA GEMM (fast path): 512 thr / 8 waves, tile 256x256, BK=64,
// 2 LDS buffers (128 KB). COUNTED-vmcnt staggered prefetch (T4):
//   issue order ... A(t), B(t), A(t+1) | wait vmcnt(4) -> t ready, A(t+1)
//   stays in flight across the barrier; B(t+1) staged after top barrier
//   (its buffer dead); A(t+2) staged after bottom barrier (buf t&1 dead).
//   vmcnt(0) only on the last K-tile.
// XCD-aware remap: grid = (nswz=N/256, 208); xcd r = w&7 sweeps all n-tiles
// of one m-tile consecutively -> A-tile L2-resident per XCD.
// EPI=0: C = act(A@W^T + bias); vt!=null => cols>=512 transposed to vt.
// EPI=1: gates mode. W = WUC (logical col n -> phys row (n&1)*256+(n>>1));
//        epilogue pairs u/c via shfl_xor(1), combines with hnT -> outF fp32.
// ---------------------------------------------------------------------------
template<int EPI>
__global__ __launch_bounds__(512) void gemm_pipe(
    const short* __restrict__ A, int lda,
    const short* __restrict__ Wb, int ldb,
    const float* __restrict__ bias, bf16* __restrict__ C, int ldc,
    int K, int act, short* __restrict__ vt,
    const float* __restrict__ bu, const float* __restrict__ bc,
    const bf16* __restrict__ hnT, float* __restrict__ outF)
{
    __shared__ __align__(16) short As[2][256 * 64];
    __shared__ __align__(16) short Bs[2][256 * 64];
    const int w_ = blockIdx.y * gridDim.x + blockIdx.x;   // dispatch-order id
    const int nswz = gridDim.x;
    const int xr = w_ & 7, sidx = w_ >> 3;
    const int mt = xr + 8 * (sidx / nswz);
    const int nt = sidx % nswz;
    if (mt >= 207) return;                                // idle pad block
    const int m0 = mt * 256, n0 = nt * 256;
    const int tid = threadIdx.x;
    const int lane = tid & 63, wid = tid >> 6;
    const int l15 = lane & 15, q = lane >> 4;
    const int wm = (wid >> 2) * 128, wn = (wid & 3) * 64;
    const int seg_r = lane >> 3;
    const int csw8 = ((lane & 7) ^ seg_r) << 3;
    const int nk = K >> 6;

    // hoisted global pointers (include swizzled chunk); advance by k0
    const short* ap[4];
    const short* bp[4];
#pragma unroll
    for (int i = 0; i < 4; i++) {
        int gm = m0 + (wid * 4 + i) * 8 + seg_r;
        ap[i] = A + (long long)gm * lda + csw8;
        int gn = n0 + (wid * 4 + i) * 8 + seg_r;
        int pr = EPI ? ((gn & 1) * 256 + (gn >> 1)) : gn;
        bp[i] = Wb + (long long)pr * ldb + csw8;
    }
    // hoisted LDS read offsets for cs=0; cs=1 is off^32 (chunk bit2 flip)
    int offA[8], offB[4];
#pragma unroll
    for (int i = 0; i < 8; i++)
        offA[i] = (wm + i * 16 + l15) * 64 + ((q ^ (l15 & 7)) << 3);
#pragma unroll
    for (int j = 0; j < 4; j++)
        offB[j] = (wn + j * 16 + l15) * 64 + ((q ^ (l15 & 7)) << 3);

    f4v acc[8][4] = {};

    auto stageA = [&](int t) {
        const int pb = t & 1;
        const int k0 = t << 6;
#pragma unroll
        for (int i = 0; i < 4; i++)
            gl16(ap[i] + k0, &As[pb][(wid * 4 + i) * 512]);
    };
    auto stageB = [&](int t) {
        const int pb = t & 1;
        const int k0 = t << 6;
#pragma unroll
        for (int i = 0; i < 4; i++)
            gl16(bp[i] + k0, &Bs[pb][(wid * 4 + i) * 512]);
    };

    // prologue: A(0), B(0), A(1)  -> 12 loads/wave outstanding
    stageA(0);
    stageB(0);
    if (nk > 1) stageA(1);

    for (int t = 0; t < nk; ++t) {
        // counted wait: first 8 outstanding (A(t),B(t)) done; A(t+1) in flight
        if (t + 1 < nk) { asm volatile("s_waitcnt vmcnt(4)" ::: "memory"); }
        else            { asm volatile("s_waitcnt vmcnt(0)" ::: "memory"); }
        __builtin_amdgcn_s_barrier();
        __builtin_amdgcn_sched_barrier(0);
        if (t + 1 < nk) stageB(t + 1);        // buf (t+1)&1 dead (read in t-1)
        const short* Asp = &As[t & 1][0];
        const short* Bsp = &Bs[t & 1][0];
#pragma unroll
        for (int cs = 0; cs < 2; ++cs) {
            const int cx = cs << 5;               // ^32 toggles k-half chunk
            s8v bfv[4];
#pragma unroll
            for (int j = 0; j < 4; j++) bfv[j] = *(const s8v*)&Bsp[offB[j] ^ cx];
#pragma unroll
            for (int half = 0; half < 2; ++half) {
                s8v af[4];
#pragma unroll
                for (int i = 0; i < 4; i++) af[i] = *(const s8v*)&Asp[offA[half * 4 + i] ^ cx];
                __builtin_amdgcn_s_setprio(1);
#pragma unroll
                for (int i = 0; i < 4; i++)
#pragma unroll
                    for (int j = 0; j < 4; j++)
                        acc[half * 4 + i][j] = MFMA(af[i], bfv[j], acc[half * 4 + i][j]);
                __builtin_amdgcn_s_setprio(0);
            }
        }
        __builtin_amdgcn_s_barrier();          // all waves done reading buf t&1
        __builtin_amdgcn_sched_barrier(0);
        if (t + 2 < nk) stageA(t + 2);         // buf t&1 now dead
    }

    if (EPI == 0) {
#pragma unroll
        for (int i = 0; i < 8; i++) {
            int mbase = m0 + wm + i * 16 + q * 4;
#pragma unroll
            for (int j = 0; j < 4; j++) {
                int n = n0 + wn + j * 16 + l15;
                float bv = bias ? bias[n] : 0.f;
#pragma unroll
                for (int r = 0; r < 4; r++) {
                    int m = mbase + r;
                    float v = acc[i][j][r] + bv;
                    if (act == 3) v = fmaxf(v, 0.f);
                    if (vt && n >= 512) {
                        int d = n - 512;
                        int bb = m / NN_;
                        int node = m - bb * NN_;
                        vt[((long long)bb * 256 + d) * 208 + node] = f2s(v);
                    } else {
                        C[(long long)m * ldc + n] = f2bf(v);
                    }
                }
            }
        }
    } else {
#pragma unroll
        for (int i = 0; i < 8; i++) {
            int mbase = m0 + wm + i * 16 + q * 4;
#pragma unroll
            for (int j = 0; j < 4; j++) {
                int n = n0 + wn + j * 16 + l15;
                int och = n >> 1;
                float bv = (n & 1) ? bc[och] : bu[och];
#pragma unroll
                for (int r = 0; r < 4; r++) {
                    int m = mbase + r;
                    float pre = acc[i][j][r] + bv;
                    float oth = __shfl_xor(pre, 1);
                    if (!(n & 1)) {
                        float u = 1.f / (1.f + __expf(-pre));
                        float cg = tanhf(oth);
                        float hv = bf2f(hnT[(long long)m * 256 + och]);
                        int bb = m / NN_;
                        int node = m - bb * NN_;
                        outF[((long long)bb * NU_ + och) * NN_ + node] = u * hv + (1.f - u) * cg;
                    }
                }
            }
        }
    }
}

// ---------------------------------------------------------------------------
// Fallback (slow path) GEMM: fp32 weights, reg-staged, 2-buffer.
// ---------------------------------------------------------------------------
__global__ __launch_bounds__(256) void gemm_nk0(
    const short* __restrict__ A, int lda,
    const float* __restrict__ Wf, int ldb,
    const float* __restrict__ bias, bf16* __restrict__ C, int ldc,
    int M, int N, int K, int act, short* __restrict__ vt)
{
    __shared__ __align__(16) short As[2][128 * 64];
    __shared__ __align__(16) short Bs[2][128 * 64];
    const int tid = threadIdx.x;
    const int lane = tid & 63, wid = tid >> 6;
    const int l15 = lane & 15, q = lane >> 4;
    const int wm = (wid >> 1) * 64, wn = (wid & 1) * 64;
    const int m0 = blockIdx.y * 128, n0 = blockIdx.x * 128;

    f4v acc[4][4] = {};
    const int nk = K >> 6;

    auto stage = [&](int k0, int pb) {
#pragma unroll
        for (int i = 0; i < 4; i++) {
            int idx = tid + (i << 8);
            int r = idx >> 3, c = idx & 7;
            int gm = m0 + r, gk = k0 + (c << 3);
            s8v v = {0, 0, 0, 0, 0, 0, 0, 0};
            if (gm < M) v = *(const s8v*)(A + (long long)gm * lda + gk);
            *(s8v*)&As[pb][r * 64 + ((c ^ (r & 7)) << 3)] = v;
        }
#pragma unroll
        for (int i = 0; i < 8; i++) {
            int idx = tid + (i << 8);
            int r = idx >> 4, c4 = idx & 15;
            int gn = n0 + r, gk = k0 + (c4 << 2);
            s4v v = {0, 0, 0, 0};
            if (gn < N) {
                float4 fx = *(const float4*)(Wf + (long long)gn * ldb + gk);
                v[0] = f2s(fx.x); v[1] = f2s(fx.y); v[2] = f2s(fx.z); v[3] = f2s(fx.w);
            }
            *(s4v*)&Bs[pb][r * 64 + (((c4 >> 1) ^ (r & 7)) << 3) + ((c4 & 1) << 2)] = v;
        }
    };

    stage(0, 0);
    __syncthreads();
    int pp = 0;
    for (int t = 0; t < nk; ++t) {
        if (t + 1 < nk) stage((t + 1) << 6, pp ^ 1);
#pragma unroll
        for (int ks = 0; ks < 64; ks += 32) {
            const int cb = ks >> 3;
            s8v af[4], bfv[4];
#pragma unroll
            for (int i = 0; i < 4; i++) {
                int rr = wm + i * 16 + l15;
                af[i] = *(const s8v*)&As[pp][SWZ(rr, cb)];
            }
#pragma unroll
            for (int j = 0; j < 4; j++) {
                int rr = wn + j * 16 + l15;
                bfv[j] = *(const s8v*)&Bs[pp][SWZ(rr, cb)];
            }
#pragma unroll
            for (int i = 0; i < 4; i++)
#pragma unroll
                for (int j = 0; j < 4; j++)
                    acc[i][j] = MFMA(af[i], bfv[j], acc[i][j]);
        }
        __syncthreads();
        pp ^= 1;
    }

#pragma unroll
    for (int i = 0; i < 4; i++) {
        int mbase = m0 + wm + i * 16 + q * 4;
#pragma unroll
        for (int j = 0; j < 4; j++) {
            int n = n0 + wn + j * 16 + l15;
            if (n >= N) continue;
            float bv = bias ? bias[n] : 0.f;
#pragma unroll
            for (int r = 0; r < 4; r++) {
                int m = mbase + r;
                if (m >= M) continue;
                float v = acc[i][j][r] + bv;
                if (act == 3) v = fmaxf(v, 0.f);
                if (vt && n >= 512) {
                    int d = n - 512;
                    int bb = m / NN_;
                    int node = m - bb * NN_;
                    vt[((long long)bb * 256 + d) * 208 + node] = f2s(v);
                } else {
                    C[(long long)m * ldc + n] = f2bf(v);
                }
            }
        }
    }
}

// ---------------------------------------------------------------------------
// MFMA attention, one block per (64-q tile, b). 4 waves, each owns 16 q.
// XCD swizzle: grid(4,256)=1024=8*128 exactly; same-b q-tiles co-locate.
// ---------------------------------------------------------------------------
__global__ __launch_bounds__(256) void attn_k(
    const short* __restrict__ qk, const short* __restrict__ vt,
    bf16* __restrict__ ao)
{
    __shared__ __align__(16) short Plds[64 * 232];
    __shared__ float sums[64];
    const int tid = threadIdx.x;
    const int lane = tid & 63, w = tid >> 6;
    const int l15 = lane & 15, quad = lane >> 4;
    const int w_ = blockIdx.y * gridDim.x + blockIdx.x;
    const int xr = w_ & 7, sidx = w_ >> 3;
    const int b = xr + 8 * (sidx >> 2);
    const int q0 = (sidx & 3) * 64;
    const long long rowcap = (long long)NB_ - 1;

    long long qrow = (long long)b * NN_ + q0 + w * 16 + l15;
    if (qrow > rowcap) qrow = rowcap;
    const short* qp = qk + qrow * 512;
    s8v bq[8];
#pragma unroll
    for (int ks = 0; ks < 8; ks++)
        bq[ks] = *(const s8v*)(qp + ks * 32 + quad * 8);

    const short* jp[13];
#pragma unroll
    for (int jf = 0; jf < 13; jf++) {
        long long jrow = (long long)b * NN_ + jf * 16 + l15;
        if (jrow > rowcap) jrow = rowcap;
        jp[jf] = qk + jrow * 512 + 256;
    }

    f4v sacc[13] = {};
#pragma unroll
    for (int ks = 0; ks < 8; ks++) {
        const int off = ks * 32 + quad * 8;
#pragma unroll
        for (int jf = 0; jf < 13; jf++) {
            s8v a = *(const s8v*)(jp[jf] + off);
            sacc[jf] = MFMA(a, bq[ks], sacc[jf]);
        }
    }

    float mx = -3.0e38f;
    float pv[13][4];
#pragma unroll
    for (int jf = 0; jf < 13; jf++)
#pragma unroll
        for (int r = 0; r < 4; r++) {
            int j = jf * 16 + quad * 4 + r;
            float v = (j < NN_) ? sacc[jf][r] * 0.0625f : -3.0e38f;
            pv[jf][r] = v;
            mx = fmaxf(mx, v);
        }
    mx = fmaxf(mx, __shfl_xor(mx, 16));
    mx = fmaxf(mx, __shfl_xor(mx, 32));
    float sum = 0.f;
#pragma unroll
    for (int jf = 0; jf < 13; jf++)
#pragma unroll
        for (int r = 0; r < 4; r++) {
            float p = __expf(pv[jf][r] - mx);
            pv[jf][r] = p;
            sum += p;
        }
    sum += __shfl_xor(sum, 16);
    sum += __shfl_xor(sum, 32);

    const int qloc = w * 16 + l15;
#pragma unroll
    for (int jf = 0; jf < 13; jf++)
#pragma unroll
        for (int r = 0; r < 4; r++)
            Plds[qloc * 232 + jf * 16 + quad * 4 + r] = f2s(pv[jf][r]);
    if (quad == 0) sums[qloc] = 1.f / sum;
#pragma unroll
    for (int i = 0; i < 4; i++) {               // zero pad cols 208..223
        int u = tid + i * 256;
        Plds[(u >> 4) * 232 + 208 + (u & 15)] = 0;
    }
    __syncthreads();

    const short* vbase = vt + (long long)b * 256 * 208;
    f4v oacc[16] = {};
#pragma unroll
    for (int ks = 0; ks < 7; ks++) {
        s8v pa = *(const s8v*)&Plds[(w * 16 + l15) * 232 + ks * 32 + quad * 8];
#pragma unroll
        for (int df = 0; df < 16; df++) {
            s8v vb = *(const s8v*)(vbase + (df * 16 + l15) * 208 + ks * 32 + quad * 8);
            oacc[df] = MFMA(pa, vb, oacc[df]);
        }
    }

#pragma unroll
    for (int df = 0; df < 16; df++) {
        int d = df * 16 + l15;
#pragma unroll
        for (int r = 0; r < 4; r++) {
            int ql = w * 16 + quad * 4 + r;
            int qg = q0 + ql;
            if (qg < NN_)
                ao[((long long)b * NN_ + qg) * 256 + d] = f2bf(oacc[df][r] * sums[ql]);
        }
    }
}

// ---------------------------------------------------------------------------
// Diffusion step in (b, node, chan) layout, batched over b.
// WB=1: adjb via global_load_lds (clamped rows); zT B-side reg-staged with
// async split (load regs early, ds_write after compute). Double-buffered.
// ---------------------------------------------------------------------------
template<int WB>
__global__ __launch_bounds__(256) void diff_k(
    const float* __restrict__ adj, const short* __restrict__ adjb,
    const short* __restrict__ zT_in,
    short* __restrict__ zT_out, int col_in, int col_out)
{
    __shared__ __align__(16) short As[2][128 * 64];
    __shared__ __align__(16) short Bs[2][128 * 64];
    const int tid = threadIdx.x;
    const int lane = tid & 63, wid = tid >> 6;
    const int l15 = lane & 15, q = lane >> 4;
    const int wm = (wid >> 1) * 64, wn = (wid & 1) * 64;
    const int m0 = blockIdx.y * 128, n0 = blockIdx.x * 128;
    const long long zb = (long long)blockIdx.z * NN_ * KC_;
    const int seg_r = lane >> 3, chunk = lane & 7;
    const int csw8 = (chunk ^ seg_r) << 3;
    const int bv_ = tid & 63, bcg = tid >> 6;   // B-stage coords

    f4v acc[4][4] = {};

    auto stageA = [&](int k0, int pb) {
        if (WB) {
#pragma unroll
            for (int i = 0; i < 4; i++) {
                int seg = wid * 4 + i;
                int gm = m0 + seg * 8 + seg_r;
                if (gm > NN_ - 1) gm = NN_ - 1;
                gl16(adjb + gm * 256 + k0 + csw8, &As[pb][seg * 512]);
            }
        } else {
#pragma unroll
            for (int i = 0; i < 32; i++) {
                int idx = tid + (i << 8);
                int r = idx >> 6, c = idx & 63;
                int gm = m0 + r, gk = k0 + c;
                short vv = (gm < NN_ && gk < NN_) ? f2s(adj[gm * NN_ + gk]) : (short)0;
                As[pb][r * 64 + (((c >> 3) ^ (r & 7)) << 3) + (c & 7)] = vv;
            }
        }
    };
    auto loadB = [&](int k0, s8v* breg) {
#pragma unroll
        for (int i = 0; i < 4; i++) {
            int gv = k0 + bv_, gc = n0 + (bcg + i * 4) * 8;
            s8v val = {0, 0, 0, 0, 0, 0, 0, 0};
            if (gv < NN_ && gc < 320)
                val = *(const s8v*)&zT_in[zb + (long long)gv * KC_ + col_in + gc];
            breg[i] = val;
        }
    };
    auto writeB = [&](s8v* breg, int pb) {
#pragma unroll
        for (int i = 0; i < 4; i++) {
            int cg = bcg + i * 4;
#pragma unroll
            for (int e = 0; e < 8; e++) {
                int row = cg * 8 + e;
                Bs[pb][row * 64 + (((bv_ >> 3) ^ (row & 7)) << 3) + (bv_ & 7)] = breg[i][e];
            }
        }
    };

    s8v breg[4];
    loadB(0, breg);
    stageA(0, 0);
    writeB(breg, 0);
    __syncthreads();
    int pp = 0;
    for (int t = 0; t < 4; ++t) {               // ceil(207/64) K-steps
        if (t < 3) { loadB((t + 1) << 6, breg); stageA((t + 1) << 6, pp ^ 1); }
#pragma unroll
        for (int ks = 0; ks < 64; ks += 32) {
            const int cb = ks >> 3;
            s8v af[4], bfv[4];
#pragma unroll
            for (int i = 0; i < 4; i++) {
                int rr = wm + i * 16 + l15;
                af[i] = *(const s8v*)&As[pp][SWZ(rr, cb)];
            }
#pragma unroll
            for (int j = 0; j < 4; j++) {
                int rr = wn + j * 16 + l15;
                bfv[j] = *(const s8v*)&Bs[pp][SWZ(rr, cb)];
            }
#pragma unroll
            for (int i = 0; i < 4; i++)
#pragma unroll
                for (int j = 0; j < 4; j++)
                    acc[i][j] = MFMA(af[i], bfv[j], acc[i][j]);
        }
        if (t < 3) writeB(breg, pp ^ 1);
        __syncthreads();
        pp ^= 1;
    }

#pragma unroll
    for (int i = 0; i < 4; i++) {
        int mbase = m0 + wm + i * 16 + q * 4;
#pragma unroll
        for (int j = 0; j < 4; j++) {
            int n = n0 + wn + j * 16 + l15;
            if (n >= 320) continue;
#pragma unroll
            for (int r = 0; r < 4; r++) {
                int m = mbase + r;
                if (m >= NN_) continue;
                zT_out[zb + (long long)m * KC_ + col_out + n] = f2s(acc[i][j][r]);
            }
        }
    }
}

// ---------------------------------------------------------------------------
// Fallback gates (slow path, fp32 weights).
// ---------------------------------------------------------------------------
__global__ __launch_bounds__(256) void gates_k0(
    const short* __restrict__ zT, const float* __restrict__ Wu,
    const float* __restrict__ Wc, const float* __restrict__ bu,
    const float* __restrict__ bc, const bf16* __restrict__ hnT,
    float* __restrict__ out)
{
    __shared__ __align__(16) short As[2][128 * 64];
    __shared__ __align__(16) short Bu[2][64 * 64];
    __shared__ __align__(16) short Bc[2][64 * 64];
    const int tid = threadIdx.x;
    const int lane = tid & 63, wid = tid >> 6;
    const int l15 = lane & 15, q = lane >> 4;
    const int b = blockIdx.z;
    const int m0 = blockIdx.y * 128;
    const int n0 = blockIdx.x * 64;
    const long long zb = (long long)b * NN_ * KC_;

    f4v aU[2][4] = {}, aC[2][4] = {};

    auto stage = [&](int k0, int pb) {
#pragma unroll
        for (int i = 0; i < 4; i++) {
            int idx = tid + (i << 8);
            int r = idx >> 3, c = idx & 7;
            int gw = m0 + r;
            s8v v = {0, 0, 0, 0, 0, 0, 0, 0};
            if (gw < NN_) v = *(const s8v*)&zT[zb + (long long)gw * KC_ + k0 + (c << 3)];
            *(s8v*)&As[pb][r * 64 + ((c ^ (r & 7)) << 3)] = v;
        }
#pragma unroll
        for (int i = 0; i < 4; i++) {
            int idx = tid + (i << 8);
            int r = idx >> 4, c4 = idx & 15;
            long long widx = (long long)(n0 + r) * KC_ + k0 + (c4 << 2);
            float4 fu = *(const float4*)(Wu + widx);
            float4 fc = *(const float4*)(Wc + widx);
            s4v vu = {f2s(fu.x), f2s(fu.y), f2s(fu.z), f2s(fu.w)};
            s4v vc = {f2s(fc.x), f2s(fc.y), f2s(fc.z), f2s(fc.w)};
            int di = r * 64 + (((c4 >> 1) ^ (r & 7)) << 3) + ((c4 & 1) << 2);
            *(s4v*)&Bu[pb][di] = vu;
            *(s4v*)&Bc[pb][di] = vc;
        }
    };

    stage(0, 0);
    __syncthreads();
    int pp = 0;
    for (int t = 0; t < 20; ++t) {
        if (t < 19) stage((t + 1) << 6, pp ^ 1);
#pragma unroll
        for (int ks = 0; ks < 64; ks += 32) {
            const int cb = ks >> 3;
            s8v af[2], bfu[4], bfc[4];
#pragma unroll
            for (int i = 0; i < 2; i++) {
                int rr = wid * 32 + i * 16 + l15;
                af[i] = *(const s8v*)&As[pp][SWZ(rr, cb)];
            }
#pragma unroll
            for (int j = 0; j < 4; j++) {
                int rr = j * 16 + l15;
                bfu[j] = *(const s8v*)&Bu[pp][SWZ(rr, cb)];
                bfc[j] = *(const s8v*)&Bc[pp][SWZ(rr, cb)];
            }
#pragma unroll
            for (int i = 0; i < 2; i++)
#pragma unroll
                for (int j = 0; j < 4; j++) {
                    aU[i][j] = MFMA(af[i], bfu[j], aU[i][j]);
                    aC[i][j] = MFMA(af[i], bfc[j], aC[i][j]);
                }
        }
        __syncthreads();
        pp ^= 1;
    }

#pragma unroll
    for (int i = 0; i < 2; i++) {
        int wbase = m0 + wid * 32 + i * 16 + q * 4;
#pragma unroll
        for (int j = 0; j < 4; j++) {
            int och = n0 + j * 16 + l15;
            float bvu = bu[och];
            float bvc = bc[och];
#pragma unroll
            for (int r = 0; r < 4; r++) {
                int w = wbase + r;
                if (w >= NN_) continue;
                float u = 1.f / (1.f + __expf(-(aU[i][j][r] + bvu)));
                float cg = tanhf(aC[i][j][r] + bvc);
                float hv = bf2f(hnT[((long long)b * NN_ + w) * 256 + och]);
                out[((long long)b * NU_ + och) * NN_ + w] = u * hv + (1.f - u) * cg;
            }
        }
    }
}

// inp[(b,n),c] = h[b,c,n] + embed[n,c] * mlt[b,n]  (32x32 LDS transpose of h)
__global__ __launch_bounds__(256) void build_inp_k(
    const float* __restrict__ h, const float* __restrict__ embed,
    const float* __restrict__ mlt, bf16* __restrict__ inp)
{
    __shared__ float t[32][33];
    const int b = blockIdx.z;
    const int n0 = blockIdx.x * 32, c0 = blockIdx.y * 32;
    const int t5 = threadIdx.x & 31, t8 = threadIdx.x >> 5;
#pragma unroll
    for (int r = 0; r < 4; r++) {
        int c = c0 + t8 + r * 8;
        int n = n0 + t5;
        t[t8 + r * 8][t5] = (n < NN_) ? h[((long long)b * 256 + c) * NN_ + n] : 0.f;
    }
    __syncthreads();
#pragma unroll
    for (int r = 0; r < 4; r++) {
        int n = n0 + t8 + r * 8;
        int c = c0 + t5;
        if (n < NN_) {
            float v = t[t5][t8 + r * 8] + embed[n * 256 + c] * mlt[b * NN_ + n];
            inp[((long long)b * NN_ + n) * 256 + c] = f2bf(v);
        }
    }
}

// out = LN(x + y) (optional tanh). One wave per 256-elem row, no barriers.
__global__ __launch_bounds__(256) void add_ln_k(
    const bf16* __restrict__ xr, const bf16* __restrict__ yr,
    const float* __restrict__ w, const float* __restrict__ bb,
    bf16* __restrict__ out, int do_tanh)
{
    const int lane = threadIdx.x & 63, wv = threadIdx.x >> 6;
    const long long row = (long long)blockIdx.x * 4 + wv;
    const long long base = row * 256 + lane * 4;
    s4v xv = *(const s4v*)((const short*)xr + base);
    s4v yv = *(const s4v*)((const short*)yr + base);
    float v[4];
    float sum = 0.f;
#pragma unroll
    for (int i = 0; i < 4; i++) {
        short sx = xv[i], sy = yv[i];
        v[i] = bf2f(*(bf16*)&sx) + bf2f(*(bf16*)&sy);
        sum += v[i];
    }
#pragma unroll
    for (int s = 1; s < 64; s <<= 1) sum += __shfl_xor(sum, s);
    float mu = sum * (1.f / 256.f);
    float vs = 0.f;
#pragma unroll
    for (int i = 0; i < 4; i++) { float d = v[i] - mu; vs += d * d; }
#pragma unroll
    for (int s = 1; s < 64; s <<= 1) vs += __shfl_xor(vs, s);
    float inv = rsqrtf(vs * (1.f / 256.f) + 1e-5f);
    s4v ov;
#pragma unroll
    for (int i = 0; i < 4; i++) {
        float r = (v[i] - mu) * inv * w[lane * 4 + i] + bb[lane * 4 + i];
        if (do_tanh) r = tanhf(r);
        ov[i] = f2s(r);
    }
    *(s4v*)((short*)out + base) = ov;
}

// hnT[(b,n),c] = step ? sqrt(1-dt)*h[b,c,n] - sqrt(dt)*eps[(b,n),c] : h[b,c,n]
__global__ __launch_bounds__(256) void hnew_k(
    const float* __restrict__ h, const bf16* __restrict__ epsb,
    const float* __restrict__ dt, const int* __restrict__ step, bf16* __restrict__ hnT)
{
    __shared__ float t[32][33];
    const int b = blockIdx.z;
    const int n0 = blockIdx.x * 32, c0 = blockIdx.y * 32;
    const int t5 = threadIdx.x & 31, t8 = threadIdx.x >> 5;
#pragma unroll
    for (int r = 0; r < 4; r++) {
        int c = c0 + t8 + r * 8;
        int n = n0 + t5;
        t[t8 + r * 8][t5] = (n < NN_) ? h[((long long)b * 256 + c) * NN_ + n] : 0.f;
    }
    __syncthreads();
    const int st = *step;
    const float d = dt[b];
    const float sa = sqrtf(fmaxf(1.f - d, 0.f)), sb = sqrtf(d);
#pragma unroll
    for (int r = 0; r < 4; r++) {
        int n = n0 + t8 + r * 8;
        int c = c0 + t5;
        if (n < NN_) {
            float hv = t[t5][t8 + r * 8];
            float val = hv;
            if (st != 0) {
                float ev = bf2f(epsb[((long long)b * NN_ + n) * 256 + c]);
                val = sa * hv - sb * ev;
            }
            hnT[((long long)b * NN_ + n) * 256 + c] = f2bf(val);
        }
    }
}

// zT[(b,n), c] = x[b,c,n] for c < 64 (transpose)
__global__ __launch_bounds__(256) void zx_k(
    const float* __restrict__ x, short* __restrict__ zT)
{
    __shared__ float t[32][33];
    const int b = blockIdx.z;
    const int n0 = blockIdx.x * 32, c0 = blockIdx.y * 32;
    const int t5 = threadIdx.x & 31, t8 = threadIdx.x >> 5;
#pragma unroll
    for (int r = 0; r < 4; r++) {
        int c = c0 + t8 + r * 8;
        int n = n0 + t5;
        t[t8 + r * 8][t5] = (n < NN_) ? x[((long long)b * DIN_ + c) * NN_ + n] : 0.f;
    }
    __syncthreads();
#pragma unroll
    for (int r = 0; r < 4; r++) {
        int n = n0 + t8 + r * 8;
        int c = c0 + t5;
        if (n < NN_)
            zT[((long long)b * NN_ + n) * KC_ + c] = f2s(t[t5][t8 + r * 8]);
    }
}

// zT[(b,n), 64+c] = hnT[(b,n), c]  (vectorized copy)
__global__ __launch_bounds__(256) void zcopy_k(
    const short* __restrict__ hnT, short* __restrict__ zT)
{
    long long u = (long long)blockIdx.x * 256 + threadIdx.x;  // < NB_*32
    long long row = u >> 5;
    int cu = (int)(u & 31);
    s8v v = *(const s8v*)(hnT + row * 256 + cu * 8);
    *(s8v*)(zT + row * KC_ + 64 + cu * 8) = v;
}

extern "C" void kernel_launch(void* const* d_in, const int* in_sizes, int n_in,
                              void* d_out, int out_size, void* d_ws, size_t ws_size,
                              hipStream_t stream) {
    const float* x          = (const float*)d_in[0];
    const float* delta_t    = (const float*)d_in[1];
    const float* h          = (const float*)d_in[2];
    const float* adj        = (const float*)d_in[3];
    const float* mlt        = (const float*)d_in[5];
    const int*  step        = (const int*)d_in[7];
    const float* embed      = (const float*)d_in[8];
    const float* in_proj_w  = (const float*)d_in[9];
    const float* in_proj_b  = (const float*)d_in[10];
    const float* out_proj_w = (const float*)d_in[11];
    const float* out_proj_b = (const float*)d_in[12];
    const float* ln1_w      = (const float*)d_in[13];
    const float* ln1_b      = (const float*)d_in[14];
    const float* ln2_w      = (const float*)d_in[15];
    const float* ln2_b      = (const float*)d_in[16];
    const float* ffn_w1     = (const float*)d_in[17];
    const float* ffn_b1     = (const float*)d_in[18];
    const float* ffn_w2     = (const float*)d_in[19];
    const float* ffn_b2     = (const float*)d_in[20];
    const float* W_u        = (const float*)d_in[21];
    const float* b_u        = (const float*)d_in[22];
    const float* W_c        = (const float*)d_in[23];
    const float* b_c        = (const float*)d_in[24];
    float* out = (float*)d_out;
    bf16* ws   = (bf16*)d_ws;

    bf16* inp = ws;
    short* qk = (short*)(ws + 1 * NBD_);
    short* vt = (short*)(ws + 3 * NBD_);
    bf16* ao  = ws + 4 * NBD_ + 65536;
    bf16* o   = ws + 1 * NBD_;
    bf16* s   = ws + 2 * NBD_;
    bf16* f   = ws + 1 * NBD_;
    bf16* f2  = ws + 3 * NBD_;
    bf16* eps = ws + 2 * NBD_;
    bf16* hnT = ws;
    short* zT = (short*)(ws + 1 * NBD_);
    short* wext = (short*)(ws + 6 * NBD_);

    const size_t need = (size_t)(6 * NBD_ + WEXT_N) * 2;
    const bool fast = ws_size >= need;   // capture-time host decision

    short* wuc  = wext + WU_OFF;         // [512][1280]: rows 0..255 Wu, 256..511 Wc
    short* ipb  = wext + IP_OFF;
    short* opb  = wext + OP_OFF;
    short* f1b  = wext + F1_OFF;
    short* f2b  = wext + F2_OFF;
    short* adjb = wext + ADJ_OFF;

    // 0. one-shot fp32 -> bf16 weight conversion
    if (fast)
        cvt_w_k<<<dim3(1024), dim3(256), 0, stream>>>(
            W_u, W_c, in_proj_w, out_proj_w, ffn_w1, ffn_w2, adj, wext);

    // 1. inp = h^T + embed * mlt   ((b,n) rows)
    build_inp_k<<<dim3(7, 8, 256), dim3(256), 0, stream>>>(h, embed, mlt, inp);

    // 2. qkv GEMM: Q,K -> qk rows (512); V -> vt transposed
    if (fast)
        gemm_pipe<0><<<dim3(3, 208), dim3(512), 0, stream>>>(
            (const short*)inp, 256, ipb, 256, in_proj_b,
            (bf16*)qk, 512, 256, 0, vt, nullptr, nullptr, nullptr, nullptr);
    else
        gemm_nk0<<<dim3(6, 414), dim3(256), 0, stream>>>(
            (const short*)inp, 256, in_proj_w, 256, in_proj_b,
            (bf16*)qk, 512, NB_, 768, 256, 0, vt);

    // 3. MFMA attention (XCD-swizzled internally)
    attn_k<<<dim3(4, 256), dim3(256), 0, stream>>>(qk, vt, ao);

    // 4. o = ao @ out_proj^T + b
    if (fast)
        gemm_pipe<0><<<dim3(1, 208), dim3(512), 0, stream>>>(
            (const short*)ao, 256, opb, 256, out_proj_b,
            o, 256, 256, 0, nullptr, nullptr, nullptr, nullptr, nullptr);
    else
        gemm_nk0<<<dim3(2, 414), dim3(256), 0, stream>>>(
            (const short*)ao, 256, out_proj_w, 256, out_proj_b, o, 256, NB_, 256, 256, 0, nullptr);

    // 5. s = LN1(inp + o)
    add_ln_k<<<dim3(NB_ / 4), dim3(256), 0, stream>>>(inp, o, ln1_w, ln1_b, s, 0);

    // 6. f = relu(s @ ffn_w1^T + b)
    if (fast)
        gemm_pipe<0><<<dim3(1, 208), dim3(512), 0, stream>>>(
            (const short*)s, 256, f1b, 256, ffn_b1,
            f, 256, 256, 3, nullptr, nullptr, nullptr, nullptr, nullptr);
    else
        gemm_nk0<<<dim3(2, 414), dim3(256), 0, stream>>>(
            (const short*)s, 256, ffn_w1, 256, ffn_b1, f, 256, NB_, 256, 256, 3, nullptr);

    // 7. f2 = f @ ffn_w2^T + b
    if (fast)
        gemm_pipe<0><<<dim3(1, 208), dim3(512), 0, stream>>>(
            (const short*)f, 256, f2b, 256, ffn_b2,
            f2, 256, 256, 0, nullptr, nullptr, nullptr, nullptr, nullptr);
    else
        gemm_nk0<<<dim3(2, 414), dim3(256), 0, stream>>>(
            (const short*)f, 256, ffn_w2, 256, ffn_b2, f2, 256, NB_, 256, 256, 0, nullptr);

    // 8. eps = tanh(LN2(s + f2))   (in-place over s)
    add_ln_k<<<dim3(NB_ / 4), dim3(256), 0, stream>>>(s, f2, ln2_w, ln2_b, eps, 1);

    // 9. hnT = step ? sqrt(1-dt)*h - sqrt(dt)*eps : h   ((b,n,c) layout)
    hnew_k<<<dim3(7, 8, 256), dim3(256), 0, stream>>>(h, eps, delta_t, step, hnT);

    // 10. zT cols 0..63 = x^T; 11. cols 64..319 = hnT
    zx_k<<<dim3(7, 2, 256), dim3(256), 0, stream>>>(x, zT);
    zcopy_k<<<dim3(6624), dim3(256), 0, stream>>>((const short*)hnT, zT);

    // 12. diffusion orders 1..3
    if (fast) {
        diff_k<1><<<dim3(3, 2, 256), dim3(256), 0, stream>>>(adj, adjb, zT, zT, 0, 320);
        diff_k<1><<<dim3(3, 2, 256), dim3(256), 0, stream>>>(adj, adjb, zT, zT, 320, 640);
        diff_k<1><<<dim3(3, 2, 256), dim3(256), 0, stream>>>(adj, adjb, zT, zT, 640, 960);
    } else {
        diff_k<0><<<dim3(3, 2, 256), dim3(256), 0, stream>>>(adj, nullptr, zT, zT, 0, 320);
        diff_k<0><<<dim3(3, 2, 256), dim3(256), 0, stream>>>(adj, nullptr, zT, zT, 320, 640);
        diff_k<0><<<dim3(3, 2, 256), dim3(256), 0, stream>>>(adj, nullptr, zT, zT, 640, 960);
    }

    // 13. fused gates + combine -> out (fp32): flat GEMM M=NB_, N=512 (u/c interleaved)
    if (fast)
        gemm_pipe<1><<<dim3(2, 208), dim3(512), 0, stream>>>(
            zT, KC_, wuc, KC_, nullptr,
            nullptr, 0, KC_, 0, nullptr, b_u, b_c, hnT, out);
    else
        gates_k0<<<dim3(4, 2, 256), dim3(256), 0, stream>>>(
            zT, W_u, W_c, b_u, b_c, hnT, out);

    (void)in_sizes; (void)n_in; (void)out_size; (void)ws_size;
}

// Round 8
// 765.737 us; speedup vs baseline: 1.0821x; 1.0821x over previous
//
#include <hip/hip_runtime.h>
#include <hip/hip_bf16.h>

typedef __hip_bfloat16 bf16;
typedef __attribute__((ext_vector_type(8))) short s8v;   // 8 bf16 in 4 VGPRs
typedef __attribute__((ext_vector_type(4))) short s4v;   // 4 bf16 in 2 VGPRs
typedef __attribute__((ext_vector_type(4))) float f4v;   // mfma accumulator

#define MFMA(a, b, c) __builtin_amdgcn_mfma_f32_16x16x32_bf16(a, b, c, 0, 0, 0)

#define B_    256
#define DIN_  64
#define NU_   256
#define NN_   207
#define KC_   1280
#define NB_   (NN_ * B_)       // 52992 transformer rows; 52992 = 414*128
#define NBD_  13565952LL       // NB_ * 256 elements (one ws region)

// bf16 weight scratch layout (shorts), appended after the 6 proven regions
#define WU_OFF   0LL           // Wu rows 0..255   } contiguous => WUC[512][1280]
#define WC_OFF   327680LL      // Wc rows 256..511 }
#define IP_OFF   655360LL
#define OP_OFF   851968LL
#define F1_OFF   917504LL
#define F2_OFF   983040LL
#define ADJ_OFF  1048576LL     // adj padded to [207][256], zeros in pad
#define WEXT_N   (ADJ_OFF + 207LL * 256LL)   // 1101568 shorts

__device__ __forceinline__ float bf2f(bf16 v) { return __bfloat162float(v); }
__device__ __forceinline__ bf16  f2bf(float v) { return __float2bfloat16(v); }
__device__ __forceinline__ short f2s(float v) { bf16 t = __float2bfloat16(v); return *(short*)&t; }

// direct global->LDS DMA, 16B per lane; lds dest must be wave-uniform
__device__ __forceinline__ void gl16(const void* g, void* l) {
    __builtin_amdgcn_global_load_lds(
        (const __attribute__((address_space(1))) void*)g,
        (__attribute__((address_space(3))) void*)l, 16, 0, 0);
}

// Swizzled LDS tile layout: tile row stride 64 shorts; 16B chunk c of row r
// lives at position c^(r&7). gl16 writes linearly (lane -> seg*512+lane*16B),
// so the global SOURCE chunk is pre-swizzled with chunk^(lane>>3).
#define SWZ(rr, cb) ((rr) * 64 + ((((cb) + q) ^ ((rr) & 7)) << 3))

// ---------------------------------------------------------------------------
// One-shot fp32 -> bf16 weight conversion into wext.
// ---------------------------------------------------------------------------
__global__ __launch_bounds__(256) void cvt_w_k(
    const float* __restrict__ Wu, const float* __restrict__ Wc,
    const float* __restrict__ ip, const float* __restrict__ op,
    const float* __restrict__ f1, const float* __restrict__ f2,
    const float* __restrict__ adj, short* __restrict__ dst)
{
    long long t = (long long)blockIdx.x * 256 + threadIdx.x;
    long long nt = (long long)gridDim.x * 256;
    for (long long g = t; g < 262144; g += nt) {   // 1048576 elems / 4
        long long e = g * 4;
        const float* src; long long off;
        if (e < WC_OFF)      { src = Wu; off = e; }
        else if (e < IP_OFF) { src = Wc; off = e - WC_OFF; }
        else if (e < OP_OFF) { src = ip; off = e - IP_OFF; }
        else if (e < F1_OFF) { src = op; off = e - OP_OFF; }
        else if (e < F2_OFF) { src = f1; off = e - F1_OFF; }
        else                 { src = f2; off = e - F2_OFF; }
        float4 fv = *(const float4*)(src + off);
        s4v v = {f2s(fv.x), f2s(fv.y), f2s(fv.z), f2s(fv.w)};
        *(s4v*)(dst + e) = v;
    }
    short* adst = dst + ADJ_OFF;
    for (long long g = t; g < 207LL * 256LL; g += nt) {
        int r = (int)(g >> 8), c = (int)(g & 255);
        adst[g] = (c < NN_) ? f2s(adj[r * NN_ + c]) : (short)0;
    }
}

// ---------------------------------------------------------------------------
// m97-structure MFMA GEMM (fast path): 256 thr / 4 waves, tile 128x128,
// BK=64, SINGLE 32 KB LDS buffer, plain stage->sync->compute->sync loop.
// Occupancy ~3 blocks/CU restores inter-block overlap (m97's 874 TF
// mechanism) -- co-resident blocks hide each other's barrier drains.
// XCD-aware remap: grid = (nswz=N/128, 416); m-tiles 414 pad to 416=52x8;
// xcd r = w&7 sweeps all nswz n-tiles of one m-tile -> A-tile L2-resident.
// EPI=0: C = act(A@W^T + bias); vt!=null => cols>=512 transposed to vt.
// EPI=1: gates mode. W = WUC (logical col n -> phys row (n&1)*256+(n>>1));
//        epilogue pairs u/c via shfl_xor(1), combines with hnT -> outF fp32.
// ---------------------------------------------------------------------------
template<int EPI>
__global__ __launch_bounds__(256, 3) void gemm128(
    const short* __restrict__ A, int lda,
    const short* __restrict__ Wb, int ldb,
    const float* __restrict__ bias, bf16* __restrict__ C, int ldc,
    int K, int act, short* __restrict__ vt,
    const float* __restrict__ bu, const float* __restrict__ bc,
    const bf16* __restrict__ hnT, float* __restrict__ outF)
{
    __shared__ __align__(16) short As[128 * 64];
    __shared__ __align__(16) short Bs[128 * 64];
    const int w_ = blockIdx.y * gridDim.x + blockIdx.x;   // dispatch-order id
    const int nswz = gridDim.x;
    const int xr = w_ & 7, sidx = w_ >> 3;
    const int mt = xr + 8 * (sidx / nswz);
    const int nt = sidx % nswz;
    if (mt >= 414) return;                                // idle pad block
    const int m0 = mt * 128, n0 = nt * 128;
    const int tid = threadIdx.x;
    const int lane = tid & 63, wid = tid >> 6;
    const int l15 = lane & 15, q = lane >> 4;
    const int wm = (wid >> 1) * 64, wn = (wid & 1) * 64;
    const int seg_r = lane >> 3;
    const int csw8 = ((lane & 7) ^ seg_r) << 3;
    const int nk = K >> 6;

    // hoisted global pointers (include swizzled chunk); advance by k0
    const short* ap[4];
    const short* bp[4];
#pragma unroll
    for (int i = 0; i < 4; i++) {
        int gm = m0 + (wid * 4 + i) * 8 + seg_r;
        ap[i] = A + (long long)gm * lda + csw8;
        int gn = n0 + (wid * 4 + i) * 8 + seg_r;
        int pr = EPI ? ((gn & 1) * 256 + (gn >> 1)) : gn;
        bp[i] = Wb + (long long)pr * ldb + csw8;
    }

    f4v acc[4][4] = {};

    for (int t = 0; t < nk; ++t) {
        const int k0 = t << 6;
#pragma unroll
        for (int i = 0; i < 4; i++) {
            gl16(ap[i] + k0, &As[(wid * 4 + i) * 512]);
            gl16(bp[i] + k0, &Bs[(wid * 4 + i) * 512]);
        }
        __syncthreads();
#pragma unroll
        for (int ks = 0; ks < 64; ks += 32) {
            const int cb = ks >> 3;
            s8v af[4], bfv[4];
#pragma unroll
            for (int i = 0; i < 4; i++) {
                int rr = wm + i * 16 + l15;
                af[i] = *(const s8v*)&As[SWZ(rr, cb)];
            }
#pragma unroll
            for (int j = 0; j < 4; j++) {
                int rr = wn + j * 16 + l15;
                bfv[j] = *(const s8v*)&Bs[SWZ(rr, cb)];
            }
#pragma unroll
            for (int i = 0; i < 4; i++)
#pragma unroll
                for (int j = 0; j < 4; j++)
                    acc[i][j] = MFMA(af[i], bfv[j], acc[i][j]);
        }
        __syncthreads();
    }

    if (EPI == 0) {
#pragma unroll
        for (int i = 0; i < 4; i++) {
            int mbase = m0 + wm + i * 16 + q * 4;
#pragma unroll
            for (int j = 0; j < 4; j++) {
                int n = n0 + wn + j * 16 + l15;
                float bv = bias ? bias[n] : 0.f;
#pragma unroll
                for (int r = 0; r < 4; r++) {
                    int m = mbase + r;
                    float v = acc[i][j][r] + bv;
                    if (act == 3) v = fmaxf(v, 0.f);
                    if (vt && n >= 512) {
                        int d = n - 512;
                        int bb = m / NN_;
                        int node = m - bb * NN_;
                        vt[((long long)bb * 256 + d) * 208 + node] = f2s(v);
                    } else {
                        C[(long long)m * ldc + n] = f2bf(v);
                    }
                }
            }
        }
    } else {
#pragma unroll
        for (int i = 0; i < 4; i++) {
            int mbase = m0 + wm + i * 16 + q * 4;
#pragma unroll
            for (int j = 0; j < 4; j++) {
                int n = n0 + wn + j * 16 + l15;
                int och = n >> 1;
                float bv = (n & 1) ? bc[och] : bu[och];
#pragma unroll
                for (int r = 0; r < 4; r++) {
                    int m = mbase + r;
                    float pre = acc[i][j][r] + bv;
                    float oth = __shfl_xor(pre, 1);
                    if (!(n & 1)) {
                        float u = 1.f / (1.f + __expf(-pre));
                        float cg = tanhf(oth);
                        float hv = bf2f(hnT[(long long)m * 256 + och]);
                        int bb = m / NN_;
                        int node = m - bb * NN_;
                        outF[((long long)bb * NU_ + och) * NN_ + node] = u * hv + (1.f - u) * cg;
                    }
                }
            }
        }
    }
}

// ---------------------------------------------------------------------------
// Fallback (slow path) GEMM: fp32 weights, reg-staged, 2-buffer.
// ---------------------------------------------------------------------------
__global__ __launch_bounds__(256) void gemm_nk0(
    const short* __restrict__ A, int lda,
    const float* __restrict__ Wf, int ldb,
    const float* __restrict__ bias, bf16* __restrict__ C, int ldc,
    int M, int N, int K, int act, short* __restrict__ vt)
{
    __shared__ __align__(16) short As[2][128 * 64];
    __shared__ __align__(16) short Bs[2][128 * 64];
    const int tid = threadIdx.x;
    const int lane = tid & 63, wid = tid >> 6;
    const int l15 = lane & 15, q = lane >> 4;
    const int wm = (wid >> 1) * 64, wn = (wid & 1) * 64;
    const int m0 = blockIdx.y * 128, n0 = blockIdx.x * 128;

    f4v acc[4][4] = {};
    const int nk = K >> 6;

    auto stage = [&](int k0, int pb) {
#pragma unroll
        for (int i = 0; i < 4; i++) {
            int idx = tid + (i << 8);
            int r = idx >> 3, c = idx & 7;
            int gm = m0 + r, gk = k0 + (c << 3);
            s8v v = {0, 0, 0, 0, 0, 0, 0, 0};
            if (gm < M) v = *(const s8v*)(A + (long long)gm * lda + gk);
            *(s8v*)&As[pb][r * 64 + ((c ^ (r & 7)) << 3)] = v;
        }
#pragma unroll
        for (int i = 0; i < 8; i++) {
            int idx = tid + (i << 8);
            int r = idx >> 4, c4 = idx & 15;
            int gn = n0 + r, gk = k0 + (c4 << 2);
            s4v v = {0, 0, 0, 0};
            if (gn < N) {
                float4 fx = *(const float4*)(Wf + (long long)gn * ldb + gk);
                v[0] = f2s(fx.x); v[1] = f2s(fx.y); v[2] = f2s(fx.z); v[3] = f2s(fx.w);
            }
            *(s4v*)&Bs[pb][r * 64 + (((c4 >> 1) ^ (r & 7)) << 3) + ((c4 & 1) << 2)] = v;
        }
    };

    stage(0, 0);
    __syncthreads();
    int pp = 0;
    for (int t = 0; t < nk; ++t) {
        if (t + 1 < nk) stage((t + 1) << 6, pp ^ 1);
#pragma unroll
        for (int ks = 0; ks < 64; ks += 32) {
            const int cb = ks >> 3;
            s8v af[4], bfv[4];
#pragma unroll
            for (int i = 0; i < 4; i++) {
                int rr = wm + i * 16 + l15;
                af[i] = *(const s8v*)&As[pp][SWZ(rr, cb)];
            }
#pragma unroll
            for (int j = 0; j < 4; j++) {
                int rr = wn + j * 16 + l15;
                bfv[j] = *(const s8v*)&Bs[pp][SWZ(rr, cb)];
            }
#pragma unroll
            for (int i = 0; i < 4; i++)
#pragma unroll
                for (int j = 0; j < 4; j++)
                    acc[i][j] = MFMA(af[i], bfv[j], acc[i][j]);
        }
        __syncthreads();
        pp ^= 1;
    }

#pragma unroll
    for (int i = 0; i < 4; i++) {
        int mbase = m0 + wm + i * 16 + q * 4;
#pragma unroll
        for (int j = 0; j < 4; j++) {
            int n = n0 + wn + j * 16 + l15;
            if (n >= N) continue;
            float bv = bias ? bias[n] : 0.f;
#pragma unroll
            for (int r = 0; r < 4; r++) {
                int m = mbase + r;
                if (m >= M) continue;
                float v = acc[i][j][r] + bv;
                if (act == 3) v = fmaxf(v, 0.f);
                if (vt && n >= 512) {
                    int d = n - 512;
                    int bb = m / NN_;
                    int node = m - bb * NN_;
                    vt[((long long)bb * 256 + d) * 208 + node] = f2s(v);
                } else {
                    C[(long long)m * ldc + n] = f2bf(v);
                }
            }
        }
    }
}

// ---------------------------------------------------------------------------
// MFMA attention, one block per (64-q tile, b). 4 waves, each owns 16 q.
// XCD swizzle: grid(4,256)=1024=8*128 exactly; same-b q-tiles co-locate.
// ---------------------------------------------------------------------------
__global__ __launch_bounds__(256) void attn_k(
    const short* __restrict__ qk, const short* __restrict__ vt,
    bf16* __restrict__ ao)
{
    __shared__ __align__(16) short Plds[64 * 232];
    __shared__ float sums[64];
    const int tid = threadIdx.x;
    const int lane = tid & 63, w = tid >> 6;
    const int l15 = lane & 15, quad = lane >> 4;
    const int w_ = blockIdx.y * gridDim.x + blockIdx.x;
    const int xr = w_ & 7, sidx = w_ >> 3;
    const int b = xr + 8 * (sidx >> 2);
    const int q0 = (sidx & 3) * 64;
    const long long rowcap = (long long)NB_ - 1;

    long long qrow = (long long)b * NN_ + q0 + w * 16 + l15;
    if (qrow > rowcap) qrow = rowcap;
    const short* qp = qk + qrow * 512;
    s8v bq[8];
#pragma unroll
    for (int ks = 0; ks < 8; ks++)
        bq[ks] = *(const s8v*)(qp + ks * 32 + quad * 8);

    const short* jp[13];
#pragma unroll
    for (int jf = 0; jf < 13; jf++) {
        long long jrow = (long long)b * NN_ + jf * 16 + l15;
        if (jrow > rowcap) jrow = rowcap;
        jp[jf] = qk + jrow * 512 + 256;
    }

    f4v sacc[13] = {};
#pragma unroll
    for (int ks = 0; ks < 8; ks++) {
        const int off = ks * 32 + quad * 8;
#pragma unroll
        for (int jf = 0; jf < 13; jf++) {
            s8v a = *(const s8v*)(jp[jf] + off);
            sacc[jf] = MFMA(a, bq[ks], sacc[jf]);
        }
    }

    float mx = -3.0e38f;
    float pv[13][4];
#pragma unroll
    for (int jf = 0; jf < 13; jf++)
#pragma unroll
        for (int r = 0; r < 4; r++) {
            int j = jf * 16 + quad * 4 + r;
            float v = (j < NN_) ? sacc[jf][r] * 0.0625f : -3.0e38f;
            pv[jf][r] = v;
            mx = fmaxf(mx, v);
        }
    mx = fmaxf(mx, __shfl_xor(mx, 16));
    mx = fmaxf(mx, __shfl_xor(mx, 32));
    float sum = 0.f;
#pragma unroll
    for (int jf = 0; jf < 13; jf++)
#pragma unroll
        for (int r = 0; r < 4; r++) {
            float p = __expf(pv[jf][r] - mx);
            pv[jf][r] = p;
            sum += p;
        }
    sum += __shfl_xor(sum, 16);
    sum += __shfl_xor(sum, 32);

    const int qloc = w * 16 + l15;
#pragma unroll
    for (int jf = 0; jf < 13; jf++)
#pragma unroll
        for (int r = 0; r < 4; r++)
            Plds[qloc * 232 + jf * 16 + quad * 4 + r] = f2s(pv[jf][r]);
    if (quad == 0) sums[qloc] = 1.f / sum;
#pragma unroll
    for (int i = 0; i < 4; i++) {               // zero pad cols 208..223
        int u = tid + i * 256;
        Plds[(u >> 4) * 232 + 208 + (u & 15)] = 0;
    }
    __syncthreads();

    const short* vbase = vt + (long long)b * 256 * 208;
    f4v oacc[16] = {};
#pragma unroll
    for (int ks = 0; ks < 7; ks++) {
        s8v pa = *(const s8v*)&Plds[(w * 16 + l15) * 232 + ks * 32 + quad * 8];
#pragma unroll
        for (int df = 0; df < 16; df++) {
            s8v vb = *(const s8v*)(vbase + (df * 16 + l15) * 208 + ks * 32 + quad * 8);
            oacc[df] = MFMA(pa, vb, oacc[df]);
        }
    }

#pragma unroll
    for (int df = 0; df < 16; df++) {
        int d = df * 16 + l15;
#pragma unroll
        for (int r = 0; r < 4; r++) {
            int ql = w * 16 + quad * 4 + r;
            int qg = q0 + ql;
            if (qg < NN_)
                ao[((long long)b * NN_ + qg) * 256 + d] = f2bf(oacc[df][r] * sums[ql]);
        }
    }
}

// ---------------------------------------------------------------------------
// Diffusion step in (b, node, chan) layout, batched over b.
// WB=1: adjb via global_load_lds (clamped rows); zT B-side reg-staged with
// async split (load regs early, ds_write after compute). Double-buffered.
// ---------------------------------------------------------------------------
template<int WB>
__global__ __launch_bounds__(256) void diff_k(
    const float* __restrict__ adj, const short* __restrict__ adjb,
    const short* __restrict__ zT_in,
    short* __restrict__ zT_out, int col_in, int col_out)
{
    __shared__ __align__(16) short As[2][128 * 64];
    __shared__ __align__(16) short Bs[2][128 * 64];
    const int tid = threadIdx.x;
    const int lane = tid & 63, wid = tid >> 6;
    const int l15 = lane & 15, q = lane >> 4;
    const int wm = (wid >> 1) * 64, wn = (wid & 1) * 64;
    const int m0 = blockIdx.y * 128, n0 = blockIdx.x * 128;
    const long long zb = (long long)blockIdx.z * NN_ * KC_;
    const int seg_r = lane >> 3, chunk = lane & 7;
    const int csw8 = (chunk ^ seg_r) << 3;
    const int bv_ = tid & 63, bcg = tid >> 6;   // B-stage coords

    f4v acc[4][4] = {};

    auto stageA = [&](int k0, int pb) {
        if (WB) {
#pragma unroll
            for (int i = 0; i < 4; i++) {
                int seg = wid * 4 + i;
                int gm = m0 + seg * 8 + seg_r;
                if (gm > NN_ - 1) gm = NN_ - 1;
                gl16(adjb + gm * 256 + k0 + csw8, &As[pb][seg * 512]);
            }
        } else {
#pragma unroll
            for (int i = 0; i < 32; i++) {
                int idx = tid + (i << 8);
                int r = idx >> 6, c = idx & 63;
                int gm = m0 + r, gk = k0 + c;
                short vv = (gm < NN_ && gk < NN_) ? f2s(adj[gm * NN_ + gk]) : (short)0;
                As[pb][r * 64 + (((c >> 3) ^ (r & 7)) << 3) + (c & 7)] = vv;
            }
        }
    };
    auto loadB = [&](int k0, s8v* breg) {
#pragma unroll
        for (int i = 0; i < 4; i++) {
            int gv = k0 + bv_, gc = n0 + (bcg + i * 4) * 8;
            s8v val = {0, 0, 0, 0, 0, 0, 0, 0};
            if (gv < NN_ && gc < 320)
                val = *(const s8v*)&zT_in[zb + (long long)gv * KC_ + col_in + gc];
            breg[i] = val;
        }
    };
    auto writeB = [&](s8v* breg, int pb) {
#pragma unroll
        for (int i = 0; i < 4; i++) {
            int cg = bcg + i * 4;
#pragma unroll
            for (int e = 0; e < 8; e++) {
                int row = cg * 8 + e;
                Bs[pb][row * 64 + (((bv_ >> 3) ^ (row & 7)) << 3) + (bv_ & 7)] = breg[i][e];
            }
        }
    };

    s8v breg[4];
    loadB(0, breg);
    stageA(0, 0);
    writeB(breg, 0);
    __syncthreads();
    int pp = 0;
    for (int t = 0; t < 4; ++t) {               // ceil(207/64) K-steps
        if (t < 3) { loadB((t + 1) << 6, breg); stageA((t + 1) << 6, pp ^ 1); }
#pragma unroll
        for (int ks = 0; ks < 64; ks += 32) {
            const int cb = ks >> 3;
            s8v af[4], bfv[4];
#pragma unroll
            for (int i = 0; i < 4; i++) {
                int rr = wm + i * 16 + l15;
                af[i] = *(const s8v*)&As[pp][SWZ(rr, cb)];
            }
#pragma unroll
            for (int j = 0; j < 4; j++) {
                int rr = wn + j * 16 + l15;
                bfv[j] = *(const s8v*)&Bs[pp][SWZ(rr, cb)];
            }
#pragma unroll
            for (int i = 0; i < 4; i++)
#pragma unroll
                for (int j = 0; j < 4; j++)
                    acc[i][j] = MFMA(af[i], bfv[j], acc[i][j]);
        }
        if (t < 3) writeB(breg, pp ^ 1);
        __syncthreads();
        pp ^= 1;
    }

#pragma unroll
    for (int i = 0; i < 4; i++) {
        int mbase = m0 + wm + i * 16 + q * 4;
#pragma unroll
        for (int j = 0; j < 4; j++) {
            int n = n0 + wn + j * 16 + l15;
            if (n >= 320) continue;
#pragma unroll
            for (int r = 0; r < 4; r++) {
                int m = mbase + r;
                if (m >= NN_) continue;
                zT_out[zb + (long long)m * KC_ + col_out + n] = f2s(acc[i][j][r]);
            }
        }
    }
}

// ---------------------------------------------------------------------------
// Fallback gates (slow path, fp32 weights).
// ---------------------------------------------------------------------------
__global__ __launch_bounds__(256) void gates_k0(
    const short* __restrict__ zT, const float* __restrict__ Wu,
    const float* __restrict__ Wc, const float* __restrict__ bu,
    const float* __restrict__ bc, const bf16* __restrict__ hnT,
    float* __restrict__ out)
{
    __shared__ __align__(16) short As[2][128 * 64];
    __shared__ __align__(16) short Bu[2][64 * 64];
    __shared__ __align__(16) short Bc[2][64 * 64];
    const int tid = threadIdx.x;
    const int lane = tid & 63, wid = tid >> 6;
    const int l15 = lane & 15, q = lane >> 4;
    const int b = blockIdx.z;
    const int m0 = blockIdx.y * 128;
    const int n0 = blockIdx.x * 64;
    const long long zb = (long long)b * NN_ * KC_;

    f4v aU[2][4] = {}, aC[2][4] = {};

    auto stage = [&](int k0, int pb) {
#pragma unroll
        for (int i = 0; i < 4; i++) {
            int idx = tid + (i << 8);
            int r = idx >> 3, c = idx & 7;
            int gw = m0 + r;
            s8v v = {0, 0, 0, 0, 0, 0, 0, 0};
            if (gw < NN_) v = *(const s8v*)&zT[zb + (long long)gw * KC_ + k0 + (c << 3)];
            *(s8v*)&As[pb][r * 64 + ((c ^ (r & 7)) << 3)] = v;
        }
#pragma unroll
        for (int i = 0; i < 4; i++) {
            int idx = tid + (i << 8);
            int r = idx >> 4, c4 = idx & 15;
            long long widx = (long long)(n0 + r) * KC_ + k0 + (c4 << 2);
            float4 fu = *(const float4*)(Wu + widx);
            float4 fc = *(const float4*)(Wc + widx);
            s4v vu = {f2s(fu.x), f2s(fu.y), f2s(fu.z), f2s(fu.w)};
            s4v vc = {f2s(fc.x), f2s(fc.y), f2s(fc.z), f2s(fc.w)};
            int di = r * 64 + (((c4 >> 1) ^ (r & 7)) << 3) + ((c4 & 1) << 2);
            *(s4v*)&Bu[pb][di] = vu;
            *(s4v*)&Bc[pb][di] = vc;
        }
    };

    stage(0, 0);
    __syncthreads();
    int pp = 0;
    for (int t = 0; t < 20; ++t) {
        if (t < 19) stage((t + 1) << 6, pp ^ 1);
#pragma unroll
        for (int ks = 0; ks < 64; ks += 32) {
            const int cb = ks >> 3;
            s8v af[2], bfu[4], bfc[4];
#pragma unroll
            for (int i = 0; i < 2; i++) {
                int rr = wid * 32 + i * 16 + l15;
                af[i] = *(const s8v*)&As[pp][SWZ(rr, cb)];
            }
#pragma unroll
            for (int j = 0; j < 4; j++) {
                int rr = j * 16 + l15;
                bfu[j] = *(const s8v*)&Bu[pp][SWZ(rr, cb)];
                bfc[j] = *(const s8v*)&Bc[pp][SWZ(rr, cb)];
            }
#pragma unroll
            for (int i = 0; i < 2; i++)
#pragma unroll
                for (int j = 0; j < 4; j++) {
                    aU[i][j] = MFMA(af[i], bfu[j], aU[i][j]);
                    aC[i][j] = MFMA(af[i], bfc[j], aC[i][j]);
                }
        }
        __syncthreads();
        pp ^= 1;
    }

#pragma unroll
    for (int i = 0; i < 2; i++) {
        int wbase = m0 + wid * 32 + i * 16 + q * 4;
#pragma unroll
        for (int j = 0; j < 4; j++) {
            int och = n0 + j * 16 + l15;
            float bvu = bu[och];
            float bvc = bc[och];
#pragma unroll
            for (int r = 0; r < 4; r++) {
                int w = wbase + r;
                if (w >= NN_) continue;
                float u = 1.f / (1.f + __expf(-(aU[i][j][r] + bvu)));
                float cg = tanhf(aC[i][j][r] + bvc);
                float hv = bf2f(hnT[((long long)b * NN_ + w) * 256 + och]);
                out[((long long)b * NU_ + och) * NN_ + w] = u * hv + (1.f - u) * cg;
            }
        }
    }
}

// inp[(b,n),c] = h[b,c,n] + embed[n,c] * mlt[b,n]  (32x32 LDS transpose of h)
__global__ __launch_bounds__(256) void build_inp_k(
    const float* __restrict__ h, const float* __restrict__ embed,
    const float* __restrict__ mlt, bf16* __restrict__ inp)
{
    __shared__ float t[32][33];
    const int b = blockIdx.z;
    const int n0 = blockIdx.x * 32, c0 = blockIdx.y * 32;
    const int t5 = threadIdx.x & 31, t8 = threadIdx.x >> 5;
#pragma unroll
    for (int r = 0; r < 4; r++) {
        int c = c0 + t8 + r * 8;
        int n = n0 + t5;
        t[t8 + r * 8][t5] = (n < NN_) ? h[((long long)b * 256 + c) * NN_ + n] : 0.f;
    }
    __syncthreads();
#pragma unroll
    for (int r = 0; r < 4; r++) {
        int n = n0 + t8 + r * 8;
        int c = c0 + t5;
        if (n < NN_) {
            float v = t[t5][t8 + r * 8] + embed[n * 256 + c] * mlt[b * NN_ + n];
            inp[((long long)b * NN_ + n) * 256 + c] = f2bf(v);
        }
    }
}

// out = LN(x + y) (optional tanh). One wave per 256-elem row, no barriers.
__global__ __launch_bounds__(256) void add_ln_k(
    const bf16* __restrict__ xr, const bf16* __restrict__ yr,
    const float* __restrict__ w, const float* __restrict__ bb,
    bf16* __restrict__ out, int do_tanh)
{
    const int lane = threadIdx.x & 63, wv = threadIdx.x >> 6;
    const long long row = (long long)blockIdx.x * 4 + wv;
    const long long base = row * 256 + lane * 4;
    s4v xv = *(const s4v*)((const short*)xr + base);
    s4v yv = *(const s4v*)((const short*)yr + base);
    float v[4];
    float sum = 0.f;
#pragma unroll
    for (int i = 0; i < 4; i++) {
        short sx = xv[i], sy = yv[i];
        v[i] = bf2f(*(bf16*)&sx) + bf2f(*(bf16*)&sy);
        sum += v[i];
    }
#pragma unroll
    for (int s = 1; s < 64; s <<= 1) sum += __shfl_xor(sum, s);
    float mu = sum * (1.f / 256.f);
    float vs = 0.f;
#pragma unroll
    for (int i = 0; i < 4; i++) { float d = v[i] - mu; vs += d * d; }
#pragma unroll
    for (int s = 1; s < 64; s <<= 1) vs += __shfl_xor(vs, s);
    float inv = rsqrtf(vs * (1.f / 256.f) + 1e-5f);
    s4v ov;
#pragma unroll
    for (int i = 0; i < 4; i++) {
        float r = (v[i] - mu) * inv * w[lane * 4 + i] + bb[lane * 4 + i];
        if (do_tanh) r = tanhf(r);
        ov[i] = f2s(r);
    }
    *(s4v*)((short*)out + base) = ov;
}

// hnT[(b,n),c] = step ? sqrt(1-dt)*h[b,c,n] - sqrt(dt)*eps[(b,n),c] : h[b,c,n]
__global__ __launch_bounds__(256) void hnew_k(
    const float* __restrict__ h, const bf16* __restrict__ epsb,
    const float* __restrict__ dt, const int* __restrict__ step, bf16* __restrict__ hnT)
{
    __shared__ float t[32][33];
    const int b = blockIdx.z;
    const int n0 = blockIdx.x * 32, c0 = blockIdx.y * 32;
    const int t5 = threadIdx.x & 31, t8 = threadIdx.x >> 5;
#pragma unroll
    for (int r = 0; r < 4; r++) {
        int c = c0 + t8 + r * 8;
        int n = n0 + t5;
        t[t8 + r * 8][t5] = (n < NN_) ? h[((long long)b * 256 + c) * NN_ + n] : 0.f;
    }
    __syncthreads();
    const int st = *step;
    const float d = dt[b];
    const float sa = sqrtf(fmaxf(1.f - d, 0.f)), sb = sqrtf(d);
#pragma unroll
    for (int r = 0; r < 4; r++) {
        int n = n0 + t8 + r * 8;
        int c = c0 + t5;
        if (n < NN_) {
            float hv = t[t5][t8 + r * 8];
            float val = hv;
            if (st != 0) {
                float ev = bf2f(epsb[((long long)b * NN_ + n) * 256 + c]);
                val = sa * hv - sb * ev;
            }
            hnT[((long long)b * NN_ + n) * 256 + c] = f2bf(val);
        }
    }
}

// zT[(b,n), c] = x[b,c,n] for c < 64 (transpose)
__global__ __launch_bounds__(256) void zx_k(
    const float* __restrict__ x, short* __restrict__ zT)
{
    __shared__ float t[32][33];
    const int b = blockIdx.z;
    const int n0 = blockIdx.x * 32, c0 = blockIdx.y * 32;
    const int t5 = threadIdx.x & 31, t8 = threadIdx.x >> 5;
#pragma unroll
    for (int r = 0; r < 4; r++) {
        int c = c0 + t8 + r * 8;
        int n = n0 + t5;
        t[t8 + r * 8][t5] = (n < NN_) ? x[((long long)b * DIN_ + c) * NN_ + n] : 0.f;
    }
    __syncthreads();
#pragma unroll
    for (int r = 0; r < 4; r++) {
        int n = n0 + t8 + r * 8;
        int c = c0 + t5;
        if (n < NN_)
            zT[((long long)b * NN_ + n) * KC_ + c] = f2s(t[t5][t8 + r * 8]);
    }
}

// zT[(b,n), 64+c] = hnT[(b,n), c]  (vectorized copy)
__global__ __launch_bounds__(256) void zcopy_k(
    const short* __restrict__ hnT, short* __restrict__ zT)
{
    long long u = (long long)blockIdx.x * 256 + threadIdx.x;  // < NB_*32
    long long row = u >> 5;
    int cu = (int)(u & 31);
    s8v v = *(const s8v*)(hnT + row * 256 + cu * 8);
    *(s8v*)(zT + row * KC_ + 64 + cu * 8) = v;
}

extern "C" void kernel_launch(void* const* d_in, const int* in_sizes, int n_in,
                              void* d_out, int out_size, void* d_ws, size_t ws_size,
                              hipStream_t stream) {
    const float* x          = (const float*)d_in[0];
    const float* delta_t    = (const float*)d_in[1];
    const float* h          = (const float*)d_in[2];
    const float* adj        = (const float*)d_in[3];
    const float* mlt        = (const float*)d_in[5];
    const int*  step        = (const int*)d_in[7];
    const float* embed      = (const float*)d_in[8];
    const float* in_proj_w  = (const float*)d_in[9];
    const float* in_proj_b  = (const float*)d_in[10];
    const float* out_proj_w = (const float*)d_in[11];
    const float* out_proj_b = (const float*)d_in[12];
    const float* ln1_w      = (const float*)d_in[13];
    const float* ln1_b      = (const float*)d_in[14];
    const float* ln2_w      = (const float*)d_in[15];
    const float* ln2_b      = (const float*)d_in[16];
    const float* ffn_w1     = (const float*)d_in[17];
    const float* ffn_b1     = (const float*)d_in[18];
    const float* ffn_w2     = (const float*)d_in[19];
    const float* ffn_b2     = (const float*)d_in[20];
    const float* W_u        = (const float*)d_in[21];
    const float* b_u        = (const float*)d_in[22];
    const float* W_c        = (const float*)d_in[23];
    const float* b_c        = (const float*)d_in[24];
    float* out = (float*)d_out;
    bf16* ws   = (bf16*)d_ws;

    bf16* inp = ws;
    short* qk = (short*)(ws + 1 * NBD_);
    short* vt = (short*)(ws + 3 * NBD_);
    bf16* ao  = ws + 4 * NBD_ + 65536;
    bf16* o   = ws + 1 * NBD_;
    bf16* s   = ws + 2 * NBD_;
    bf16* f   = ws + 1 * NBD_;
    bf16* f2  = ws + 3 * NBD_;
    bf16* eps = ws + 2 * NBD_;
    bf16* hnT = ws;
    short* zT = (short*)(ws + 1 * NBD_);
    short* wext = (short*)(ws + 6 * NBD_);

    const size_t need = (size_t)(6 * NBD_ + WEXT_N) * 2;
    const bool fast = ws_size >= need;   // capture-time host decision

    short* wuc  = wext + WU_OFF;         // [512][1280]: rows 0..255 Wu, 256..511 Wc
    short* ipb  = wext + IP_OFF;
    short* opb  = wext + OP_OFF;
    short* f1b  = wext + F1_OFF;
    short* f2b  = wext + F2_OFF;
    short* adjb = wext + ADJ_OFF;

    // 0. one-shot fp32 -> bf16 weight conversion
    if (fast)
        cvt_w_k<<<dim3(1024), dim3(256), 0, stream>>>(
            W_u, W_c, in_proj_w, out_proj_w, ffn_w1, ffn_w2, adj, wext);

    // 1. inp = h^T + embed * mlt   ((b,n) rows)
    build_inp_k<<<dim3(7, 8, 256), dim3(256), 0, stream>>>(h, embed, mlt, inp);

    // 2. qkv GEMM: Q,K -> qk rows (512); V -> vt transposed
    if (fast)
        gemm128<0><<<dim3(6, 416), dim3(256), 0, stream>>>(
            (const short*)inp, 256, ipb, 256, in_proj_b,
            (bf16*)qk, 512, 256, 0, vt, nullptr, nullptr, nullptr, nullptr);
    else
        gemm_nk0<<<dim3(6, 414), dim3(256), 0, stream>>>(
            (const short*)inp, 256, in_proj_w, 256, in_proj_b,
            (bf16*)qk, 512, NB_, 768, 256, 0, vt);

    // 3. MFMA attention (XCD-swizzled internally)
    attn_k<<<dim3(4, 256), dim3(256), 0, stream>>>(qk, vt, ao);

    // 4. o = ao @ out_proj^T + b
    if (fast)
        gemm128<0><<<dim3(2, 416), dim3(256), 0, stream>>>(
            (const short*)ao, 256, opb, 256, out_proj_b,
            o, 256, 256, 0, nullptr, nullptr, nullptr, nullptr, nullptr);
    else
        gemm_nk0<<<dim3(2, 414), dim3(256), 0, stream>>>(
            (const short*)ao, 256, out_proj_w, 256, out_proj_b, o, 256, NB_, 256, 256, 0, nullptr);

    // 5. s = LN1(inp + o)
    add_ln_k<<<dim3(NB_ / 4), dim3(256), 0, stream>>>(inp, o, ln1_w, ln1_b, s, 0);

    // 6. f = relu(s @ ffn_w1^T + b)
    if (fast)
        gemm128<0><<<dim3(2, 416), dim3(256), 0, stream>>>(
            (const short*)s, 256, f1b, 256, ffn_b1,
            f, 256, 256, 3, nullptr, nullptr, nullptr, nullptr, nullptr);
    else
        gemm_nk0<<<dim3(2, 414), dim3(256), 0, stream>>>(
            (const short*)s, 256, ffn_w1, 256, ffn_b1, f, 256, NB_, 256, 256, 3, nullptr);

    // 7. f2 = f @ ffn_w2^T + b
    if (fast)
        gemm128<0><<<dim3(2, 416), dim3(256), 0, stream>>>(
            (const short*)f, 256, f2b, 256, ffn_b2,
            f2, 256, 256, 0, nullptr, nullptr, nullptr, nullptr, nullptr);
    else
        gemm_nk0<<<dim3(2, 414), dim3(256), 0, stream>>>(
            (const short*)f, 256, ffn_w2, 256, ffn_b2, f2, 256, NB_, 256, 256, 0, nullptr);

    // 8. eps = tanh(LN2(s + f2))   (in-place over s)
    add_ln_k<<<dim3(NB_ / 4), dim3(256), 0, stream>>>(s, f2, ln2_w, ln2_b, eps, 1);

    // 9. hnT = step ? sqrt(1-dt)*h - sqrt(dt)*eps : h   ((b,n,c) layout)
    hnew_k<<<dim3(7, 8, 256), dim3(256), 0, stream>>>(h, eps, delta_t, step, hnT);

    // 10. zT cols 0..63 = x^T; 11. cols 64..319 = hnT
    zx_k<<<dim3(7, 2, 256), dim3(256), 0, stream>>>(x, zT);
    zcopy_k<<<dim3(6624), dim3(256), 0, stream>>>((const short*)hnT, zT);

    // 12. diffusion orders 1..3
    if (fast) {
        diff_k<1><<<dim3(3, 2, 256), dim3(256), 0, stream>>>(adj, adjb, zT, zT, 0, 320);
        diff_k<1><<<dim3(3, 2, 256), dim3(256), 0, stream>>>(adj, adjb, zT, zT, 320, 640);
        diff_k<1><<<dim3(3, 2, 256), dim3(256), 0, stream>>>(adj, adjb, zT, zT, 640, 960);
    } else {
        diff_k<0><<<dim3(3, 2, 256), dim3(256), 0, stream>>>(adj, nullptr, zT, zT, 0, 320);
        diff_k<0><<<dim3(3, 2, 256), dim3(256), 0, stream>>>(adj, nullptr, zT, zT, 320, 640);
        diff_k<0><<<dim3(3, 2, 256), dim3(256), 0, stream>>>(adj, nullptr, zT, zT, 640, 960);
    }

    // 13. fused gates + combine -> out (fp32): flat GEMM M=NB_, N=512 (u/c interleaved)
    if (fast)
        gemm128<1><<<dim3(4, 416), dim3(256), 0, stream>>>(
            zT, KC_, wuc, KC_, nullptr,
            nullptr, 0, KC_, 0, nullptr, b_u, b_c, hnT, out);
    else
        gates_k0<<<dim3(4, 2, 256), dim3(256), 0, stream>>>(
            zT, W_u, W_c, b_u, b_c, hnT, out);

    (void)in_sizes; (void)n_in; (void)out_size; (void)ws_size;
}

// Round 9
// 710.055 us; speedup vs baseline: 1.1670x; 1.0784x over previous
//
#include <hip/hip_runtime.h>
#include <hip/hip_bf16.h>

typedef __hip_bfloat16 bf16;
typedef __attribute__((ext_vector_type(8))) short s8v;   // 8 bf16 in 4 VGPRs
typedef __attribute__((ext_vector_type(4))) short s4v;   // 4 bf16 in 2 VGPRs
typedef __attribute__((ext_vector_type(4))) float f4v;   // mfma accumulator

#define MFMA(a, b, c) __builtin_amdgcn_mfma_f32_16x16x32_bf16(a, b, c, 0, 0, 0)

#define B_    256
#define DIN_  64
#define NU_   256
#define NN_   207
#define KC_   1280
#define NB_   (NN_ * B_)       // 52992 transformer rows; 52992 = 414*128
#define NBD_  13565952LL       // NB_ * 256 elements (one ws region)

// bf16 weight scratch layout (shorts), appended after the 6 proven regions
#define WU_OFF   0LL           // Wu rows 0..255   } contiguous => WUC[512][1280]
#define WC_OFF   327680LL      // Wc rows 256..511 }
#define IP_OFF   655360LL
#define OP_OFF   851968LL
#define F1_OFF   917504LL
#define F2_OFF   983040LL
#define ADJ_OFF  1048576LL     // adj padded to [207][256], zeros in pad
#define WEXT_N   (ADJ_OFF + 207LL * 256LL)   // 1101568 shorts

__device__ __forceinline__ float bf2f(bf16 v) { return __bfloat162float(v); }
__device__ __forceinline__ bf16  f2bf(float v) { return __float2bfloat16(v); }
__device__ __forceinline__ short f2s(float v) { bf16 t = __float2bfloat16(v); return *(short*)&t; }

// direct global->LDS DMA, 16B per lane; lds dest must be wave-uniform
__device__ __forceinline__ void gl16(const void* g, void* l) {
    __builtin_amdgcn_global_load_lds(
        (const __attribute__((address_space(1))) void*)g,
        (__attribute__((address_space(3))) void*)l, 16, 0, 0);
}

// Swizzled LDS tile layout: tile row stride 64 shorts; 16B chunk c of row r
// lives at position c^(r&7). gl16 writes linearly (lane -> seg*512+lane*16B),
// so the global SOURCE chunk is pre-swizzled with chunk^(lane>>3).
#define SWZ(rr, cb) ((rr) * 64 + ((((cb) + q) ^ ((rr) & 7)) << 3))

// ---------------------------------------------------------------------------
// One-shot fp32 -> bf16 weight conversion into wext.
// ---------------------------------------------------------------------------
__global__ __launch_bounds__(256) void cvt_w_k(
    const float* __restrict__ Wu, const float* __restrict__ Wc,
    const float* __restrict__ ip, const float* __restrict__ op,
    const float* __restrict__ f1, const float* __restrict__ f2,
    const float* __restrict__ adj, short* __restrict__ dst)
{
    long long t = (long long)blockIdx.x * 256 + threadIdx.x;
    long long nt = (long long)gridDim.x * 256;
    for (long long g = t; g < 262144; g += nt) {   // 1048576 elems / 4
        long long e = g * 4;
        const float* src; long long off;
        if (e < WC_OFF)      { src = Wu; off = e; }
        else if (e < IP_OFF) { src = Wc; off = e - WC_OFF; }
        else if (e < OP_OFF) { src = ip; off = e - IP_OFF; }
        else if (e < F1_OFF) { src = op; off = e - OP_OFF; }
        else if (e < F2_OFF) { src = f1; off = e - F1_OFF; }
        else                 { src = f2; off = e - F2_OFF; }
        float4 fv = *(const float4*)(src + off);
        s4v v = {f2s(fv.x), f2s(fv.y), f2s(fv.z), f2s(fv.w)};
        *(s4v*)(dst + e) = v;
    }
    short* adst = dst + ADJ_OFF;
    for (long long g = t; g < 207LL * 256LL; g += nt) {
        int r = (int)(g >> 8), c = (int)(g & 255);
        adst[g] = (c < NN_) ? f2s(adj[r * NN_ + c]) : (short)0;
    }
}

// ---------------------------------------------------------------------------
// m97-structure MFMA GEMM (fast path): 256 thr / 4 waves, tile 128x128,
// BK=64, SINGLE 32 KB LDS buffer, plain stage->sync->compute->sync loop.
// ~3 blocks/CU -> inter-block overlap hides barrier drains (m97 mechanism).
// XCD-aware remap: grid = (nswz, 416); m-tiles 414 pad to 416=52x8.
// EPI=0: C = act(A@W^T + bias); vt!=null => cols>=512 transposed to vt.
// EPI=1: gates mode. W = WUC (logical col n -> phys row (n&1)*256+(n>>1)).
//   Epilogue: odd l15 lanes compute tanh (c-gate), even compute sigmoid
//   (u-gate); shfl_xor(1) pairs them. Result staged in the dead 32KB tile
//   LDS (XOR-swizzled) and written to outF with lane-consecutive node.
// ---------------------------------------------------------------------------
template<int EPI>
__global__ __launch_bounds__(256, 3) void gemm128(
    const short* __restrict__ A, int lda,
    const short* __restrict__ Wb, int ldb,
    const float* __restrict__ bias, bf16* __restrict__ C, int ldc,
    int K, int act, short* __restrict__ vt,
    const float* __restrict__ bu, const float* __restrict__ bc,
    const bf16* __restrict__ hnT, float* __restrict__ outF)
{
    __shared__ __align__(16) short Tiles[2][128 * 64];   // As | Bs ; reused as 32KB fp32 out-stage
    short* As = Tiles[0];
    short* Bs = Tiles[1];
    float* outS = (float*)&Tiles[0][0];                  // 8192 floats = 64 och x 128 m
    const int w_ = blockIdx.y * gridDim.x + blockIdx.x;   // dispatch-order id
    const int nswz = gridDim.x;
    const int xr = w_ & 7, sidx = w_ >> 3;
    const int mt = xr + 8 * (sidx / nswz);
    const int nt = sidx % nswz;
    if (mt >= 414) return;                                // idle pad block
    const int m0 = mt * 128, n0 = nt * 128;
    const int tid = threadIdx.x;
    const int lane = tid & 63, wid = tid >> 6;
    const int l15 = lane & 15, q = lane >> 4;
    const int wm = (wid >> 1) * 64, wn = (wid & 1) * 64;
    const int seg_r = lane >> 3;
    const int csw8 = ((lane & 7) ^ seg_r) << 3;
    const int nk = K >> 6;

    // hoisted global pointers (include swizzled chunk); advance by k0
    const short* ap[4];
    const short* bp[4];
#pragma unroll
    for (int i = 0; i < 4; i++) {
        int gm = m0 + (wid * 4 + i) * 8 + seg_r;
        ap[i] = A + (long long)gm * lda + csw8;
        int gn = n0 + (wid * 4 + i) * 8 + seg_r;
        int pr = EPI ? ((gn & 1) * 256 + (gn >> 1)) : gn;
        bp[i] = Wb + (long long)pr * ldb + csw8;
    }

    f4v acc[4][4] = {};

    for (int t = 0; t < nk; ++t) {
        const int k0 = t << 6;
#pragma unroll
        for (int i = 0; i < 4; i++) {
            gl16(ap[i] + k0, &As[(wid * 4 + i) * 512]);
            gl16(bp[i] + k0, &Bs[(wid * 4 + i) * 512]);
        }
        __syncthreads();
#pragma unroll
        for (int ks = 0; ks < 64; ks += 32) {
            const int cb = ks >> 3;
            s8v af[4], bfv[4];
#pragma unroll
            for (int i = 0; i < 4; i++) {
                int rr = wm + i * 16 + l15;
                af[i] = *(const s8v*)&As[SWZ(rr, cb)];
            }
#pragma unroll
            for (int j = 0; j < 4; j++) {
                int rr = wn + j * 16 + l15;
                bfv[j] = *(const s8v*)&Bs[SWZ(rr, cb)];
            }
#pragma unroll
            for (int i = 0; i < 4; i++)
#pragma unroll
                for (int j = 0; j < 4; j++)
                    acc[i][j] = MFMA(af[i], bfv[j], acc[i][j]);
        }
        __syncthreads();
    }

    if (EPI == 0) {
#pragma unroll
        for (int i = 0; i < 4; i++) {
            int mbase = m0 + wm + i * 16 + q * 4;
#pragma unroll
            for (int j = 0; j < 4; j++) {
                int n = n0 + wn + j * 16 + l15;
                float bv = bias ? bias[n] : 0.f;
#pragma unroll
                for (int r = 0; r < 4; r++) {
                    int m = mbase + r;
                    float v = acc[i][j][r] + bv;
                    if (act == 3) v = fmaxf(v, 0.f);
                    if (vt && n >= 512) {
                        int d = n - 512;
                        int bb = m / NN_;
                        int node = m - bb * NN_;
                        vt[((long long)bb * 256 + d) * 208 + node] = f2s(v);
                    } else {
                        C[(long long)m * ldc + n] = f2bf(v);
                    }
                }
            }
        }
    } else {
        const int odd = l15 & 1;
#pragma unroll
        for (int i = 0; i < 4; i++) {
            int mlbase = wm + i * 16 + q * 4;
#pragma unroll
            for (int j = 0; j < 4; j++) {
                int n = n0 + wn + j * 16 + l15;
                int och = n >> 1;
                int ochl = (wn + j * 16 + l15) >> 1;
                float bv = odd ? bc[och] : bu[och];
#pragma unroll
                for (int r = 0; r < 4; r++) {
                    int ml = mlbase + r;
                    float pre = acc[i][j][r] + bv;
                    float myv;
                    if (odd) {                       // c-gate lane: tanh via exp
                        float e = __expf(2.f * pre);
                        myv = (e - 1.f) / (e + 1.f);
                    } else {                         // u-gate lane: sigmoid
                        myv = 1.f / (1.f + __expf(-pre));
                    }
                    float oth = __shfl_xor(myv, 1);  // even lane <- tanh(c)
                    if (!odd) {
                        int m = m0 + ml;
                        float hv = bf2f(hnT[(long long)m * 256 + och]);
                        float res = myv * hv + (1.f - myv) * oth;
                        outS[ochl * 128 + (ml ^ ((ochl & 7) << 2))] = res;
                    }
                }
            }
        }
        __syncthreads();
        // coalesced out write: wave covers 64 consecutive m per och row
        for (int orow = tid >> 6; orow < 64; orow += 4) {
            int och = (n0 >> 1) + orow;
            const int sx = (orow & 7) << 2;
#pragma unroll
            for (int half = 0; half < 2; half++) {
                int ml = lane + half * 64;
                float v = outS[orow * 128 + (ml ^ sx)];
                int m = m0 + ml;
                int bb = m / NN_;
                int node = m - bb * NN_;
                outF[((long long)bb * NU_ + och) * NN_ + node] = v;
            }
        }
    }
}

// ---------------------------------------------------------------------------
// Fallback (slow path) GEMM: fp32 weights, reg-staged, 2-buffer.
// ---------------------------------------------------------------------------
__global__ __launch_bounds__(256) void gemm_nk0(
    const short* __restrict__ A, int lda,
    const float* __restrict__ Wf, int ldb,
    const float* __restrict__ bias, bf16* __restrict__ C, int ldc,
    int M, int N, int K, int act, short* __restrict__ vt)
{
    __shared__ __align__(16) short As[2][128 * 64];
    __shared__ __align__(16) short Bs[2][128 * 64];
    const int tid = threadIdx.x;
    const int lane = tid & 63, wid = tid >> 6;
    const int l15 = lane & 15, q = lane >> 4;
    const int wm = (wid >> 1) * 64, wn = (wid & 1) * 64;
    const int m0 = blockIdx.y * 128, n0 = blockIdx.x * 128;

    f4v acc[4][4] = {};
    const int nk = K >> 6;

    auto stage = [&](int k0, int pb) {
#pragma unroll
        for (int i = 0; i < 4; i++) {
            int idx = tid + (i << 8);
            int r = idx >> 3, c = idx & 7;
            int gm = m0 + r, gk = k0 + (c << 3);
            s8v v = {0, 0, 0, 0, 0, 0, 0, 0};
            if (gm < M) v = *(const s8v*)(A + (long long)gm * lda + gk);
            *(s8v*)&As[pb][r * 64 + ((c ^ (r & 7)) << 3)] = v;
        }
#pragma unroll
        for (int i = 0; i < 8; i++) {
            int idx = tid + (i << 8);
            int r = idx >> 4, c4 = idx & 15;
            int gn = n0 + r, gk = k0 + (c4 << 2);
            s4v v = {0, 0, 0, 0};
            if (gn < N) {
                float4 fx = *(const float4*)(Wf + (long long)gn * ldb + gk);
                v[0] = f2s(fx.x); v[1] = f2s(fx.y); v[2] = f2s(fx.z); v[3] = f2s(fx.w);
            }
            *(s4v*)&Bs[pb][r * 64 + (((c4 >> 1) ^ (r & 7)) << 3) + ((c4 & 1) << 2)] = v;
        }
    };

    stage(0, 0);
    __syncthreads();
    int pp = 0;
    for (int t = 0; t < nk; ++t) {
        if (t + 1 < nk) stage((t + 1) << 6, pp ^ 1);
#pragma unroll
        for (int ks = 0; ks < 64; ks += 32) {
            const int cb = ks >> 3;
            s8v af[4], bfv[4];
#pragma unroll
            for (int i = 0; i < 4; i++) {
                int rr = wm + i * 16 + l15;
                af[i] = *(const s8v*)&As[pp][SWZ(rr, cb)];
            }
#pragma unroll
            for (int j = 0; j < 4; j++) {
                int rr = wn + j * 16 + l15;
                bfv[j] = *(const s8v*)&Bs[pp][SWZ(rr, cb)];
            }
#pragma unroll
            for (int i = 0; i < 4; i++)
#pragma unroll
                for (int j = 0; j < 4; j++)
                    acc[i][j] = MFMA(af[i], bfv[j], acc[i][j]);
        }
        __syncthreads();
        pp ^= 1;
    }

#pragma unroll
    for (int i = 0; i < 4; i++) {
        int mbase = m0 + wm + i * 16 + q * 4;
#pragma unroll
        for (int j = 0; j < 4; j++) {
            int n = n0 + wn + j * 16 + l15;
            if (n >= N) continue;
            float bv = bias ? bias[n] : 0.f;
#pragma unroll
            for (int r = 0; r < 4; r++) {
                int m = mbase + r;
                if (m >= M) continue;
                float v = acc[i][j][r] + bv;
                if (act == 3) v = fmaxf(v, 0.f);
                if (vt && n >= 512) {
                    int d = n - 512;
                    int bb = m / NN_;
                    int node = m - bb * NN_;
                    vt[((long long)bb * 256 + d) * 208 + node] = f2s(v);
                } else {
                    C[(long long)m * ldc + n] = f2bf(v);
                }
            }
        }
    }
}

// ---------------------------------------------------------------------------
// MFMA attention, one block per (64-q tile, b). 4 waves, each owns 16 q.
// XCD swizzle: grid(4,256)=1024=8*128 exactly; same-b q-tiles co-locate.
// ---------------------------------------------------------------------------
__global__ __launch_bounds__(256) void attn_k(
    const short* __restrict__ qk, const short* __restrict__ vt,
    bf16* __restrict__ ao)
{
    __shared__ __align__(16) short Plds[64 * 232];
    __shared__ float sums[64];
    const int tid = threadIdx.x;
    const int lane = tid & 63, w = tid >> 6;
    const int l15 = lane & 15, quad = lane >> 4;
    const int w_ = blockIdx.y * gridDim.x + blockIdx.x;
    const int xr = w_ & 7, sidx = w_ >> 3;
    const int b = xr + 8 * (sidx >> 2);
    const int q0 = (sidx & 3) * 64;
    const long long rowcap = (long long)NB_ - 1;

    long long qrow = (long long)b * NN_ + q0 + w * 16 + l15;
    if (qrow > rowcap) qrow = rowcap;
    const short* qp = qk + qrow * 512;
    s8v bq[8];
#pragma unroll
    for (int ks = 0; ks < 8; ks++)
        bq[ks] = *(const s8v*)(qp + ks * 32 + quad * 8);

    const short* jp[13];
#pragma unroll
    for (int jf = 0; jf < 13; jf++) {
        long long jrow = (long long)b * NN_ + jf * 16 + l15;
        if (jrow > rowcap) jrow = rowcap;
        jp[jf] = qk + jrow * 512 + 256;
    }

    f4v sacc[13] = {};
#pragma unroll
    for (int ks = 0; ks < 8; ks++) {
        const int off = ks * 32 + quad * 8;
#pragma unroll
        for (int jf = 0; jf < 13; jf++) {
            s8v a = *(const s8v*)(jp[jf] + off);
            sacc[jf] = MFMA(a, bq[ks], sacc[jf]);
        }
    }

    float mx = -3.0e38f;
    float pv[13][4];
#pragma unroll
    for (int jf = 0; jf < 13; jf++)
#pragma unroll
        for (int r = 0; r < 4; r++) {
            int j = jf * 16 + quad * 4 + r;
            float v = (j < NN_) ? sacc[jf][r] * 0.0625f : -3.0e38f;
            pv[jf][r] = v;
            mx = fmaxf(mx, v);
        }
    mx = fmaxf(mx, __shfl_xor(mx, 16));
    mx = fmaxf(mx, __shfl_xor(mx, 32));
    float sum = 0.f;
#pragma unroll
    for (int jf = 0; jf < 13; jf++)
#pragma unroll
        for (int r = 0; r < 4; r++) {
            float p = __expf(pv[jf][r] - mx);
            pv[jf][r] = p;
            sum += p;
        }
    sum += __shfl_xor(sum, 16);
    sum += __shfl_xor(sum, 32);

    const int qloc = w * 16 + l15;
#pragma unroll
    for (int jf = 0; jf < 13; jf++)
#pragma unroll
        for (int r = 0; r < 4; r++)
            Plds[qloc * 232 + jf * 16 + quad * 4 + r] = f2s(pv[jf][r]);
    if (quad == 0) sums[qloc] = 1.f / sum;
#pragma unroll
    for (int i = 0; i < 4; i++) {               // zero pad cols 208..223
        int u = tid + i * 256;
        Plds[(u >> 4) * 232 + 208 + (u & 15)] = 0;
    }
    __syncthreads();

    const short* vbase = vt + (long long)b * 256 * 208;
    f4v oacc[16] = {};
#pragma unroll
    for (int ks = 0; ks < 7; ks++) {
        s8v pa = *(const s8v*)&Plds[(w * 16 + l15) * 232 + ks * 32 + quad * 8];
#pragma unroll
        for (int df = 0; df < 16; df++) {
            s8v vb = *(const s8v*)(vbase + (df * 16 + l15) * 208 + ks * 32 + quad * 8);
            oacc[df] = MFMA(pa, vb, oacc[df]);
        }
    }

#pragma unroll
    for (int df = 0; df < 16; df++) {
        int d = df * 16 + l15;
#pragma unroll
        for (int r = 0; r < 4; r++) {
            int ql = w * 16 + quad * 4 + r;
            int qg = q0 + ql;
            if (qg < NN_)
                ao[((long long)b * NN_ + qg) * 256 + d] = f2bf(oacc[df][r] * sums[ql]);
        }
    }
}

// ---------------------------------------------------------------------------
// Diffusion step in (b, node, chan) layout, batched over b.
// WB=1: adjb via global_load_lds (clamped rows); zT B-side reg-staged with
// async split (load regs early, ds_write after compute). Double-buffered.
// ---------------------------------------------------------------------------
template<int WB>
__global__ __launch_bounds__(256) void diff_k(
    const float* __restrict__ adj, const short* __restrict__ adjb,
    const short* __restrict__ zT_in,
    short* __restrict__ zT_out, int col_in, int col_out)
{
    __shared__ __align__(16) short As[2][128 * 64];
    __shared__ __align__(16) short Bs[2][128 * 64];
    const int tid = threadIdx.x;
    const int lane = tid & 63, wid = tid >> 6;
    const int l15 = lane & 15, q = lane >> 4;
    const int wm = (wid >> 1) * 64, wn = (wid & 1) * 64;
    const int m0 = blockIdx.y * 128, n0 = blockIdx.x * 128;
    const long long zb = (long long)blockIdx.z * NN_ * KC_;
    const int seg_r = lane >> 3, chunk = lane & 7;
    const int csw8 = (chunk ^ seg_r) << 3;
    const int bv_ = tid & 63, bcg = tid >> 6;   // B-stage coords

    f4v acc[4][4] = {};

    auto stageA = [&](int k0, int pb) {
        if (WB) {
#pragma unroll
            for (int i = 0; i < 4; i++) {
                int seg = wid * 4 + i;
                int gm = m0 + seg * 8 + seg_r;
                if (gm > NN_ - 1) gm = NN_ - 1;
                gl16(adjb + gm * 256 + k0 + csw8, &As[pb][seg * 512]);
            }
        } else {
#pragma unroll
            for (int i = 0; i < 32; i++) {
                int idx = tid + (i << 8);
                int r = idx >> 6, c = idx & 63;
                int gm = m0 + r, gk = k0 + c;
                short vv = (gm < NN_ && gk < NN_) ? f2s(adj[gm * NN_ + gk]) : (short)0;
                As[pb][r * 64 + (((c >> 3) ^ (r & 7)) << 3) + (c & 7)] = vv;
            }
        }
    };
    auto loadB = [&](int k0, s8v* breg) {
#pragma unroll
        for (int i = 0; i < 4; i++) {
            int gv = k0 + bv_, gc = n0 + (bcg + i * 4) * 8;
            s8v val = {0, 0, 0, 0, 0, 0, 0, 0};
            if (gv < NN_ && gc < 320)
                val = *(const s8v*)&zT_in[zb + (long long)gv * KC_ + col_in + gc];
            breg[i] = val;
        }
    };
    auto writeB = [&](s8v* breg, int pb) {
#pragma unroll
        for (int i = 0; i < 4; i++) {
            int cg = bcg + i * 4;
#pragma unroll
            for (int e = 0; e < 8; e++) {
                int row = cg * 8 + e;
                Bs[pb][row * 64 + (((bv_ >> 3) ^ (row & 7)) << 3) + (bv_ & 7)] = breg[i][e];
            }
        }
    };

    s8v breg[4];
    loadB(0, breg);
    stageA(0, 0);
    writeB(breg, 0);
    __syncthreads();
    int pp = 0;
    for (int t = 0; t < 4; ++t) {               // ceil(207/64) K-steps
        if (t < 3) { loadB((t + 1) << 6, breg); stageA((t + 1) << 6, pp ^ 1); }
#pragma unroll
        for (int ks = 0; ks < 64; ks += 32) {
            const int cb = ks >> 3;
            s8v af[4], bfv[4];
#pragma unroll
            for (int i = 0; i < 4; i++) {
                int rr = wm + i * 16 + l15;
                af[i] = *(const s8v*)&As[pp][SWZ(rr, cb)];
            }
#pragma unroll
            for (int j = 0; j < 4; j++) {
                int rr = wn + j * 16 + l15;
                bfv[j] = *(const s8v*)&Bs[pp][SWZ(rr, cb)];
            }
#pragma unroll
            for (int i = 0; i < 4; i++)
#pragma unroll
                for (int j = 0; j < 4; j++)
                    acc[i][j] = MFMA(af[i], bfv[j], acc[i][j]);
        }
        if (t < 3) writeB(breg, pp ^ 1);
        __syncthreads();
        pp ^= 1;
    }

#pragma unroll
    for (int i = 0; i < 4; i++) {
        int mbase = m0 + wm + i * 16 + q * 4;
#pragma unroll
        for (int j = 0; j < 4; j++) {
            int n = n0 + wn + j * 16 + l15;
            if (n >= 320) continue;
#pragma unroll
            for (int r = 0; r < 4; r++) {
                int m = mbase + r;
                if (m >= NN_) continue;
                zT_out[zb + (long long)m * KC_ + col_out + n] = f2s(acc[i][j][r]);
            }
        }
    }
}

// ---------------------------------------------------------------------------
// Fallback gates (slow path, fp32 weights).
// ---------------------------------------------------------------------------
__global__ __launch_bounds__(256) void gates_k0(
    const short* __restrict__ zT, const float* __restrict__ Wu,
    const float* __restrict__ Wc, const float* __restrict__ bu,
    const float* __restrict__ bc, const bf16* __restrict__ hnT,
    float* __restrict__ out)
{
    __shared__ __align__(16) short As[2][128 * 64];
    __shared__ __align__(16) short Bu[2][64 * 64];
    __shared__ __align__(16) short Bc[2][64 * 64];
    const int tid = threadIdx.x;
    const int lane = tid & 63, wid = tid >> 6;
    const int l15 = lane & 15, q = lane >> 4;
    const int b = blockIdx.z;
    const int m0 = blockIdx.y * 128;
    const int n0 = blockIdx.x * 64;
    const long long zb = (long long)b * NN_ * KC_;

    f4v aU[2][4] = {}, aC[2][4] = {};

    auto stage = [&](int k0, int pb) {
#pragma unroll
        for (int i = 0; i < 4; i++) {
            int idx = tid + (i << 8);
            int r = idx >> 3, c = idx & 7;
            int gw = m0 + r;
            s8v v = {0, 0, 0, 0, 0, 0, 0, 0};
            if (gw < NN_) v = *(const s8v*)&zT[zb + (long long)gw * KC_ + k0 + (c << 3)];
            *(s8v*)&As[pb][r * 64 + ((c ^ (r & 7)) << 3)] = v;
        }
#pragma unroll
        for (int i = 0; i < 4; i++) {
            int idx = tid + (i << 8);
            int r = idx >> 4, c4 = idx & 15;
            long long widx = (long long)(n0 + r) * KC_ + k0 + (c4 << 2);
            float4 fu = *(const float4*)(Wu + widx);
            float4 fc = *(const float4*)(Wc + widx);
            s4v vu = {f2s(fu.x), f2s(fu.y), f2s(fu.z), f2s(fu.w)};
            s4v vc = {f2s(fc.x), f2s(fc.y), f2s(fc.z), f2s(fc.w)};
            int di = r * 64 + (((c4 >> 1) ^ (r & 7)) << 3) + ((c4 & 1) << 2);
            *(s4v*)&Bu[pb][di] = vu;
            *(s4v*)&Bc[pb][di] = vc;
        }
    };

    stage(0, 0);
    __syncthreads();
    int pp = 0;
    for (int t = 0; t < 20; ++t) {
        if (t < 19) stage((t + 1) << 6, pp ^ 1);
#pragma unroll
        for (int ks = 0; ks < 64; ks += 32) {
            const int cb = ks >> 3;
            s8v af[2], bfu[4], bfc[4];
#pragma unroll
            for (int i = 0; i < 2; i++) {
                int rr = wid * 32 + i * 16 + l15;
                af[i] = *(const s8v*)&As[pp][SWZ(rr, cb)];
            }
#pragma unroll
            for (int j = 0; j < 4; j++) {
                int rr = j * 16 + l15;
                bfu[j] = *(const s8v*)&Bu[pp][SWZ(rr, cb)];
                bfc[j] = *(const s8v*)&Bc[pp][SWZ(rr, cb)];
            }
#pragma unroll
            for (int i = 0; i < 2; i++)
#pragma unroll
                for (int j = 0; j < 4; j++) {
                    aU[i][j] = MFMA(af[i], bfu[j], aU[i][j]);
                    aC[i][j] = MFMA(af[i], bfc[j], aC[i][j]);
                }
        }
        __syncthreads();
        pp ^= 1;
    }

#pragma unroll
    for (int i = 0; i < 2; i++) {
        int wbase = m0 + wid * 32 + i * 16 + q * 4;
#pragma unroll
        for (int j = 0; j < 4; j++) {
            int och = n0 + j * 16 + l15;
            float bvu = bu[och];
            float bvc = bc[och];
#pragma unroll
            for (int r = 0; r < 4; r++) {
                int w = wbase + r;
                if (w >= NN_) continue;
                float u = 1.f / (1.f + __expf(-(aU[i][j][r] + bvu)));
                float cg = tanhf(aC[i][j][r] + bvc);
                float hv = bf2f(hnT[((long long)b * NN_ + w) * 256 + och]);
                out[((long long)b * NU_ + och) * NN_ + w] = u * hv + (1.f - u) * cg;
            }
        }
    }
}

// inp[(b,n),c] = h[b,c,n] + embed[n,c] * mlt[b,n]  (32x32 LDS transpose of h)
__global__ __launch_bounds__(256) void build_inp_k(
    const float* __restrict__ h, const float* __restrict__ embed,
    const float* __restrict__ mlt, bf16* __restrict__ inp)
{
    __shared__ float t[32][33];
    const int b = blockIdx.z;
    const int n0 = blockIdx.x * 32, c0 = blockIdx.y * 32;
    const int t5 = threadIdx.x & 31, t8 = threadIdx.x >> 5;
#pragma unroll
    for (int r = 0; r < 4; r++) {
        int c = c0 + t8 + r * 8;
        int n = n0 + t5;
        t[t8 + r * 8][t5] = (n < NN_) ? h[((long long)b * 256 + c) * NN_ + n] : 0.f;
    }
    __syncthreads();
#pragma unroll
    for (int r = 0; r < 4; r++) {
        int n = n0 + t8 + r * 8;
        int c = c0 + t5;
        if (n < NN_) {
            float v = t[t5][t8 + r * 8] + embed[n * 256 + c] * mlt[b * NN_ + n];
            inp[((long long)b * NN_ + n) * 256 + c] = f2bf(v);
        }
    }
}

// out = LN(x + y) (optional tanh). One wave per 256-elem row, no barriers.
__global__ __launch_bounds__(256) void add_ln_k(
    const bf16* __restrict__ xr, const bf16* __restrict__ yr,
    const float* __restrict__ w, const float* __restrict__ bb,
    bf16* __restrict__ out, int do_tanh)
{
    const int lane = threadIdx.x & 63, wv = threadIdx.x >> 6;
    const long long row = (long long)blockIdx.x * 4 + wv;
    const long long base = row * 256 + lane * 4;
    s4v xv = *(const s4v*)((const short*)xr + base);
    s4v yv = *(const s4v*)((const short*)yr + base);
    float v[4];
    float sum = 0.f;
#pragma unroll
    for (int i = 0; i < 4; i++) {
        short sx = xv[i], sy = yv[i];
        v[i] = bf2f(*(bf16*)&sx) + bf2f(*(bf16*)&sy);
        sum += v[i];
    }
#pragma unroll
    for (int s = 1; s < 64; s <<= 1) sum += __shfl_xor(sum, s);
    float mu = sum * (1.f / 256.f);
    float vs = 0.f;
#pragma unroll
    for (int i = 0; i < 4; i++) { float d = v[i] - mu; vs += d * d; }
#pragma unroll
    for (int s = 1; s < 64; s <<= 1) vs += __shfl_xor(vs, s);
    float inv = rsqrtf(vs * (1.f / 256.f) + 1e-5f);
    s4v ov;
#pragma unroll
    for (int i = 0; i < 4; i++) {
        float r = (v[i] - mu) * inv * w[lane * 4 + i] + bb[lane * 4 + i];
        if (do_tanh) r = tanhf(r);
        ov[i] = f2s(r);
    }
    *(s4v*)((short*)out + base) = ov;
}

// hnT[(b,n),c] = step ? sqrt(1-dt)*h[b,c,n] - sqrt(dt)*eps[(b,n),c] : h[b,c,n]
__global__ __launch_bounds__(256) void hnew_k(
    const float* __restrict__ h, const bf16* __restrict__ epsb,
    const float* __restrict__ dt, const int* __restrict__ step, bf16* __restrict__ hnT)
{
    __shared__ float t[32][33];
    const int b = blockIdx.z;
    const int n0 = blockIdx.x * 32, c0 = blockIdx.y * 32;
    const int t5 = threadIdx.x & 31, t8 = threadIdx.x >> 5;
#pragma unroll
    for (int r = 0; r < 4; r++) {
        int c = c0 + t8 + r * 8;
        int n = n0 + t5;
        t[t8 + r * 8][t5] = (n < NN_) ? h[((long long)b * 256 + c) * NN_ + n] : 0.f;
    }
    __syncthreads();
    const int st = *step;
    const float d = dt[b];
    const float sa = sqrtf(fmaxf(1.f - d, 0.f)), sb = sqrtf(d);
#pragma unroll
    for (int r = 0; r < 4; r++) {
        int n = n0 + t8 + r * 8;
        int c = c0 + t5;
        if (n < NN_) {
            float hv = t[t5][t8 + r * 8];
            float val = hv;
            if (st != 0) {
                float ev = bf2f(epsb[((long long)b * NN_ + n) * 256 + c]);
                val = sa * hv - sb * ev;
            }
            hnT[((long long)b * NN_ + n) * 256 + c] = f2bf(val);
        }
    }
}

// zT[(b,n), c] = x[b,c,n] for c < 64 (transpose)
__global__ __launch_bounds__(256) void zx_k(
    const float* __restrict__ x, short* __restrict__ zT)
{
    __shared__ float t[32][33];
    const int b = blockIdx.z;
    const int n0 = blockIdx.x * 32, c0 = blockIdx.y * 32;
    const int t5 = threadIdx.x & 31, t8 = threadIdx.x >> 5;
#pragma unroll
    for (int r = 0; r < 4; r++) {
        int c = c0 + t8 + r * 8;
        int n = n0 + t5;
        t[t8 + r * 8][t5] = (n < NN_) ? x[((long long)b * DIN_ + c) * NN_ + n] : 0.f;
    }
    __syncthreads();
#pragma unroll
    for (int r = 0; r < 4; r++) {
        int n = n0 + t8 + r * 8;
        int c = c0 + t5;
        if (n < NN_)
            zT[((long long)b * NN_ + n) * KC_ + c] = f2s(t[t5][t8 + r * 8]);
    }
}

// zT[(b,n), 64+c] = hnT[(b,n), c]  (vectorized copy)
__global__ __launch_bounds__(256) void zcopy_k(
    const short* __restrict__ hnT, short* __restrict__ zT)
{
    long long u = (long long)blockIdx.x * 256 + threadIdx.x;  // < NB_*32
    long long row = u >> 5;
    int cu = (int)(u & 31);
    s8v v = *(const s8v*)(hnT + row * 256 + cu * 8);
    *(s8v*)(zT + row * KC_ + 64 + cu * 8) = v;
}

extern "C" void kernel_launch(void* const* d_in, const int* in_sizes, int n_in,
                              void* d_out, int out_size, void* d_ws, size_t ws_size,
                              hipStream_t stream) {
    const float* x          = (const float*)d_in[0];
    const float* delta_t    = (const float*)d_in[1];
    const float* h          = (const float*)d_in[2];
    const float* adj        = (const float*)d_in[3];
    const float* mlt        = (const float*)d_in[5];
    const int*  step        = (const int*)d_in[7];
    const float* embed      = (const float*)d_in[8];
    const float* in_proj_w  = (const float*)d_in[9];
    const float* in_proj_b  = (const float*)d_in[10];
    const float* out_proj_w = (const float*)d_in[11];
    const float* out_proj_b = (const float*)d_in[12];
    const float* ln1_w      = (const float*)d_in[13];
    const float* ln1_b      = (const float*)d_in[14];
    const float* ln2_w      = (const float*)d_in[15];
    const float* ln2_b      = (const float*)d_in[16];
    const float* ffn_w1     = (const float*)d_in[17];
    const float* ffn_b1     = (const float*)d_in[18];
    const float* ffn_w2     = (const float*)d_in[19];
    const float* ffn_b2     = (const float*)d_in[20];
    const float* W_u        = (const float*)d_in[21];
    const float* b_u        = (const float*)d_in[22];
    const float* W_c        = (const float*)d_in[23];
    const float* b_c        = (const float*)d_in[24];
    float* out = (float*)d_out;
    bf16* ws   = (bf16*)d_ws;

    bf16* inp = ws;
    short* qk = (short*)(ws + 1 * NBD_);
    short* vt = (short*)(ws + 3 * NBD_);
    bf16* ao  = ws + 4 * NBD_ + 65536;
    bf16* o   = ws + 1 * NBD_;
    bf16* s   = ws + 2 * NBD_;
    bf16* f   = ws + 1 * NBD_;
    bf16* f2  = ws + 3 * NBD_;
    bf16* eps = ws + 2 * NBD_;
    bf16* hnT = ws;
    short* zT = (short*)(ws + 1 * NBD_);
    short* wext = (short*)(ws + 6 * NBD_);

    const size_t need = (size_t)(6 * NBD_ + WEXT_N) * 2;
    const bool fast = ws_size >= need;   // capture-time host decision

    short* wuc  = wext + WU_OFF;         // [512][1280]: rows 0..255 Wu, 256..511 Wc
    short* ipb  = wext + IP_OFF;
    short* opb  = wext + OP_OFF;
    short* f1b  = wext + F1_OFF;
    short* f2b  = wext + F2_OFF;
    short* adjb = wext + ADJ_OFF;

    // 0. one-shot fp32 -> bf16 weight conversion
    if (fast)
        cvt_w_k<<<dim3(1024), dim3(256), 0, stream>>>(
            W_u, W_c, in_proj_w, out_proj_w, ffn_w1, ffn_w2, adj, wext);

    // 1. inp = h^T + embed * mlt   ((b,n) rows)
    build_inp_k<<<dim3(7, 8, 256), dim3(256), 0, stream>>>(h, embed, mlt, inp);

    // 2. qkv GEMM: Q,K -> qk rows (512); V -> vt transposed
    if (fast)
        gemm128<0><<<dim3(6, 416), dim3(256), 0, stream>>>(
            (const short*)inp, 256, ipb, 256, in_proj_b,
            (bf16*)qk, 512, 256, 0, vt, nullptr, nullptr, nullptr, nullptr);
    else
        gemm_nk0<<<dim3(6, 414), dim3(256), 0, stream>>>(
            (const short*)inp, 256, in_proj_w, 256, in_proj_b,
            (bf16*)qk, 512, NB_, 768, 256, 0, vt);

    // 3. MFMA attention (XCD-swizzled internally)
    attn_k<<<dim3(4, 256), dim3(256), 0, stream>>>(qk, vt, ao);

    // 4. o = ao @ out_proj^T + b
    if (fast)
        gemm128<0><<<dim3(2, 416), dim3(256), 0, stream>>>(
            (const short*)ao, 256, opb, 256, out_proj_b,
            o, 256, 256, 0, nullptr, nullptr, nullptr, nullptr, nullptr);
    else
        gemm_nk0<<<dim3(2, 414), dim3(256), 0, stream>>>(
            (const short*)ao, 256, out_proj_w, 256, out_proj_b, o, 256, NB_, 256, 256, 0, nullptr);

    // 5. s = LN1(inp + o)
    add_ln_k<<<dim3(NB_ / 4), dim3(256), 0, stream>>>(inp, o, ln1_w, ln1_b, s, 0);

    // 6. f = relu(s @ ffn_w1^T + b)
    if (fast)
        gemm128<0><<<dim3(2, 416), dim3(256), 0, stream>>>(
            (const short*)s, 256, f1b, 256, ffn_b1,
            f, 256, 256, 3, nullptr, nullptr, nullptr, nullptr, nullptr);
    else
        gemm_nk0<<<dim3(2, 414), dim3(256), 0, stream>>>(
            (const short*)s, 256, ffn_w1, 256, ffn_b1, f, 256, NB_, 256, 256, 3, nullptr);

    // 7. f2 = f @ ffn_w2^T + b
    if (fast)
        gemm128<0><<<dim3(2, 416), dim3(256), 0, stream>>>(
            (const short*)f, 256, f2b, 256, ffn_b2,
            f2, 256, 256, 0, nullptr, nullptr, nullptr, nullptr, nullptr);
    else
        gemm_nk0<<<dim3(2, 414), dim3(256), 0, stream>>>(
            (const short*)f, 256, ffn_w2, 256, ffn_b2, f2, 256, NB_, 256, 256, 0, nullptr);

    // 8. eps = tanh(LN2(s + f2))   (in-place over s)
    add_ln_k<<<dim3(NB_ / 4), dim3(256), 0, stream>>>(s, f2, ln2_w, ln2_b, eps, 1);

    // 9. hnT = step ? sqrt(1-dt)*h - sqrt(dt)*eps : h   ((b,n,c) layout)
    hnew_k<<<dim3(7, 8, 256), dim3(256), 0, stream>>>(h, eps, delta_t, step, hnT);

    // 10. zT cols 0..63 = x^T; 11. cols 64..319 = hnT
    zx_k<<<dim3(7, 2, 256), dim3(256), 0, stream>>>(x, zT);
    zcopy_k<<<dim3(6624), dim3(256), 0, stream>>>((const short*)hnT, zT);

    // 12. diffusion orders 1..3
    if (fast) {
        diff_k<1><<<dim3(3, 2, 256), dim3(256), 0, stream>>>(adj, adjb, zT, zT, 0, 320);
        diff_k<1><<<dim3(3, 2, 256), dim3(256), 0, stream>>>(adj, adjb, zT, zT, 320, 640);
        diff_k<1><<<dim3(3, 2, 256), dim3(256), 0, stream>>>(adj, adjb, zT, zT, 640, 960);
    } else {
        diff_k<0><<<dim3(3, 2, 256), dim3(256), 0, stream>>>(adj, nullptr, zT, zT, 0, 320);
        diff_k<0><<<dim3(3, 2, 256), dim3(256), 0, stream>>>(adj, nullptr, zT, zT, 320, 640);
        diff_k<0><<<dim3(3, 2, 256), dim3(256), 0, stream>>>(adj, nullptr, zT, zT, 640, 960);
    }

    // 13. fused gates + combine -> out (fp32): flat GEMM M=NB_, N=512 (u/c interleaved)
    if (fast)
        gemm128<1><<<dim3(4, 416), dim3(256), 0, stream>>>(
            zT, KC_, wuc, KC_, nullptr,
            nullptr, 0, KC_, 0, nullptr, b_u, b_c, hnT, out);
    else
        gates_k0<<<dim3(4, 2, 256), dim3(256), 0, stream>>>(
            zT, W_u, W_c, b_u, b_c, hnT, out);

    (void)in_sizes; (void)n_in; (void)out_size; (void)ws_size;
}

// Round 10
// 674.467 us; speedup vs baseline: 1.2285x; 1.0528x over previous
//
#include <hip/hip_runtime.h>
#include <hip/hip_bf16.h>

typedef __hip_bfloat16 bf16;
typedef __attribute__((ext_vector_type(8))) short s8v;   // 8 bf16 in 4 VGPRs
typedef __attribute__((ext_vector_type(4))) short s4v;   // 4 bf16 in 2 VGPRs
typedef __attribute__((ext_vector_type(4))) float f4v;   // mfma accumulator

#define MFMA(a, b, c) __builtin_amdgcn_mfma_f32_16x16x32_bf16(a, b, c, 0, 0, 0)

#define B_    256
#define DIN_  64
#define NU_   256
#define NN_   207
#define KC_   1280
#define NB_   (NN_ * B_)       // 52992 transformer rows; 52992 = 414*128
#define NBD_  13565952LL       // NB_ * 256 elements (one ws region)

// bf16 weight scratch layout (shorts), appended after the 6 proven regions
#define WU_OFF   0LL           // Wu rows 0..255   } contiguous => WUC[512][1280]
#define WC_OFF   327680LL      // Wc rows 256..511 }
#define IP_OFF   655360LL
#define OP_OFF   851968LL
#define F1_OFF   917504LL
#define F2_OFF   983040LL
#define ADJ_OFF  1048576LL     // adj padded to [207][256], zeros in pad
#define WEXT_N   (ADJ_OFF + 207LL * 256LL)   // 1101568 shorts

__device__ __forceinline__ float bf2f(bf16 v) { return __bfloat162float(v); }
__device__ __forceinline__ bf16  f2bf(float v) { return __float2bfloat16(v); }
__device__ __forceinline__ short f2s(float v) { bf16 t = __float2bfloat16(v); return *(short*)&t; }

// direct global->LDS DMA, 16B per lane; lds dest must be wave-uniform
__device__ __forceinline__ void gl16(const void* g, void* l) {
    __builtin_amdgcn_global_load_lds(
        (const __attribute__((address_space(1))) void*)g,
        (__attribute__((address_space(3))) void*)l, 16, 0, 0);
}

// Swizzled LDS tile layout: tile row stride 64 shorts; 16B chunk c of row r
// lives at position c^(r&7). gl16 writes linearly (lane -> seg*512+lane*16B),
// so the global SOURCE chunk is pre-swizzled with chunk^(lane>>3).
#define SWZ(rr, cb) ((rr) * 64 + ((((cb) + q) ^ ((rr) & 7)) << 3))

// ---------------------------------------------------------------------------
// One-shot fp32 -> bf16 weight conversion into wext.
// ---------------------------------------------------------------------------
__global__ __launch_bounds__(256) void cvt_w_k(
    const float* __restrict__ Wu, const float* __restrict__ Wc,
    const float* __restrict__ ip, const float* __restrict__ op,
    const float* __restrict__ f1, const float* __restrict__ f2,
    const float* __restrict__ adj, short* __restrict__ dst)
{
    long long t = (long long)blockIdx.x * 256 + threadIdx.x;
    long long nt = (long long)gridDim.x * 256;
    for (long long g = t; g < 262144; g += nt) {   // 1048576 elems / 4
        long long e = g * 4;
        const float* src; long long off;
        if (e < WC_OFF)      { src = Wu; off = e; }
        else if (e < IP_OFF) { src = Wc; off = e - WC_OFF; }
        else if (e < OP_OFF) { src = ip; off = e - IP_OFF; }
        else if (e < F1_OFF) { src = op; off = e - OP_OFF; }
        else if (e < F2_OFF) { src = f1; off = e - F1_OFF; }
        else                 { src = f2; off = e - F2_OFF; }
        float4 fv = *(const float4*)(src + off);
        s4v v = {f2s(fv.x), f2s(fv.y), f2s(fv.z), f2s(fv.w)};
        *(s4v*)(dst + e) = v;
    }
    short* adst = dst + ADJ_OFF;
    for (long long g = t; g < 207LL * 256LL; g += nt) {
        int r = (int)(g >> 8), c = (int)(g & 255);
        adst[g] = (c < NN_) ? f2s(adj[r * NN_ + c]) : (short)0;
    }
}

// ---------------------------------------------------------------------------
// m97-structure MFMA GEMM (fast path): 256 thr / 4 waves, tile 128x128,
// BK=64, SINGLE 32 KB LDS buffer, plain stage->sync->compute->sync loop.
// ~3 blocks/CU -> inter-block overlap hides barrier drains (m97 mechanism).
// XCD-aware remap: grid = (nswz, 416); m-tiles 414 pad to 416=52x8.
// EPI=0: C = act(A@W^T + bias); vt!=null => cols>=512 transposed to vt.
// EPI=1: gates mode (lane-split transcendentals, LDS-staged coalesced out).
// ---------------------------------------------------------------------------
template<int EPI>
__global__ __launch_bounds__(256, 3) void gemm128(
    const short* __restrict__ A, int lda,
    const short* __restrict__ Wb, int ldb,
    const float* __restrict__ bias, bf16* __restrict__ C, int ldc,
    int K, int act, short* __restrict__ vt,
    const float* __restrict__ bu, const float* __restrict__ bc,
    const bf16* __restrict__ hnT, float* __restrict__ outF)
{
    __shared__ __align__(16) short Tiles[2][128 * 64];   // As | Bs ; reused as 32KB fp32 out-stage
    short* As = Tiles[0];
    short* Bs = Tiles[1];
    float* outS = (float*)&Tiles[0][0];                  // 8192 floats = 64 och x 128 m
    const int w_ = blockIdx.y * gridDim.x + blockIdx.x;   // dispatch-order id
    const int nswz = gridDim.x;
    const int xr = w_ & 7, sidx = w_ >> 3;
    const int mt = xr + 8 * (sidx / nswz);
    const int nt = sidx % nswz;
    if (mt >= 414) return;                                // idle pad block
    const int m0 = mt * 128, n0 = nt * 128;
    const int tid = threadIdx.x;
    const int lane = tid & 63, wid = tid >> 6;
    const int l15 = lane & 15, q = lane >> 4;
    const int wm = (wid >> 1) * 64, wn = (wid & 1) * 64;
    const int seg_r = lane >> 3;
    const int csw8 = ((lane & 7) ^ seg_r) << 3;
    const int nk = K >> 6;

    // hoisted global pointers (include swizzled chunk); advance by k0
    const short* ap[4];
    const short* bp[4];
#pragma unroll
    for (int i = 0; i < 4; i++) {
        int gm = m0 + (wid * 4 + i) * 8 + seg_r;
        ap[i] = A + (long long)gm * lda + csw8;
        int gn = n0 + (wid * 4 + i) * 8 + seg_r;
        int pr = EPI ? ((gn & 1) * 256 + (gn >> 1)) : gn;
        bp[i] = Wb + (long long)pr * ldb + csw8;
    }

    f4v acc[4][4] = {};

    for (int t = 0; t < nk; ++t) {
        const int k0 = t << 6;
#pragma unroll
        for (int i = 0; i < 4; i++) {
            gl16(ap[i] + k0, &As[(wid * 4 + i) * 512]);
            gl16(bp[i] + k0, &Bs[(wid * 4 + i) * 512]);
        }
        __syncthreads();
#pragma unroll
        for (int ks = 0; ks < 64; ks += 32) {
            const int cb = ks >> 3;
            s8v af[4], bfv[4];
#pragma unroll
            for (int i = 0; i < 4; i++) {
                int rr = wm + i * 16 + l15;
                af[i] = *(const s8v*)&As[SWZ(rr, cb)];
            }
#pragma unroll
            for (int j = 0; j < 4; j++) {
                int rr = wn + j * 16 + l15;
                bfv[j] = *(const s8v*)&Bs[SWZ(rr, cb)];
            }
#pragma unroll
            for (int i = 0; i < 4; i++)
#pragma unroll
                for (int j = 0; j < 4; j++)
                    acc[i][j] = MFMA(af[i], bfv[j], acc[i][j]);
        }
        __syncthreads();
    }

    if (EPI == 0) {
#pragma unroll
        for (int i = 0; i < 4; i++) {
            int mbase = m0 + wm + i * 16 + q * 4;
#pragma unroll
            for (int j = 0; j < 4; j++) {
                int n = n0 + wn + j * 16 + l15;
                float bv = bias ? bias[n] : 0.f;
#pragma unroll
                for (int r = 0; r < 4; r++) {
                    int m = mbase + r;
                    float v = acc[i][j][r] + bv;
                    if (act == 3) v = fmaxf(v, 0.f);
                    if (vt && n >= 512) {
                        int d = n - 512;
                        int bb = m / NN_;
                        int node = m - bb * NN_;
                        vt[((long long)bb * 256 + d) * 208 + node] = f2s(v);
                    } else {
                        C[(long long)m * ldc + n] = f2bf(v);
                    }
                }
            }
        }
    } else {
        const int odd = l15 & 1;
#pragma unroll
        for (int i = 0; i < 4; i++) {
            int mlbase = wm + i * 16 + q * 4;
#pragma unroll
            for (int j = 0; j < 4; j++) {
                int n = n0 + wn + j * 16 + l15;
                int och = n >> 1;
                int ochl = (wn + j * 16 + l15) >> 1;
                float bv = odd ? bc[och] : bu[och];
#pragma unroll
                for (int r = 0; r < 4; r++) {
                    int ml = mlbase + r;
                    float pre = acc[i][j][r] + bv;
                    float myv;
                    if (odd) {                       // c-gate lane: tanh via exp
                        float e = __expf(2.f * pre);
                        myv = (e - 1.f) / (e + 1.f);
                    } else {                         // u-gate lane: sigmoid
                        myv = 1.f / (1.f + __expf(-pre));
                    }
                    float oth = __shfl_xor(myv, 1);  // even lane <- tanh(c)
                    if (!odd) {
                        int m = m0 + ml;
                        float hv = bf2f(hnT[(long long)m * 256 + och]);
                        float res = myv * hv + (1.f - myv) * oth;
                        outS[ochl * 128 + (ml ^ ((ochl & 7) << 2))] = res;
                    }
                }
            }
        }
        __syncthreads();
        // coalesced out write: wave covers 64 consecutive m per och row
        for (int orow = tid >> 6; orow < 64; orow += 4) {
            int och = (n0 >> 1) + orow;
            const int sx = (orow & 7) << 2;
#pragma unroll
            for (int half = 0; half < 2; half++) {
                int ml = lane + half * 64;
                float v = outS[orow * 128 + (ml ^ sx)];
                int m = m0 + ml;
                int bb = m / NN_;
                int node = m - bb * NN_;
                outF[((long long)bb * NU_ + och) * NN_ + node] = v;
            }
        }
    }
}

// ---------------------------------------------------------------------------
// Fallback (slow path) GEMM: fp32 weights, reg-staged, 2-buffer.
// ---------------------------------------------------------------------------
__global__ __launch_bounds__(256) void gemm_nk0(
    const short* __restrict__ A, int lda,
    const float* __restrict__ Wf, int ldb,
    const float* __restrict__ bias, bf16* __restrict__ C, int ldc,
    int M, int N, int K, int act, short* __restrict__ vt)
{
    __shared__ __align__(16) short As[2][128 * 64];
    __shared__ __align__(16) short Bs[2][128 * 64];
    const int tid = threadIdx.x;
    const int lane = tid & 63, wid = tid >> 6;
    const int l15 = lane & 15, q = lane >> 4;
    const int wm = (wid >> 1) * 64, wn = (wid & 1) * 64;
    const int m0 = blockIdx.y * 128, n0 = blockIdx.x * 128;

    f4v acc[4][4] = {};
    const int nk = K >> 6;

    auto stage = [&](int k0, int pb) {
#pragma unroll
        for (int i = 0; i < 4; i++) {
            int idx = tid + (i << 8);
            int r = idx >> 3, c = idx & 7;
            int gm = m0 + r, gk = k0 + (c << 3);
            s8v v = {0, 0, 0, 0, 0, 0, 0, 0};
            if (gm < M) v = *(const s8v*)(A + (long long)gm * lda + gk);
            *(s8v*)&As[pb][r * 64 + ((c ^ (r & 7)) << 3)] = v;
        }
#pragma unroll
        for (int i = 0; i < 8; i++) {
            int idx = tid + (i << 8);
            int r = idx >> 4, c4 = idx & 15;
            int gn = n0 + r, gk = k0 + (c4 << 2);
            s4v v = {0, 0, 0, 0};
            if (gn < N) {
                float4 fx = *(const float4*)(Wf + (long long)gn * ldb + gk);
                v[0] = f2s(fx.x); v[1] = f2s(fx.y); v[2] = f2s(fx.z); v[3] = f2s(fx.w);
            }
            *(s4v*)&Bs[pb][r * 64 + (((c4 >> 1) ^ (r & 7)) << 3) + ((c4 & 1) << 2)] = v;
        }
    };

    stage(0, 0);
    __syncthreads();
    int pp = 0;
    for (int t = 0; t < nk; ++t) {
        if (t + 1 < nk) stage((t + 1) << 6, pp ^ 1);
#pragma unroll
        for (int ks = 0; ks < 64; ks += 32) {
            const int cb = ks >> 3;
            s8v af[4], bfv[4];
#pragma unroll
            for (int i = 0; i < 4; i++) {
                int rr = wm + i * 16 + l15;
                af[i] = *(const s8v*)&As[pp][SWZ(rr, cb)];
            }
#pragma unroll
            for (int j = 0; j < 4; j++) {
                int rr = wn + j * 16 + l15;
                bfv[j] = *(const s8v*)&Bs[pp][SWZ(rr, cb)];
            }
#pragma unroll
            for (int i = 0; i < 4; i++)
#pragma unroll
                for (int j = 0; j < 4; j++)
                    acc[i][j] = MFMA(af[i], bfv[j], acc[i][j]);
        }
        __syncthreads();
        pp ^= 1;
    }

#pragma unroll
    for (int i = 0; i < 4; i++) {
        int mbase = m0 + wm + i * 16 + q * 4;
#pragma unroll
        for (int j = 0; j < 4; j++) {
            int n = n0 + wn + j * 16 + l15;
            if (n >= N) continue;
            float bv = bias ? bias[n] : 0.f;
#pragma unroll
            for (int r = 0; r < 4; r++) {
                int m = mbase + r;
                if (m >= M) continue;
                float v = acc[i][j][r] + bv;
                if (act == 3) v = fmaxf(v, 0.f);
                if (vt && n >= 512) {
                    int d = n - 512;
                    int bb = m / NN_;
                    int node = m - bb * NN_;
                    vt[((long long)bb * 256 + d) * 208 + node] = f2s(v);
                } else {
                    C[(long long)m * ldc + n] = f2bf(v);
                }
            }
        }
    }
}

// ---------------------------------------------------------------------------
// MFMA attention v2: one block per (64-q tile, b), 4 waves.
// K and V staged in a shared 16 KB LDS buffer ONCE per block (waves shared
// identical A-operands before -> 4x global re-read eliminated).
// K: 7 chunks of 32 rows x 256 (swizzle chunk^(row&7));
// V: per-ks chunks of 256 d-rows x 32 nodes (swizzle chunk^((d>>1)&3)).
// XCD swizzle: grid(4,256)=1024=8*128; same-b q-tiles co-locate.
// ---------------------------------------------------------------------------
__global__ __launch_bounds__(256, 3) void attn_k(
    const short* __restrict__ qk, const short* __restrict__ vt,
    bf16* __restrict__ ao)
{
    __shared__ __align__(16) short KV[8192];        // 16 KB K/V staging
    __shared__ __align__(16) short Plds[64 * 232];  // 29.75 KB
    __shared__ float sums[64];
    const int tid = threadIdx.x;
    const int lane = tid & 63, w = tid >> 6;
    const int l15 = lane & 15, quad = lane >> 4;
    const int w_ = blockIdx.y * gridDim.x + blockIdx.x;
    const int xr = w_ & 7, sidx = w_ >> 3;
    const int b = xr + 8 * (sidx >> 2);
    const int q0 = (sidx & 3) * 64;
    const long long rowcap = (long long)NB_ - 1;
    const long long bbase = (long long)b * NN_;

    // Q frags (B-operand): own 16 q rows per wave, kept in registers
    long long qrow = bbase + q0 + w * 16 + l15;
    if (qrow > rowcap) qrow = rowcap;
    const short* qp = qk + qrow * 512;
    s8v bq[8];
#pragma unroll
    for (int ks = 0; ks < 8; ks++)
        bq[ks] = *(const s8v*)(qp + ks * 32 + quad * 8);

    // Phase 1: QK^T with K staged in 32-row chunks (shared across waves)
    f4v sacc[13] = {};
    const int sr2 = lane >> 5;          // row within 1KB pair
    const int c32 = lane & 31;          // 16B col chunk (32 per 512B row)
#pragma unroll
    for (int jc = 0; jc < 7; ++jc) {
#pragma unroll
        for (int i = 0; i < 4; i++) {   // stage 32 rows: 16 x 1KB, 4/wave
            int lrow = w * 8 + i * 2 + sr2;
            int jrow = jc * 32 + lrow;
            if (jrow > NN_ - 1) jrow = NN_ - 1;
            gl16(qk + (bbase + jrow) * 512 + 256 + ((c32 ^ (lrow & 7)) << 3),
                 &KV[(w * 8 + i * 2) * 256]);
        }
        __syncthreads();
#pragma unroll
        for (int jf2 = 0; jf2 < 2; jf2++) {
            const int jf = jc * 2 + jf2;
            if (jf < 13) {
                const int lrow = jf2 * 16 + l15;
#pragma unroll
                for (int ks = 0; ks < 8; ks++) {
                    s8v a = *(const s8v*)&KV[lrow * 256 + (((ks * 4 + quad) ^ (lrow & 7)) << 3)];
                    sacc[jf] = MFMA(a, bq[ks], sacc[jf]);
                }
            }
        }
        __syncthreads();
    }

    // softmax over j for this lane's q
    float mx = -3.0e38f;
    float pv[13][4];
#pragma unroll
    for (int jf = 0; jf < 13; jf++)
#pragma unroll
        for (int r = 0; r < 4; r++) {
            int j = jf * 16 + quad * 4 + r;
            float v = (j < NN_) ? sacc[jf][r] * 0.0625f : -3.0e38f;
            pv[jf][r] = v;
            mx = fmaxf(mx, v);
        }
    mx = fmaxf(mx, __shfl_xor(mx, 16));
    mx = fmaxf(mx, __shfl_xor(mx, 32));
    float sum = 0.f;
#pragma unroll
    for (int jf = 0; jf < 13; jf++)
#pragma unroll
        for (int r = 0; r < 4; r++) {
            float p = __expf(pv[jf][r] - mx);
            pv[jf][r] = p;
            sum += p;
        }
    sum += __shfl_xor(sum, 16);
    sum += __shfl_xor(sum, 32);

    const int qloc = w * 16 + l15;
#pragma unroll
    for (int jf = 0; jf < 13; jf++)
#pragma unroll
        for (int r = 0; r < 4; r++)
            Plds[qloc * 232 + jf * 16 + quad * 4 + r] = f2s(pv[jf][r]);
    if (quad == 0) sums[qloc] = 1.f / sum;
#pragma unroll
    for (int i = 0; i < 4; i++) {               // zero pad cols 208..223
        int u = tid + i * 256;
        Plds[(u >> 4) * 232 + 208 + (u & 15)] = 0;
    }
    __syncthreads();

    // Phase 2: PV with V staged per-ks (256 d-rows x 32 nodes, shared)
    const short* vbase = vt + (long long)b * 256 * 208;
    f4v oacc[16] = {};
    const int vr = lane >> 2;           // d row within 16
    const int vc = lane & 3;            // 16B chunk (4 per 64B row)
    for (int ks = 0; ks < 7; ks++) {
#pragma unroll
        for (int i = 0; i < 4; i++) {   // stage 16 KB: 16 x 1KB, 4/wave
            int d = w * 64 + i * 16 + vr;
            gl16(vbase + (long long)d * 208 + ks * 32 + ((vc ^ ((d >> 1) & 3)) << 3),
                 &KV[(w * 64 + i * 16) * 32]);
        }
        __syncthreads();
        s8v pa = *(const s8v*)&Plds[(w * 16 + l15) * 232 + ks * 32 + quad * 8];
#pragma unroll
        for (int df = 0; df < 16; df++) {
            const int dl = df * 16 + l15;
            s8v vb = *(const s8v*)&KV[dl * 32 + ((quad ^ ((dl >> 1) & 3)) << 3)];
            oacc[df] = MFMA(pa, vb, oacc[df]);
        }
        __syncthreads();
    }

#pragma unroll
    for (int df = 0; df < 16; df++) {
        int d = df * 16 + l15;
#pragma unroll
        for (int r = 0; r < 4; r++) {
            int ql = w * 16 + quad * 4 + r;
            int qg = q0 + ql;
            if (qg < NN_)
                ao[((long long)b * NN_ + qg) * 256 + d] = f2bf(oacc[df][r] * sums[ql]);
        }
    }
}

// ---------------------------------------------------------------------------
// Diffusion step in (b, node, chan) layout, batched over b.
// WB=1: adjb via global_load_lds (clamped rows); zT B-side reg-staged with
// async split (load regs early, ds_write after compute). Double-buffered.
// ---------------------------------------------------------------------------
template<int WB>
__global__ __launch_bounds__(256) void diff_k(
    const float* __restrict__ adj, const short* __restrict__ adjb,
    const short* __restrict__ zT_in,
    short* __restrict__ zT_out, int col_in, int col_out)
{
    __shared__ __align__(16) short As[2][128 * 64];
    __shared__ __align__(16) short Bs[2][128 * 64];
    const int tid = threadIdx.x;
    const int lane = tid & 63, wid = tid >> 6;
    const int l15 = lane & 15, q = lane >> 4;
    const int wm = (wid >> 1) * 64, wn = (wid & 1) * 64;
    const int m0 = blockIdx.y * 128, n0 = blockIdx.x * 128;
    const long long zb = (long long)blockIdx.z * NN_ * KC_;
    const int seg_r = lane >> 3, chunk = lane & 7;
    const int csw8 = (chunk ^ seg_r) << 3;
    const int bv_ = tid & 63, bcg = tid >> 6;   // B-stage coords

    f4v acc[4][4] = {};

    auto stageA = [&](int k0, int pb) {
        if (WB) {
#pragma unroll
            for (int i = 0; i < 4; i++) {
                int seg = wid * 4 + i;
                int gm = m0 + seg * 8 + seg_r;
                if (gm > NN_ - 1) gm = NN_ - 1;
                gl16(adjb + gm * 256 + k0 + csw8, &As[pb][seg * 512]);
            }
        } else {
#pragma unroll
            for (int i = 0; i < 32; i++) {
                int idx = tid + (i << 8);
                int r = idx >> 6, c = idx & 63;
                int gm = m0 + r, gk = k0 + c;
                short vv = (gm < NN_ && gk < NN_) ? f2s(adj[gm * NN_ + gk]) : (short)0;
                As[pb][r * 64 + (((c >> 3) ^ (r & 7)) << 3) + (c & 7)] = vv;
            }
        }
    };
    auto loadB = [&](int k0, s8v* breg) {
#pragma unroll
        for (int i = 0; i < 4; i++) {
            int gv = k0 + bv_, gc = n0 + (bcg + i * 4) * 8;
            s8v val = {0, 0, 0, 0, 0, 0, 0, 0};
            if (gv < NN_ && gc < 320)
                val = *(const s8v*)&zT_in[zb + (long long)gv * KC_ + col_in + gc];
            breg[i] = val;
        }
    };
    auto writeB = [&](s8v* breg, int pb) {
#pragma unroll
        for (int i = 0; i < 4; i++) {
            int cg = bcg + i * 4;
#pragma unroll
            for (int e = 0; e < 8; e++) {
                int row = cg * 8 + e;
                Bs[pb][row * 64 + (((bv_ >> 3) ^ (row & 7)) << 3) + (bv_ & 7)] = breg[i][e];
            }
        }
    };

    s8v breg[4];
    loadB(0, breg);
    stageA(0, 0);
    writeB(breg, 0);
    __syncthreads();
    int pp = 0;
    for (int t = 0; t < 4; ++t) {               // ceil(207/64) K-steps
        if (t < 3) { loadB((t + 1) << 6, breg); stageA((t + 1) << 6, pp ^ 1); }
#pragma unroll
        for (int ks = 0; ks < 64; ks += 32) {
            const int cb = ks >> 3;
            s8v af[4], bfv[4];
#pragma unroll
            for (int i = 0; i < 4; i++) {
                int rr = wm + i * 16 + l15;
                af[i] = *(const s8v*)&As[pp][SWZ(rr, cb)];
            }
#pragma unroll
            for (int j = 0; j < 4; j++) {
                int rr = wn + j * 16 + l15;
                bfv[j] = *(const s8v*)&Bs[pp][SWZ(rr, cb)];
            }
#pragma unroll
            for (int i = 0; i < 4; i++)
#pragma unroll
                for (int j = 0; j < 4; j++)
                    acc[i][j] = MFMA(af[i], bfv[j], acc[i][j]);
        }
        if (t < 3) writeB(breg, pp ^ 1);
        __syncthreads();
        pp ^= 1;
    }

#pragma unroll
    for (int i = 0; i < 4; i++) {
        int mbase = m0 + wm + i * 16 + q * 4;
#pragma unroll
        for (int j = 0; j < 4; j++) {
            int n = n0 + wn + j * 16 + l15;
            if (n >= 320) continue;
#pragma unroll
            for (int r = 0; r < 4; r++) {
                int m = mbase + r;
                if (m >= NN_) continue;
                zT_out[zb + (long long)m * KC_ + col_out + n] = f2s(acc[i][j][r]);
            }
        }
    }
}

// ---------------------------------------------------------------------------
// Fallback gates (slow path, fp32 weights).
// ---------------------------------------------------------------------------
__global__ __launch_bounds__(256) void gates_k0(
    const short* __restrict__ zT, const float* __restrict__ Wu,
    const float* __restrict__ Wc, const float* __restrict__ bu,
    const float* __restrict__ bc, const bf16* __restrict__ hnT,
    float* __restrict__ out)
{
    __shared__ __align__(16) short As[2][128 * 64];
    __shared__ __align__(16) short Bu[2][64 * 64];
    __shared__ __align__(16) short Bc[2][64 * 64];
    const int tid = threadIdx.x;
    const int lane = tid & 63, wid = tid >> 6;
    const int l15 = lane & 15, q = lane >> 4;
    const int b = blockIdx.z;
    const int m0 = blockIdx.y * 128;
    const int n0 = blockIdx.x * 64;
    const long long zb = (long long)b * NN_ * KC_;

    f4v aU[2][4] = {}, aC[2][4] = {};

    auto stage = [&](int k0, int pb) {
#pragma unroll
        for (int i = 0; i < 4; i++) {
            int idx = tid + (i << 8);
            int r = idx >> 3, c = idx & 7;
            int gw = m0 + r;
            s8v v = {0, 0, 0, 0, 0, 0, 0, 0};
            if (gw < NN_) v = *(const s8v*)&zT[zb + (long long)gw * KC_ + k0 + (c << 3)];
            *(s8v*)&As[pb][r * 64 + ((c ^ (r & 7)) << 3)] = v;
        }
#pragma unroll
        for (int i = 0; i < 4; i++) {
            int idx = tid + (i << 8);
            int r = idx >> 4, c4 = idx & 15;
            long long widx = (long long)(n0 + r) * KC_ + k0 + (c4 << 2);
            float4 fu = *(const float4*)(Wu + widx);
            float4 fc = *(const float4*)(Wc + widx);
            s4v vu = {f2s(fu.x), f2s(fu.y), f2s(fu.z), f2s(fu.w)};
            s4v vc = {f2s(fc.x), f2s(fc.y), f2s(fc.z), f2s(fc.w)};
            int di = r * 64 + (((c4 >> 1) ^ (r & 7)) << 3) + ((c4 & 1) << 2);
            *(s4v*)&Bu[pb][di] = vu;
            *(s4v*)&Bc[pb][di] = vc;
        }
    };

    stage(0, 0);
    __syncthreads();
    int pp = 0;
    for (int t = 0; t < 20; ++t) {
        if (t < 19) stage((t + 1) << 6, pp ^ 1);
#pragma unroll
        for (int ks = 0; ks < 64; ks += 32) {
            const int cb = ks >> 3;
            s8v af[2], bfu[4], bfc[4];
#pragma unroll
            for (int i = 0; i < 2; i++) {
                int rr = wid * 32 + i * 16 + l15;
                af[i] = *(const s8v*)&As[pp][SWZ(rr, cb)];
            }
#pragma unroll
            for (int j = 0; j < 4; j++) {
                int rr = j * 16 + l15;
                bfu[j] = *(const s8v*)&Bu[pp][SWZ(rr, cb)];
                bfc[j] = *(const s8v*)&Bc[pp][SWZ(rr, cb)];
            }
#pragma unroll
            for (int i = 0; i < 2; i++)
#pragma unroll
                for (int j = 0; j < 4; j++) {
                    aU[i][j] = MFMA(af[i], bfu[j], aU[i][j]);
                    aC[i][j] = MFMA(af[i], bfc[j], aC[i][j]);
                }
        }
        __syncthreads();
        pp ^= 1;
    }

#pragma unroll
    for (int i = 0; i < 2; i++) {
        int wbase = m0 + wid * 32 + i * 16 + q * 4;
#pragma unroll
        for (int j = 0; j < 4; j++) {
            int och = n0 + j * 16 + l15;
            float bvu = bu[och];
            float bvc = bc[och];
#pragma unroll
            for (int r = 0; r < 4; r++) {
                int w = wbase + r;
                if (w >= NN_) continue;
                float u = 1.f / (1.f + __expf(-(aU[i][j][r] + bvu)));
                float cg = tanhf(aC[i][j][r] + bvc);
                float hv = bf2f(hnT[((long long)b * NN_ + w) * 256 + och]);
                out[((long long)b * NU_ + och) * NN_ + w] = u * hv + (1.f - u) * cg;
            }
        }
    }
}

// inp[(b,n),c] = h[b,c,n] + embed[n,c] * mlt[b,n]  (32x32 LDS transpose of h)
__global__ __launch_bounds__(256) void build_inp_k(
    const float* __restrict__ h, const float* __restrict__ embed,
    const float* __restrict__ mlt, bf16* __restrict__ inp)
{
    __shared__ float t[32][33];
    const int b = blockIdx.z;
    const int n0 = blockIdx.x * 32, c0 = blockIdx.y * 32;
    const int t5 = threadIdx.x & 31, t8 = threadIdx.x >> 5;
#pragma unroll
    for (int r = 0; r < 4; r++) {
        int c = c0 + t8 + r * 8;
        int n = n0 + t5;
        t[t8 + r * 8][t5] = (n < NN_) ? h[((long long)b * 256 + c) * NN_ + n] : 0.f;
    }
    __syncthreads();
#pragma unroll
    for (int r = 0; r < 4; r++) {
        int n = n0 + t8 + r * 8;
        int c = c0 + t5;
        if (n < NN_) {
            float v = t[t5][t8 + r * 8] + embed[n * 256 + c] * mlt[b * NN_ + n];
            inp[((long long)b * NN_ + n) * 256 + c] = f2bf(v);
        }
    }
}

// out = LN(x + y) (optional tanh). One wave per 256-elem row, no barriers.
__global__ __launch_bounds__(256) void add_ln_k(
    const bf16* __restrict__ xr, const bf16* __restrict__ yr,
    const float* __restrict__ w, const float* __restrict__ bb,
    bf16* __restrict__ out, int do_tanh)
{
    const int lane = threadIdx.x & 63, wv = threadIdx.x >> 6;
    const long long row = (long long)blockIdx.x * 4 + wv;
    const long long base = row * 256 + lane * 4;
    s4v xv = *(const s4v*)((const short*)xr + base);
    s4v yv = *(const s4v*)((const short*)yr + base);
    float v[4];
    float sum = 0.f;
#pragma unroll
    for (int i = 0; i < 4; i++) {
        short sx = xv[i], sy = yv[i];
        v[i] = bf2f(*(bf16*)&sx) + bf2f(*(bf16*)&sy);
        sum += v[i];
    }
#pragma unroll
    for (int s = 1; s < 64; s <<= 1) sum += __shfl_xor(sum, s);
    float mu = sum * (1.f / 256.f);
    float vs = 0.f;
#pragma unroll
    for (int i = 0; i < 4; i++) { float d = v[i] - mu; vs += d * d; }
#pragma unroll
    for (int s = 1; s < 64; s <<= 1) vs += __shfl_xor(vs, s);
    float inv = rsqrtf(vs * (1.f / 256.f) + 1e-5f);
    s4v ov;
#pragma unroll
    for (int i = 0; i < 4; i++) {
        float r = (v[i] - mu) * inv * w[lane * 4 + i] + bb[lane * 4 + i];
        if (do_tanh) r = tanhf(r);
        ov[i] = f2s(r);
    }
    *(s4v*)((short*)out + base) = ov;
}

// hnT[(b,n),c] = step ? sqrt(1-dt)*h[b,c,n] - sqrt(dt)*eps[(b,n),c] : h[b,c,n]
__global__ __launch_bounds__(256) void hnew_k(
    const float* __restrict__ h, const bf16* __restrict__ epsb,
    const float* __restrict__ dt, const int* __restrict__ step, bf16* __restrict__ hnT)
{
    __shared__ float t[32][33];
    const int b = blockIdx.z;
    const int n0 = blockIdx.x * 32, c0 = blockIdx.y * 32;
    const int t5 = threadIdx.x & 31, t8 = threadIdx.x >> 5;
#pragma unroll
    for (int r = 0; r < 4; r++) {
        int c = c0 + t8 + r * 8;
        int n = n0 + t5;
        t[t8 + r * 8][t5] = (n < NN_) ? h[((long long)b * 256 + c) * NN_ + n] : 0.f;
    }
    __syncthreads();
    const int st = *step;
    const float d = dt[b];
    const float sa = sqrtf(fmaxf(1.f - d, 0.f)), sb = sqrtf(d);
#pragma unroll
    for (int r = 0; r < 4; r++) {
        int n = n0 + t8 + r * 8;
        int c = c0 + t5;
        if (n < NN_) {
            float hv = t[t5][t8 + r * 8];
            float val = hv;
            if (st != 0) {
                float ev = bf2f(epsb[((long long)b * NN_ + n) * 256 + c]);
                val = sa * hv - sb * ev;
            }
            hnT[((long long)b * NN_ + n) * 256 + c] = f2bf(val);
        }
    }
}

// zT[(b,n), c] = x[b,c,n] for c < 64 (transpose)
__global__ __launch_bounds__(256) void zx_k(
    const float* __restrict__ x, short* __restrict__ zT)
{
    __shared__ float t[32][33];
    const int b = blockIdx.z;
    const int n0 = blockIdx.x * 32, c0 = blockIdx.y * 32;
    const int t5 = threadIdx.x & 31, t8 = threadIdx.x >> 5;
#pragma unroll
    for (int r = 0; r < 4; r++) {
        int c = c0 + t8 + r * 8;
        int n = n0 + t5;
        t[t8 + r * 8][t5] = (n < NN_) ? x[((long long)b * DIN_ + c) * NN_ + n] : 0.f;
    }
    __syncthreads();
#pragma unroll
    for (int r = 0; r < 4; r++) {
        int n = n0 + t8 + r * 8;
        int c = c0 + t5;
        if (n < NN_)
            zT[((long long)b * NN_ + n) * KC_ + c] = f2s(t[t5][t8 + r * 8]);
    }
}

// zT[(b,n), 64+c] = hnT[(b,n), c]  (vectorized copy)
__global__ __launch_bounds__(256) void zcopy_k(
    const short* __restrict__ hnT, short* __restrict__ zT)
{
    long long u = (long long)blockIdx.x * 256 + threadIdx.x;  // < NB_*32
    long long row = u >> 5;
    int cu = (int)(u & 31);
    s8v v = *(const s8v*)(hnT + row * 256 + cu * 8);
    *(s8v*)(zT + row * KC_ + 64 + cu * 8) = v;
}

extern "C" void kernel_launch(void* const* d_in, const int* in_sizes, int n_in,
                              void* d_out, int out_size, void* d_ws, size_t ws_size,
                              hipStream_t stream) {
    const float* x          = (const float*)d_in[0];
    const float* delta_t    = (const float*)d_in[1];
    const float* h          = (const float*)d_in[2];
    const float* adj        = (const float*)d_in[3];
    const float* mlt        = (const float*)d_in[5];
    const int*  step        = (const int*)d_in[7];
    const float* embed      = (const float*)d_in[8];
    const float* in_proj_w  = (const float*)d_in[9];
    const float* in_proj_b  = (const float*)d_in[10];
    const float* out_proj_w = (const float*)d_in[11];
    const float* out_proj_b = (const float*)d_in[12];
    const float* ln1_w      = (const float*)d_in[13];
    const float* ln1_b      = (const float*)d_in[14];
    const float* ln2_w      = (const float*)d_in[15];
    const float* ln2_b      = (const float*)d_in[16];
    const float* ffn_w1     = (const float*)d_in[17];
    const float* ffn_b1     = (const float*)d_in[18];
    const float* ffn_w2     = (const float*)d_in[19];
    const float* ffn_b2     = (const float*)d_in[20];
    const float* W_u        = (const float*)d_in[21];
    const float* b_u        = (const float*)d_in[22];
    const float* W_c        = (const float*)d_in[23];
    const float* b_c        = (const float*)d_in[24];
    float* out = (float*)d_out;
    bf16* ws   = (bf16*)d_ws;

    bf16* inp = ws;
    short* qk = (short*)(ws + 1 * NBD_);
    short* vt = (short*)(ws + 3 * NBD_);
    bf16* ao  = ws + 4 * NBD_ + 65536;
    bf16* o   = ws + 1 * NBD_;
    bf16* s   = ws + 2 * NBD_;
    bf16* f   = ws + 1 * NBD_;
    bf16* f2  = ws + 3 * NBD_;
    bf16* eps = ws + 2 * NBD_;
    bf16* hnT = ws;
    short* zT = (short*)(ws + 1 * NBD_);
    short* wext = (short*)(ws + 6 * NBD_);

    const size_t need = (size_t)(6 * NBD_ + WEXT_N) * 2;
    const bool fast = ws_size >= need;   // capture-time host decision

    short* wuc  = wext + WU_OFF;         // [512][1280]: rows 0..255 Wu, 256..511 Wc
    short* ipb  = wext + IP_OFF;
    short* opb  = wext + OP_OFF;
    short* f1b  = wext + F1_OFF;
    short* f2b  = wext + F2_OFF;
    short* adjb = wext + ADJ_OFF;

    // 0. one-shot fp32 -> bf16 weight conversion
    if (fast)
        cvt_w_k<<<dim3(1024), dim3(256), 0, stream>>>(
            W_u, W_c, in_proj_w, out_proj_w, ffn_w1, ffn_w2, adj, wext);

    // 1. inp = h^T + embed * mlt   ((b,n) rows)
    build_inp_k<<<dim3(7, 8, 256), dim3(256), 0, stream>>>(h, embed, mlt, inp);

    // 2. qkv GEMM: Q,K -> qk rows (512); V -> vt transposed
    if (fast)
        gemm128<0><<<dim3(6, 416), dim3(256), 0, stream>>>(
            (const short*)inp, 256, ipb, 256, in_proj_b,
            (bf16*)qk, 512, 256, 0, vt, nullptr, nullptr, nullptr, nullptr);
    else
        gemm_nk0<<<dim3(6, 414), dim3(256), 0, stream>>>(
            (const short*)inp, 256, in_proj_w, 256, in_proj_b,
            (bf16*)qk, 512, NB_, 768, 256, 0, vt);

    // 3. MFMA attention v2 (LDS-shared K/V, XCD-swizzled)
    attn_k<<<dim3(4, 256), dim3(256), 0, stream>>>(qk, vt, ao);

    // 4. o = ao @ out_proj^T + b
    if (fast)
        gemm128<0><<<dim3(2, 416), dim3(256), 0, stream>>>(
            (const short*)ao, 256, opb, 256, out_proj_b,
            o, 256, 256, 0, nullptr, nullptr, nullptr, nullptr, nullptr);
    else
        gemm_nk0<<<dim3(2, 414), dim3(256), 0, stream>>>(
            (const short*)ao, 256, out_proj_w, 256, out_proj_b, o, 256, NB_, 256, 256, 0, nullptr);

    // 5. s = LN1(inp + o)
    add_ln_k<<<dim3(NB_ / 4), dim3(256), 0, stream>>>(inp, o, ln1_w, ln1_b, s, 0);

    // 6. f = relu(s @ ffn_w1^T + b)
    if (fast)
        gemm128<0><<<dim3(2, 416), dim3(256), 0, stream>>>(
            (const short*)s, 256, f1b, 256, ffn_b1,
            f, 256, 256, 3, nullptr, nullptr, nullptr, nullptr, nullptr);
    else
        gemm_nk0<<<dim3(2, 414), dim3(256), 0, stream>>>(
            (const short*)s, 256, ffn_w1, 256, ffn_b1, f, 256, NB_, 256, 256, 3, nullptr);

    // 7. f2 = f @ ffn_w2^T + b
    if (fast)
        gemm128<0><<<dim3(2, 416), dim3(256), 0, stream>>>(
            (const short*)f, 256, f2b, 256, ffn_b2,
            f2, 256, 256, 0, nullptr, nullptr, nullptr, nullptr, nullptr);
    else
        gemm_nk0<<<dim3(2, 414), dim3(256), 0, stream>>>(
            (const short*)f, 256, ffn_w2, 256, ffn_b2, f2, 256, NB_, 256, 256, 0, nullptr);

    // 8. eps = tanh(LN2(s + f2))   (in-place over s)
    add_ln_k<<<dim3(NB_ / 4), dim3(256), 0, stream>>>(s, f2, ln2_w, ln2_b, eps, 1);

    // 9. hnT = step ? sqrt(1-dt)*h - sqrt(dt)*eps : h   ((b,n,c) layout)
    hnew_k<<<dim3(7, 8, 256), dim3(256), 0, stream>>>(h, eps, delta_t, step, hnT);

    // 10. zT cols 0..63 = x^T; 11. cols 64..319 = hnT
    zx_k<<<dim3(7, 2, 256), dim3(256), 0, stream>>>(x, zT);
    zcopy_k<<<dim3(6624), dim3(256), 0, stream>>>((const short*)hnT, zT);

    // 12. diffusion orders 1..3
    if (fast) {
        diff_k<1><<<dim3(3, 2, 256), dim3(256), 0, stream>>>(adj, adjb, zT, zT, 0, 320);
        diff_k<1><<<dim3(3, 2, 256), dim3(256), 0, stream>>>(adj, adjb, zT, zT, 320, 640);
        diff_k<1><<<dim3(3, 2, 256), dim3(256), 0, stream>>>(adj, adjb, zT, zT, 640, 960);
    } else {
        diff_k<0><<<dim3(3, 2, 256), dim3(256), 0, stream>>>(adj, nullptr, zT, zT, 0, 320);
        diff_k<0><<<dim3(3, 2, 256), dim3(256), 0, stream>>>(adj, nullptr, zT, zT, 320, 640);
        diff_k<0><<<dim3(3, 2, 256), dim3(256), 0, stream>>>(adj, nullptr, zT, zT, 640, 960);
    }

    // 13. fused gates + combine -> out (fp32): flat GEMM M=NB_, N=512 (u/c interleaved)
    if (fast)
        gemm128<1><<<dim3(4, 416), dim3(256), 0, stream>>>(
            zT, KC_, wuc, KC_, nullptr,
            nullptr, 0, KC_, 0, nullptr, b_u, b_c, hnT, out);
    else
        gates_k0<<<dim3(4, 2, 256), dim3(256), 0, stream>>>(
            zT, W_u, W_c, b_u, b_c, hnT, out);

    (void)in_sizes; (void)n_in; (void)out_size; (void)ws_size;
}

// Round 13
// 661.123 us; speedup vs baseline: 1.2533x; 1.0202x over previous
//
#include <hip/hip_runtime.h>
#include <hip/hip_bf16.h>

typedef __hip_bfloat16 bf16;
typedef __attribute__((ext_vector_type(8))) short s8v;   // 8 bf16 in 4 VGPRs
typedef __attribute__((ext_vector_type(4))) short s4v;   // 4 bf16 in 2 VGPRs
typedef __attribute__((ext_vector_type(4))) float f4v;   // mfma accumulator

#define MFMA(a, b, c) __builtin_amdgcn_mfma_f32_16x16x32_bf16(a, b, c, 0, 0, 0)

#define B_    256
#define DIN_  64
#define NU_   256
#define NN_   207
#define KC_   1280
#define NB_   (NN_ * B_)       // 52992 transformer rows; 52992 = 414*128
#define NBD_  13565952LL       // NB_ * 256 elements (one ws region)

// bf16 weight scratch layout (shorts), appended after the 6 proven regions
#define WU_OFF   0LL           // Wu rows 0..255   } contiguous => WUC[512][1280]
#define WC_OFF   327680LL      // Wc rows 256..511 }
#define IP_OFF   655360LL
#define OP_OFF   851968LL
#define F1_OFF   917504LL
#define F2_OFF   983040LL
#define ADJ_OFF  1048576LL     // adj padded to [207][256], zeros in pad
#define WEXT_N   (ADJ_OFF + 207LL * 256LL)   // 1101568 shorts

__device__ __forceinline__ float bf2f(bf16 v) { return __bfloat162float(v); }
__device__ __forceinline__ bf16  f2bf(float v) { return __float2bfloat16(v); }
__device__ __forceinline__ short f2s(float v) { bf16 t = __float2bfloat16(v); return *(short*)&t; }

// direct global->LDS DMA, 16B per lane; lds dest must be wave-uniform
__device__ __forceinline__ void gl16(const void* g, void* l) {
    __builtin_amdgcn_global_load_lds(
        (const __attribute__((address_space(1))) void*)g,
        (__attribute__((address_space(3))) void*)l, 16, 0, 0);
}

// Swizzled LDS tile layout: tile row stride 64 shorts; 16B chunk c of row r
// lives at position c^(r&7). gl16 writes linearly (lane -> seg*512+lane*16B),
// so the global SOURCE chunk is pre-swizzled with chunk^(lane>>3).
#define SWZ(rr, cb) ((rr) * 64 + ((((cb) + q) ^ ((rr) & 7)) << 3))

// ---------------------------------------------------------------------------
// One-shot fp32 -> bf16 weight conversion into wext.
// ---------------------------------------------------------------------------
__global__ __launch_bounds__(256) void cvt_w_k(
    const float* __restrict__ Wu, const float* __restrict__ Wc,
    const float* __restrict__ ip, const float* __restrict__ op,
    const float* __restrict__ f1, const float* __restrict__ f2,
    const float* __restrict__ adj, short* __restrict__ dst)
{
    long long t = (long long)blockIdx.x * 256 + threadIdx.x;
    long long nt = (long long)gridDim.x * 256;
    for (long long g = t; g < 262144; g += nt) {   // 1048576 elems / 4
        long long e = g * 4;
        const float* src; long long off;
        if (e < WC_OFF)      { src = Wu; off = e; }
        else if (e < IP_OFF) { src = Wc; off = e - WC_OFF; }
        else if (e < OP_OFF) { src = ip; off = e - IP_OFF; }
        else if (e < F1_OFF) { src = op; off = e - OP_OFF; }
        else if (e < F2_OFF) { src = f1; off = e - F1_OFF; }
        else                 { src = f2; off = e - F2_OFF; }
        float4 fv = *(const float4*)(src + off);
        s4v v = {f2s(fv.x), f2s(fv.y), f2s(fv.z), f2s(fv.w)};
        *(s4v*)(dst + e) = v;
    }
    short* adst = dst + ADJ_OFF;
    for (long long g = t; g < 207LL * 256LL; g += nt) {
        int r = (int)(g >> 8), c = (int)(g & 255);
        adst[g] = (c < NN_) ? f2s(adj[r * NN_ + c]) : (short)0;
    }
}

// ---------------------------------------------------------------------------
// m97-structure MFMA GEMM (fast path): 256 thr / 4 waves, tile 128x128,
// BK=64, SINGLE 32 KB LDS buffer, plain stage->sync->compute->sync loop.
// ~3 blocks/CU -> inter-block overlap hides barrier drains (m97 mechanism).
// XCD-aware remap: grid = (nswz, 416); m-tiles 414 pad to 416=52x8.
// EPI=0: C = act(A@W^T + bias); vt!=null => cols>=512 transposed to vt.
// EPI=1: gates mode (lane-split transcendentals, LDS-staged coalesced out).
// ---------------------------------------------------------------------------
template<int EPI>
__global__ __launch_bounds__(256, 3) void gemm128(
    const short* __restrict__ A, int lda,
    const short* __restrict__ Wb, int ldb,
    const float* __restrict__ bias, bf16* __restrict__ C, int ldc,
    int K, int act, short* __restrict__ vt,
    const float* __restrict__ bu, const float* __restrict__ bc,
    const bf16* __restrict__ hnT, float* __restrict__ outF)
{
    __shared__ __align__(16) short Tiles[2][128 * 64];   // As | Bs ; reused as 32KB fp32 out-stage
    short* As = Tiles[0];
    short* Bs = Tiles[1];
    float* outS = (float*)&Tiles[0][0];                  // 8192 floats = 64 och x 128 m
    const int w_ = blockIdx.y * gridDim.x + blockIdx.x;   // dispatch-order id
    const int nswz = gridDim.x;
    const int xr = w_ & 7, sidx = w_ >> 3;
    const int mt = xr + 8 * (sidx / nswz);
    const int nt = sidx % nswz;
    if (mt >= 414) return;                                // idle pad block
    const int m0 = mt * 128, n0 = nt * 128;
    const int tid = threadIdx.x;
    const int lane = tid & 63, wid = tid >> 6;
    const int l15 = lane & 15, q = lane >> 4;
    const int wm = (wid >> 1) * 64, wn = (wid & 1) * 64;
    const int seg_r = lane >> 3;
    const int csw8 = ((lane & 7) ^ seg_r) << 3;
    const int nk = K >> 6;

    // hoisted global pointers (include swizzled chunk); advance by k0
    const short* ap[4];
    const short* bp[4];
#pragma unroll
    for (int i = 0; i < 4; i++) {
        int gm = m0 + (wid * 4 + i) * 8 + seg_r;
        ap[i] = A + (long long)gm * lda + csw8;
        int gn = n0 + (wid * 4 + i) * 8 + seg_r;
        int pr = EPI ? ((gn & 1) * 256 + (gn >> 1)) : gn;
        bp[i] = Wb + (long long)pr * ldb + csw8;
    }

    f4v acc[4][4] = {};

    for (int t = 0; t < nk; ++t) {
        const int k0 = t << 6;
#pragma unroll
        for (int i = 0; i < 4; i++) {
            gl16(ap[i] + k0, &As[(wid * 4 + i) * 512]);
            gl16(bp[i] + k0, &Bs[(wid * 4 + i) * 512]);
        }
        __syncthreads();
#pragma unroll
        for (int ks = 0; ks < 64; ks += 32) {
            const int cb = ks >> 3;
            s8v af[4], bfv[4];
#pragma unroll
            for (int i = 0; i < 4; i++) {
                int rr = wm + i * 16 + l15;
                af[i] = *(const s8v*)&As[SWZ(rr, cb)];
            }
#pragma unroll
            for (int j = 0; j < 4; j++) {
                int rr = wn + j * 16 + l15;
                bfv[j] = *(const s8v*)&Bs[SWZ(rr, cb)];
            }
#pragma unroll
            for (int i = 0; i < 4; i++)
#pragma unroll
                for (int j = 0; j < 4; j++)
                    acc[i][j] = MFMA(af[i], bfv[j], acc[i][j]);
        }
        __syncthreads();
    }

    if (EPI == 0) {
#pragma unroll
        for (int i = 0; i < 4; i++) {
            int mbase = m0 + wm + i * 16 + q * 4;
#pragma unroll
            for (int j = 0; j < 4; j++) {
                int n = n0 + wn + j * 16 + l15;
                float bv = bias ? bias[n] : 0.f;
#pragma unroll
                for (int r = 0; r < 4; r++) {
                    int m = mbase + r;
                    float v = acc[i][j][r] + bv;
                    if (act == 3) v = fmaxf(v, 0.f);
                    if (vt && n >= 512) {
                        int d = n - 512;
                        int bb = m / NN_;
                        int node = m - bb * NN_;
                        vt[((long long)bb * 256 + d) * 208 + node] = f2s(v);
                    } else {
                        C[(long long)m * ldc + n] = f2bf(v);
                    }
                }
            }
        }
    } else {
        const int odd = l15 & 1;
#pragma unroll
        for (int i = 0; i < 4; i++) {
            int mlbase = wm + i * 16 + q * 4;
#pragma unroll
            for (int j = 0; j < 4; j++) {
                int n = n0 + wn + j * 16 + l15;
                int och = n >> 1;
                int ochl = (wn + j * 16 + l15) >> 1;
                float bv = odd ? bc[och] : bu[och];
#pragma unroll
                for (int r = 0; r < 4; r++) {
                    int ml = mlbase + r;
                    float pre = acc[i][j][r] + bv;
                    float myv;
                    if (odd) {                       // c-gate lane: tanh via exp
                        float e = __expf(2.f * pre);
                        myv = (e - 1.f) / (e + 1.f);
                    } else {                         // u-gate lane: sigmoid
                        myv = 1.f / (1.f + __expf(-pre));
                    }
                    float oth = __shfl_xor(myv, 1);  // even lane <- tanh(c)
                    if (!odd) {
                        int m = m0 + ml;
                        float hv = bf2f(hnT[(long long)m * 256 + och]);
                        float res = myv * hv + (1.f - myv) * oth;
                        outS[ochl * 128 + (ml ^ ((ochl & 7) << 2))] = res;
                    }
                }
            }
        }
        __syncthreads();
        // coalesced out write: wave covers 64 consecutive m per och row
        for (int orow = tid >> 6; orow < 64; orow += 4) {
            int och = (n0 >> 1) + orow;
            const int sx = (orow & 7) << 2;
#pragma unroll
            for (int half = 0; half < 2; half++) {
                int ml = lane + half * 64;
                float v = outS[orow * 128 + (ml ^ sx)];
                int m = m0 + ml;
                int bb = m / NN_;
                int node = m - bb * NN_;
                outF[((long long)bb * NU_ + och) * NN_ + node] = v;
            }
        }
    }
}

// ---------------------------------------------------------------------------
// Fallback (slow path) GEMM: fp32 weights, reg-staged, 2-buffer.
// ---------------------------------------------------------------------------
__global__ __launch_bounds__(256) void gemm_nk0(
    const short* __restrict__ A, int lda,
    const float* __restrict__ Wf, int ldb,
    const float* __restrict__ bias, bf16* __restrict__ C, int ldc,
    int M, int N, int K, int act, short* __restrict__ vt)
{
    __shared__ __align__(16) short As[2][128 * 64];
    __shared__ __align__(16) short Bs[2][128 * 64];
    const int tid = threadIdx.x;
    const int lane = tid & 63, wid = tid >> 6;
    const int l15 = lane & 15, q = lane >> 4;
    const int wm = (wid >> 1) * 64, wn = (wid & 1) * 64;
    const int m0 = blockIdx.y * 128, n0 = blockIdx.x * 128;

    f4v acc[4][4] = {};
    const int nk = K >> 6;

    auto stage = [&](int k0, int pb) {
#pragma unroll
        for (int i = 0; i < 4; i++) {
            int idx = tid + (i << 8);
            int r = idx >> 3, c = idx & 7;
            int gm = m0 + r, gk = k0 + (c << 3);
            s8v v = {0, 0, 0, 0, 0, 0, 0, 0};
            if (gm < M) v = *(const s8v*)(A + (long long)gm * lda + gk);
            *(s8v*)&As[pb][r * 64 + ((c ^ (r & 7)) << 3)] = v;
        }
#pragma unroll
        for (int i = 0; i < 8; i++) {
            int idx = tid + (i << 8);
            int r = idx >> 4, c4 = idx & 15;
            int gn = n0 + r, gk = k0 + (c4 << 2);
            s4v v = {0, 0, 0, 0};
            if (gn < N) {
                float4 fx = *(const float4*)(Wf + (long long)gn * ldb + gk);
                v[0] = f2s(fx.x); v[1] = f2s(fx.y); v[2] = f2s(fx.z); v[3] = f2s(fx.w);
            }
            *(s4v*)&Bs[pb][r * 64 + (((c4 >> 1) ^ (r & 7)) << 3) + ((c4 & 1) << 2)] = v;
        }
    };

    stage(0, 0);
    __syncthreads();
    int pp = 0;
    for (int t = 0; t < nk; ++t) {
        if (t + 1 < nk) stage((t + 1) << 6, pp ^ 1);
#pragma unroll
        for (int ks = 0; ks < 64; ks += 32) {
            const int cb = ks >> 3;
            s8v af[4], bfv[4];
#pragma unroll
            for (int i = 0; i < 4; i++) {
                int rr = wm + i * 16 + l15;
                af[i] = *(const s8v*)&As[pp][SWZ(rr, cb)];
            }
#pragma unroll
            for (int j = 0; j < 4; j++) {
                int rr = wn + j * 16 + l15;
                bfv[j] = *(const s8v*)&Bs[pp][SWZ(rr, cb)];
            }
#pragma unroll
            for (int i = 0; i < 4; i++)
#pragma unroll
                for (int j = 0; j < 4; j++)
                    acc[i][j] = MFMA(af[i], bfv[j], acc[i][j]);
        }
        __syncthreads();
        pp ^= 1;
    }

#pragma unroll
    for (int i = 0; i < 4; i++) {
        int mbase = m0 + wm + i * 16 + q * 4;
#pragma unroll
        for (int j = 0; j < 4; j++) {
            int n = n0 + wn + j * 16 + l15;
            if (n >= N) continue;
            float bv = bias ? bias[n] : 0.f;
#pragma unroll
            for (int r = 0; r < 4; r++) {
                int m = mbase + r;
                if (m >= M) continue;
                float v = acc[i][j][r] + bv;
                if (act == 3) v = fmaxf(v, 0.f);
                if (vt && n >= 512) {
                    int d = n - 512;
                    int bb = m / NN_;
                    int node = m - bb * NN_;
                    vt[((long long)bb * 256 + d) * 208 + node] = f2s(v);
                } else {
                    C[(long long)m * ldc + n] = f2bf(v);
                }
            }
        }
    }
}

// ---------------------------------------------------------------------------
// MFMA attention v2: one block per (64-q tile, b), 4 waves.
// K and V staged in a shared 16 KB LDS buffer once per block.
// XCD swizzle: grid(4,256)=1024=8*128; same-b q-tiles co-locate.
// ---------------------------------------------------------------------------
__global__ __launch_bounds__(256, 3) void attn_k(
    const short* __restrict__ qk, const short* __restrict__ vt,
    bf16* __restrict__ ao)
{
    __shared__ __align__(16) short KV[8192];        // 16 KB K/V staging
    __shared__ __align__(16) short Plds[64 * 232];  // 29.75 KB
    __shared__ float sums[64];
    const int tid = threadIdx.x;
    const int lane = tid & 63, w = tid >> 6;
    const int l15 = lane & 15, quad = lane >> 4;
    const int w_ = blockIdx.y * gridDim.x + blockIdx.x;
    const int xr = w_ & 7, sidx = w_ >> 3;
    const int b = xr + 8 * (sidx >> 2);
    const int q0 = (sidx & 3) * 64;
    const long long rowcap = (long long)NB_ - 1;
    const long long bbase = (long long)b * NN_;

    long long qrow = bbase + q0 + w * 16 + l15;
    if (qrow > rowcap) qrow = rowcap;
    const short* qp = qk + qrow * 512;
    s8v bq[8];
#pragma unroll
    for (int ks = 0; ks < 8; ks++)
        bq[ks] = *(const s8v*)(qp + ks * 32 + quad * 8);

    // Phase 1: QK^T with K staged in 32-row chunks (shared across waves)
    f4v sacc[13] = {};
    const int sr2 = lane >> 5;          // row within 1KB pair
    const int c32 = lane & 31;          // 16B col chunk (32 per 512B row)
#pragma unroll
    for (int jc = 0; jc < 7; ++jc) {
#pragma unroll
        for (int i = 0; i < 4; i++) {   // stage 32 rows: 16 x 1KB, 4/wave
            int lrow = w * 8 + i * 2 + sr2;
            int jrow = jc * 32 + lrow;
            if (jrow > NN_ - 1) jrow = NN_ - 1;
            gl16(qk + (bbase + jrow) * 512 + 256 + ((c32 ^ (lrow & 7)) << 3),
                 &KV[(w * 8 + i * 2) * 256]);
        }
        __syncthreads();
#pragma unroll
        for (int jf2 = 0; jf2 < 2; jf2++) {
            const int jf = jc * 2 + jf2;
            if (jf < 13) {
                const int lrow = jf2 * 16 + l15;
#pragma unroll
                for (int ks = 0; ks < 8; ks++) {
                    s8v a = *(const s8v*)&KV[lrow * 256 + (((ks * 4 + quad) ^ (lrow & 7)) << 3)];
                    sacc[jf] = MFMA(a, bq[ks], sacc[jf]);
                }
            }
        }
        __syncthreads();
    }

    // softmax over j for this lane's q
    float mx = -3.0e38f;
    float pv[13][4];
#pragma unroll
    for (int jf = 0; jf < 13; jf++)
#pragma unroll
        for (int r = 0; r < 4; r++) {
            int j = jf * 16 + quad * 4 + r;
            float v = (j < NN_) ? sacc[jf][r] * 0.0625f : -3.0e38f;
            pv[jf][r] = v;
            mx = fmaxf(mx, v);
        }
    mx = fmaxf(mx, __shfl_xor(mx, 16));
    mx = fmaxf(mx, __shfl_xor(mx, 32));
    float sum = 0.f;
#pragma unroll
    for (int jf = 0; jf < 13; jf++)
#pragma unroll
        for (int r = 0; r < 4; r++) {
            float p = __expf(pv[jf][r] - mx);
            pv[jf][r] = p;
            sum += p;
        }
    sum += __shfl_xor(sum, 16);
    sum += __shfl_xor(sum, 32);

    const int qloc = w * 16 + l15;
#pragma unroll
    for (int jf = 0; jf < 13; jf++)
#pragma unroll
        for (int r = 0; r < 4; r++)
            Plds[qloc * 232 + jf * 16 + quad * 4 + r] = f2s(pv[jf][r]);
    if (quad == 0) sums[qloc] = 1.f / sum;
#pragma unroll
    for (int i = 0; i < 4; i++) {               // zero pad cols 208..223
        int u = tid + i * 256;
        Plds[(u >> 4) * 232 + 208 + (u & 15)] = 0;
    }
    __syncthreads();

    // Phase 2: PV with V staged per-ks (256 d-rows x 32 nodes, shared)
    const short* vbase = vt + (long long)b * 256 * 208;
    f4v oacc[16] = {};
    const int vr = lane >> 2;           // d row within 16
    const int vc = lane & 3;            // 16B chunk (4 per 64B row)
    for (int ks = 0; ks < 7; ks++) {
#pragma unroll
        for (int i = 0; i < 4; i++) {   // stage 16 KB: 16 x 1KB, 4/wave
            int d = w * 64 + i * 16 + vr;
            gl16(vbase + (long long)d * 208 + ks * 32 + ((vc ^ ((d >> 1) & 3)) << 3),
                 &KV[(w * 64 + i * 16) * 32]);
        }
        __syncthreads();
        s8v pa = *(const s8v*)&Plds[(w * 16 + l15) * 232 + ks * 32 + quad * 8];
#pragma unroll
        for (int df = 0; df < 16; df++) {
            const int dl = df * 16 + l15;
            s8v vb = *(const s8v*)&KV[dl * 32 + ((quad ^ ((dl >> 1) & 3)) << 3)];
            oacc[df] = MFMA(pa, vb, oacc[df]);
        }
        __syncthreads();
    }

#pragma unroll
    for (int df = 0; df < 16; df++) {
        int d = df * 16 + l15;
#pragma unroll
        for (int r = 0; r < 4; r++) {
            int ql = w * 16 + quad * 4 + r;
            int qg = q0 + ql;
            if (qg < NN_)
                ao[((long long)b * NN_ + qg) * 256 + d] = f2bf(oacc[df][r] * sums[ql]);
        }
    }
}

// ---------------------------------------------------------------------------
// Diffusion step in (b, node, chan) layout, batched over b.
// WB=1: adjb via global_load_lds (clamped rows); zT B-side reg-staged with
// async split (load regs early, ds_write after compute). Double-buffered.
// ---------------------------------------------------------------------------
template<int WB>
__global__ __launch_bounds__(256) void diff_k(
    const float* __restrict__ adj, const short* __restrict__ adjb,
    const short* __restrict__ zT_in,
    short* __restrict__ zT_out, int col_in, int col_out)
{
    __shared__ __align__(16) short As[2][128 * 64];
    __shared__ __align__(16) short Bs[2][128 * 64];
    const int tid = threadIdx.x;
    const int lane = tid & 63, wid = tid >> 6;
    const int l15 = lane & 15, q = lane >> 4;
    const int wm = (wid >> 1) * 64, wn = (wid & 1) * 64;
    const int m0 = blockIdx.y * 128, n0 = blockIdx.x * 128;
    const long long zb = (long long)blockIdx.z * NN_ * KC_;
    const int seg_r = lane >> 3, chunk = lane & 7;
    const int csw8 = (chunk ^ seg_r) << 3;
    const int bv_ = tid & 63, bcg = tid >> 6;   // B-stage coords

    f4v acc[4][4] = {};

    auto stageA = [&](int k0, int pb) {
        if (WB) {
#pragma unroll
            for (int i = 0; i < 4; i++) {
                int seg = wid * 4 + i;
                int gm = m0 + seg * 8 + seg_r;
                if (gm > NN_ - 1) gm = NN_ - 1;
                gl16(adjb + gm * 256 + k0 + csw8, &As[pb][seg * 512]);
            }
        } else {
#pragma unroll
            for (int i = 0; i < 32; i++) {
                int idx = tid + (i << 8);
                int r = idx >> 6, c = idx & 63;
                int gm = m0 + r, gk = k0 + c;
                short vv = (gm < NN_ && gk < NN_) ? f2s(adj[gm * NN_ + gk]) : (short)0;
                As[pb][r * 64 + (((c >> 3) ^ (r & 7)) << 3) + (c & 7)] = vv;
            }
        }
    };
    auto loadB = [&](int k0, s8v* breg) {
#pragma unroll
        for (int i = 0; i < 4; i++) {
            int gv = k0 + bv_, gc = n0 + (bcg + i * 4) * 8;
            s8v val = {0, 0, 0, 0, 0, 0, 0, 0};
            if (gv < NN_ && gc < 320)
                val = *(const s8v*)&zT_in[zb + (long long)gv * KC_ + col_in + gc];
            breg[i] = val;
        }
    };
    auto writeB = [&](s8v* breg, int pb) {
#pragma unroll
        for (int i = 0; i < 4; i++) {
            int cg = bcg + i * 4;
#pragma unroll
            for (int e = 0; e < 8; e++) {
                int row = cg * 8 + e;
                Bs[pb][row * 64 + (((bv_ >> 3) ^ (row & 7)) << 3) + (bv_ & 7)] = breg[i][e];
            }
        }
    };

    s8v breg[4];
    loadB(0, breg);
    stageA(0, 0);
    writeB(breg, 0);
    __syncthreads();
    int pp = 0;
    for (int t = 0; t < 4; ++t) {               // ceil(207/64) K-steps
        if (t < 3) { loadB((t + 1) << 6, breg); stageA((t + 1) << 6, pp ^ 1); }
#pragma unroll
        for (int ks = 0; ks < 64; ks += 32) {
            const int cb = ks >> 3;
            s8v af[4], bfv[4];
#pragma unroll
            for (int i = 0; i < 4; i++) {
                int rr = wm + i * 16 + l15;
                af[i] = *(const s8v*)&As[pp][SWZ(rr, cb)];
            }
#pragma unroll
            for (int j = 0; j < 4; j++) {
                int rr = wn + j * 16 + l15;
                bfv[j] = *(const s8v*)&Bs[pp][SWZ(rr, cb)];
            }
#pragma unroll
            for (int i = 0; i < 4; i++)
#pragma unroll
                for (int j = 0; j < 4; j++)
                    acc[i][j] = MFMA(af[i], bfv[j], acc[i][j]);
        }
        if (t < 3) writeB(breg, pp ^ 1);
        __syncthreads();
        pp ^= 1;
    }

#pragma unroll
    for (int i = 0; i < 4; i++) {
        int mbase = m0 + wm + i * 16 + q * 4;
#pragma unroll
        for (int j = 0; j < 4; j++) {
            int n = n0 + wn + j * 16 + l15;
            if (n >= 320) continue;
#pragma unroll
            for (int r = 0; r < 4; r++) {
                int m = mbase + r;
                if (m >= NN_) continue;
                zT_out[zb + (long long)m * KC_ + col_out + n] = f2s(acc[i][j][r]);
            }
        }
    }
}

// ---------------------------------------------------------------------------
// Fallback gates (slow path, fp32 weights).
// ---------------------------------------------------------------------------
__global__ __launch_bounds__(256) void gates_k0(
    const short* __restrict__ zT, const float* __restrict__ Wu,
    const float* __restrict__ Wc, const float* __restrict__ bu,
    const float* __restrict__ bc, const bf16* __restrict__ hnT,
    float* __restrict__ out)
{
    __shared__ __align__(16) short As[2][128 * 64];
    __shared__ __align__(16) short Bu[2][64 * 64];
    __shared__ __align__(16) short Bc[2][64 * 64];
    const int tid = threadIdx.x;
    const int lane = tid & 63, wid = tid >> 6;
    const int l15 = lane & 15, q = lane >> 4;
    const int b = blockIdx.z;
    const int m0 = blockIdx.y * 128;
    const int n0 = blockIdx.x * 64;
    const long long zb = (long long)b * NN_ * KC_;

    f4v aU[2][4] = {}, aC[2][4] = {};

    auto stage = [&](int k0, int pb) {
#pragma unroll
        for (int i = 0; i < 4; i++) {
            int idx = tid + (i << 8);
            int r = idx >> 3, c = idx & 7;
            int gw = m0 + r;
            s8v v = {0, 0, 0, 0, 0, 0, 0, 0};
            if (gw < NN_) v = *(const s8v*)&zT[zb + (long long)gw * KC_ + k0 + (c << 3)];
            *(s8v*)&As[pb][r * 64 + ((c ^ (r & 7)) << 3)] = v;
        }
#pragma unroll
        for (int i = 0; i < 4; i++) {
            int idx = tid + (i << 8);
            int r = idx >> 4, c4 = idx & 15;
            long long widx = (long long)(n0 + r) * KC_ + k0 + (c4 << 2);
            float4 fu = *(const float4*)(Wu + widx);
            float4 fc = *(const float4*)(Wc + widx);
            s4v vu = {f2s(fu.x), f2s(fu.y), f2s(fu.z), f2s(fu.w)};
            s4v vc = {f2s(fc.x), f2s(fc.y), f2s(fc.z), f2s(fc.w)};
            int di = r * 64 + (((c4 >> 1) ^ (r & 7)) << 3) + ((c4 & 1) << 2);
            *(s4v*)&Bu[pb][di] = vu;
            *(s4v*)&Bc[pb][di] = vc;
        }
    };

    stage(0, 0);
    __syncthreads();
    int pp = 0;
    for (int t = 0; t < 20; ++t) {
        if (t < 19) stage((t + 1) << 6, pp ^ 1);
#pragma unroll
        for (int ks = 0; ks < 64; ks += 32) {
            const int cb = ks >> 3;
            s8v af[2], bfu[4], bfc[4];
#pragma unroll
            for (int i = 0; i < 2; i++) {
                int rr = wid * 32 + i * 16 + l15;
                af[i] = *(const s8v*)&As[pp][SWZ(rr, cb)];
            }
#pragma unroll
            for (int j = 0; j < 4; j++) {
                int rr = j * 16 + l15;
                bfu[j] = *(const s8v*)&Bu[pp][SWZ(rr, cb)];
                bfc[j] = *(const s8v*)&Bc[pp][SWZ(rr, cb)];
            }
#pragma unroll
            for (int i = 0; i < 2; i++)
#pragma unroll
                for (int j = 0; j < 4; j++) {
                    aU[i][j] = MFMA(af[i], bfu[j], aU[i][j]);
                    aC[i][j] = MFMA(af[i], bfc[j], aC[i][j]);
                }
        }
        __syncthreads();
        pp ^= 1;
    }

#pragma unroll
    for (int i = 0; i < 2; i++) {
        int wbase = m0 + wid * 32 + i * 16 + q * 4;
#pragma unroll
        for (int j = 0; j < 4; j++) {
            int och = n0 + j * 16 + l15;
            float bvu = bu[och];
            float bvc = bc[och];
#pragma unroll
            for (int r = 0; r < 4; r++) {
                int w = wbase + r;
                if (w >= NN_) continue;
                float u = 1.f / (1.f + __expf(-(aU[i][j][r] + bvu)));
                float cg = tanhf(aC[i][j][r] + bvc);
                float hv = bf2f(hnT[((long long)b * NN_ + w) * 256 + och]);
                out[((long long)b * NU_ + och) * NN_ + w] = u * hv + (1.f - u) * cg;
            }
        }
    }
}

// inp[(b,n),c] = h[b,c,n] + embed[n,c] * mlt[b,n]  (32x32 LDS transpose of h)
__global__ __launch_bounds__(256) void build_inp_k(
    const float* __restrict__ h, const float* __restrict__ embed,
    const float* __restrict__ mlt, bf16* __restrict__ inp)
{
    __shared__ float t[32][33];
    const int b = blockIdx.z;
    const int n0 = blockIdx.x * 32, c0 = blockIdx.y * 32;
    const int t5 = threadIdx.x & 31, t8 = threadIdx.x >> 5;
#pragma unroll
    for (int r = 0; r < 4; r++) {
        int c = c0 + t8 + r * 8;
        int n = n0 + t5;
        t[t8 + r * 8][t5] = (n < NN_) ? h[((long long)b * 256 + c) * NN_ + n] : 0.f;
    }
    __syncthreads();
#pragma unroll
    for (int r = 0; r < 4; r++) {
        int n = n0 + t8 + r * 8;
        int c = c0 + t5;
        if (n < NN_) {
            float v = t[t5][t8 + r * 8] + embed[n * 256 + c] * mlt[b * NN_ + n];
            inp[((long long)b * NN_ + n) * 256 + c] = f2bf(v);
        }
    }
}

// out = LN(x + y) (optional tanh). One wave per 256-elem row, no barriers.
__global__ __launch_bounds__(256) void add_ln_k(
    const bf16* __restrict__ xr, const bf16* __restrict__ yr,
    const float* __restrict__ w, const float* __restrict__ bb,
    bf16* __restrict__ out, int do_tanh)
{
    const int lane = threadIdx.x & 63, wv = threadIdx.x >> 6;
    const long long row = (long long)blockIdx.x * 4 + wv;
    const long long base = row * 256 + lane * 4;
    s4v xv = *(const s4v*)((const short*)xr + base);
    s4v yv = *(const s4v*)((const short*)yr + base);
    float v[4];
    float sum = 0.f;
#pragma unroll
    for (int i = 0; i < 4; i++) {
        short sx = xv[i], sy = yv[i];
        v[i] = bf2f(*(bf16*)&sx) + bf2f(*(bf16*)&sy);
        sum += v[i];
    }
#pragma unroll
    for (int s = 1; s < 64; s <<= 1) sum += __shfl_xor(sum, s);
    float mu = sum * (1.f / 256.f);
    float vs = 0.f;
#pragma unroll
    for (int i = 0; i < 4; i++) { float d = v[i] - mu; vs += d * d; }
#pragma unroll
    for (int s = 1; s < 64; s <<= 1) vs += __shfl_xor(vs, s);
    float inv = rsqrtf(vs * (1.f / 256.f) + 1e-5f);
    s4v ov;
#pragma unroll
    for (int i = 0; i < 4; i++) {
        float r = (v[i] - mu) * inv * w[lane * 4 + i] + bb[lane * 4 + i];
        if (do_tanh) r = tanhf(r);
        ov[i] = f2s(r);
    }
    *(s4v*)((short*)out + base) = ov;
}

// hnT[(b,n),c] = step ? sqrt(1-dt)*h[b,c,n] - sqrt(dt)*eps[(b,n),c] : h[b,c,n]
// Also writes zT[(b,n), 64+c] = same value (fused zcopy). SAFE only because
// eps now lives in region 0 (disjoint from zT regions 1..5); hnT shares
// region 0 with eps but at identical per-thread indices (load-then-store).
__global__ __launch_bounds__(256) void hnew_k(
    const float* __restrict__ h, const bf16* __restrict__ epsb,
    const float* __restrict__ dt, const int* __restrict__ step,
    bf16* __restrict__ hnT, short* __restrict__ zTs)
{
    __shared__ float t[32][33];
    const int b = blockIdx.z;
    const int n0 = blockIdx.x * 32, c0 = blockIdx.y * 32;
    const int t5 = threadIdx.x & 31, t8 = threadIdx.x >> 5;
#pragma unroll
    for (int r = 0; r < 4; r++) {
        int c = c0 + t8 + r * 8;
        int n = n0 + t5;
        t[t8 + r * 8][t5] = (n < NN_) ? h[((long long)b * 256 + c) * NN_ + n] : 0.f;
    }
    __syncthreads();
    const int st = *step;
    const float d = dt[b];
    const float sa = sqrtf(fmaxf(1.f - d, 0.f)), sb = sqrtf(d);
#pragma unroll
    for (int r = 0; r < 4; r++) {
        int n = n0 + t8 + r * 8;
        int c = c0 + t5;
        if (n < NN_) {
            float hv = t[t5][t8 + r * 8];
            float val = hv;
            if (st != 0) {
                float ev = bf2f(epsb[((long long)b * NN_ + n) * 256 + c]);
                val = sa * hv - sb * ev;
            }
            short sv = f2s(val);
            hnT[((long long)b * NN_ + n) * 256 + c] = *(bf16*)&sv;
            zTs[((long long)b * NN_ + n) * KC_ + 64 + c] = sv;
        }
    }
}

// zT[(b,n), c] = x[b,c,n] for c < 64 (transpose)
__global__ __launch_bounds__(256) void zx_k(
    const float* __restrict__ x, short* __restrict__ zT)
{
    __shared__ float t[32][33];
    const int b = blockIdx.z;
    const int n0 = blockIdx.x * 32, c0 = blockIdx.y * 32;
    const int t5 = threadIdx.x & 31, t8 = threadIdx.x >> 5;
#pragma unroll
    for (int r = 0; r < 4; r++) {
        int c = c0 + t8 + r * 8;
        int n = n0 + t5;
        t[t8 + r * 8][t5] = (n < NN_) ? x[((long long)b * DIN_ + c) * NN_ + n] : 0.f;
    }
    __syncthreads();
#pragma unroll
    for (int r = 0; r < 4; r++) {
        int n = n0 + t8 + r * 8;
        int c = c0 + t5;
        if (n < NN_)
            zT[((long long)b * NN_ + n) * KC_ + c] = f2s(t[t5][t8 + r * 8]);
    }
}

extern "C" void kernel_launch(void* const* d_in, const int* in_sizes, int n_in,
                              void* d_out, int out_size, void* d_ws, size_t ws_size,
                              hipStream_t stream) {
    const float* x          = (const float*)d_in[0];
    const float* delta_t    = (const float*)d_in[1];
    const float* h          = (const float*)d_in[2];
    const float* adj        = (const float*)d_in[3];
    const float* mlt        = (const float*)d_in[5];
    const int*  step        = (const int*)d_in[7];
    const float* embed      = (const float*)d_in[8];
    const float* in_proj_w  = (const float*)d_in[9];
    const float* in_proj_b  = (const float*)d_in[10];
    const float* out_proj_w = (const float*)d_in[11];
    const float* out_proj_b = (const float*)d_in[12];
    const float* ln1_w      = (const float*)d_in[13];
    const float* ln1_b      = (const float*)d_in[14];
    const float* ln2_w      = (const float*)d_in[15];
    const float* ln2_b      = (const float*)d_in[16];
    const float* ffn_w1     = (const float*)d_in[17];
    const float* ffn_b1     = (const float*)d_in[18];
    const float* ffn_w2     = (const float*)d_in[19];
    const float* ffn_b2     = (const float*)d_in[20];
    const float* W_u        = (const float*)d_in[21];
    const float* b_u        = (const float*)d_in[22];
    const float* W_c        = (const float*)d_in[23];
    const float* b_c        = (const float*)d_in[24];
    float* out = (float*)d_out;
    bf16* ws   = (bf16*)d_ws;

    // Region lifetimes:
    //  r0: inp (steps 1-5) -> eps (step 8-9) -> hnT (step 9-12; same idx map)
    //  r1-r2: qk -> o(r1)/f(r1), s(r2)
    //  r3: vt -> f2
    //  r4+65536: ao
    //  r1-r5: zT (steps 9-12; eps moved OUT of r2 to avoid the R11/R12
    //         fused-zcopy race where zT rows >=10598 alias r2)
    bf16* inp = ws;
    short* qk = (short*)(ws + 1 * NBD_);
    short* vt = (short*)(ws + 3 * NBD_);
    bf16* ao  = ws + 4 * NBD_ + 65536;
    bf16* o   = ws + 1 * NBD_;
    bf16* s   = ws + 2 * NBD_;
    bf16* f   = ws + 1 * NBD_;
    bf16* f2  = ws + 3 * NBD_;
    bf16* eps = ws;                      // region 0 (was r2: aliased zT -> race)
    bf16* hnT = ws;
    short* zT = (short*)(ws + 1 * NBD_);
    short* wext = (short*)(ws + 6 * NBD_);

    const size_t need = (size_t)(6 * NBD_ + WEXT_N) * 2;
    const bool fast = ws_size >= need;   // capture-time host decision

    short* wuc  = wext + WU_OFF;         // [512][1280]: rows 0..255 Wu, 256..511 Wc
    short* ipb  = wext + IP_OFF;
    short* opb  = wext + OP_OFF;
    short* f1b  = wext + F1_OFF;
    short* f2b  = wext + F2_OFF;
    short* adjb = wext + ADJ_OFF;

    // 0. one-shot fp32 -> bf16 weight conversion
    if (fast)
        cvt_w_k<<<dim3(1024), dim3(256), 0, stream>>>(
            W_u, W_c, in_proj_w, out_proj_w, ffn_w1, ffn_w2, adj, wext);

    // 1. inp = h^T + embed * mlt   ((b,n) rows)
    build_inp_k<<<dim3(7, 8, 256), dim3(256), 0, stream>>>(h, embed, mlt, inp);

    // 2. qkv GEMM: Q,K -> qk rows (512); V -> vt transposed
    if (fast)
        gemm128<0><<<dim3(6, 416), dim3(256), 0, stream>>>(
            (const short*)inp, 256, ipb, 256, in_proj_b,
            (bf16*)qk, 512, 256, 0, vt, nullptr, nullptr, nullptr, nullptr);
    else
        gemm_nk0<<<dim3(6, 414), dim3(256), 0, stream>>>(
            (const short*)inp, 256, in_proj_w, 256, in_proj_b,
            (bf16*)qk, 512, NB_, 768, 256, 0, vt);

    // 3. MFMA attention v2 (LDS-shared K/V, XCD-swizzled)
    attn_k<<<dim3(4, 256), dim3(256), 0, stream>>>(qk, vt, ao);

    // 4. o = ao @ out_proj^T + b
    if (fast)
        gemm128<0><<<dim3(2, 416), dim3(256), 0, stream>>>(
            (const short*)ao, 256, opb, 256, out_proj_b,
            o, 256, 256, 0, nullptr, nullptr, nullptr, nullptr, nullptr);
    else
        gemm_nk0<<<dim3(2, 414), dim3(256), 0, stream>>>(
            (const short*)ao, 256, out_proj_w, 256, out_proj_b, o, 256, NB_, 256, 256, 0, nullptr);

    // 5. s = LN1(inp + o)   (last read of inp/r0)
    add_ln_k<<<dim3(NB_ / 4), dim3(256), 0, stream>>>(inp, o, ln1_w, ln1_b, s, 0);

    // 6. f = relu(s @ ffn_w1^T + b)
    if (fast)
        gemm128<0><<<dim3(2, 416), dim3(256), 0, stream>>>(
            (const short*)s, 256, f1b, 256, ffn_b1,
            f, 256, 256, 3, nullptr, nullptr, nullptr, nullptr, nullptr);
    else
        gemm_nk0<<<dim3(2, 414), dim3(256), 0, stream>>>(
            (const short*)s, 256, ffn_w1, 256, ffn_b1, f, 256, NB_, 256, 256, 3, nullptr);

    // 7. f2 = f @ ffn_w2^T + b
    if (fast)
        gemm128<0><<<dim3(2, 416), dim3(256), 0, stream>>>(
            (const short*)f, 256, f2b, 256, ffn_b2,
            f2, 256, 256, 0, nullptr, nullptr, nullptr, nullptr, nullptr);
    else
        gemm_nk0<<<dim3(2, 414), dim3(256), 0, stream>>>(
            (const short*)f, 256, ffn_w2, 256, ffn_b2, f2, 256, NB_, 256, 256, 0, nullptr);

    // 8. eps = tanh(LN2(s + f2))   (writes region 0; s/f2 consumed here)
    add_ln_k<<<dim3(NB_ / 4), dim3(256), 0, stream>>>(s, f2, ln2_w, ln2_b, eps, 1);

    // 9. hnT = step ? sqrt(1-dt)*h - sqrt(dt)*eps : h; also zT cols 64..319
    hnew_k<<<dim3(7, 8, 256), dim3(256), 0, stream>>>(h, eps, delta_t, step, hnT, zT);

    // 10. zT cols 0..63 = x^T
    zx_k<<<dim3(7, 2, 256), dim3(256), 0, stream>>>(x, zT);

    // 11. diffusion orders 1..3 (chained, proven)
    if (fast) {
        diff_k<1><<<dim3(3, 2, 256), dim3(256), 0, stream>>>(adj, adjb, zT, zT, 0, 320);
        diff_k<1><<<dim3(3, 2, 256), dim3(256), 0, stream>>>(adj, adjb, zT, zT, 320, 640);
        diff_k<1><<<dim3(3, 2, 256), dim3(256), 0, stream>>>(adj, adjb, zT, zT, 640, 960);
    } else {
        diff_k<0><<<dim3(3, 2, 256), dim3(256), 0, stream>>>(adj, nullptr, zT, zT, 0, 320);
        diff_k<0><<<dim3(3, 2, 256), dim3(256), 0, stream>>>(adj, nullptr, zT, zT, 320, 640);
        diff_k<0><<<dim3(3, 2, 256), dim3(256), 0, stream>>>(adj, nullptr, zT, zT, 640, 960);
    }

    // 12. fused gates + combine -> out (fp32): flat GEMM M=NB_, N=512 (u/c interleaved)
    if (fast)
        gemm128<1><<<dim3(4, 416), dim3(256), 0, stream>>>(
            zT, KC_, wuc, KC_, nullptr,
            nullptr, 0, KC_, 0, nullptr, b_u, b_c, hnT, out);
    else
        gates_k0<<<dim3(4, 2, 256), dim3(256), 0, stream>>>(
            zT, W_u, W_c, b_u, b_c, hnT, out);

    (void)in_sizes; (void)n_in; (void)out_size; (void)ws_size;
}